// Round 7
// baseline (1071.349 us; speedup 1.0000x reference)
//
#include <hip/hip_runtime.h>
#include <hip/hip_fp16.h>
#include <cstdint>

#ifndef JAX_PARTITIONABLE
#define JAX_PARTITIONABLE 1   // modern JAX (>=0.5) default threefry_partitionable
#endif

#define NCELLS (128*128*128)          // 2,097,152
#define NQBINS (32*32*32)             // coarse query bins (4x4x4 cells each)

typedef _Float16 f16;
typedef f16  half8 __attribute__((ext_vector_type(8)));
typedef f16  half4 __attribute__((ext_vector_type(4)));
typedef float f32x4 __attribute__((ext_vector_type(4)));

#define WSTR 40   // row stride (halfs) for [64][32] W1^T tile
#define DSTR 40   // row stride (halfs) for per-wave [64][32] DEC tile
#define W2STR 72  // row stride (halfs) for [64][64] W2^T tile

// Packed grid cell (16B): u32[0]=(f0,f1) u32[1]=(f2,u0) u32[2]=(u1,u2) as f16 x1024;
// u32[3] = d in f32. Particles accumulate DIRECTLY into this layout via
// global_atomic_pk_add_f16 (f/u channels) + global_atomic_add_f32 (d channel).
// d stays f32: the dmean>1e-5 mask boundary amplifies d-perturbations (round-2 class).
// f/u f16 accumulation adds ~1-2e-3 rounding (<=~12 contributions/cell) - in budget.
#define GRID_SCALE 1024.0f
#define GRID_ISCALE 0.0009765625f

// ---------------- Threefry-2x32, key = (0, 42)  (jax.random.key(42)) ----------------
__device__ __forceinline__ uint32_t rotl32(uint32_t v, int s){ return (v << s) | (v >> (32 - s)); }

__device__ __forceinline__ void tf2x32(uint32_t& x0, uint32_t& x1){
  const uint32_t k0 = 0u, k1 = 42u;
  const uint32_t k2 = 0x1BD11BDAu ^ k0 ^ k1;
  x0 += k0; x1 += k1;
#define TFR(r) { x0 += x1; x1 = rotl32(x1,(r)); x1 ^= x0; }
  TFR(13) TFR(15) TFR(26) TFR(6)
  x0 += k1; x1 += k2 + 1u;
  TFR(17) TFR(29) TFR(16) TFR(24)
  x0 += k2; x1 += k0 + 2u;
  TFR(13) TFR(15) TFR(26) TFR(6)
  x0 += k0; x1 += k1 + 3u;
  TFR(17) TFR(29) TFR(16) TFR(24)
  x0 += k1; x1 += k2 + 4u;
  TFR(13) TFR(15) TFR(26) TFR(6)
  x0 += k2; x1 += k0 + 5u;
#undef TFR
}

// XLA f32 ErfInv (Giles) — exact coefficient match with jax/XLA.
// NOTE: must stay BIT-EXACT (log1pf, not a log2 rewrite): noise feeds
// f_norm = r0/max(r3,1e-5), whose derivative -f_norm/r3 amplifies ~1e-6
// noise shifts to ~1e-2 output error in sparse regions (round-2 fail).
__device__ __forceinline__ float erfinv_xla(float x){
  float w = -log1pf(-x*x);
  float p;
  if (w < 5.0f){
    w -= 2.5f;
    p =  2.81022636e-08f;
    p = fmaf(p,w, 3.43273939e-07f);
    p = fmaf(p,w,-3.5233877e-06f);
    p = fmaf(p,w,-4.39150654e-06f);
    p = fmaf(p,w, 0.00021858087f);
    p = fmaf(p,w,-0.00125372503f);
    p = fmaf(p,w,-0.00417768164f);
    p = fmaf(p,w, 0.246640727f);
    p = fmaf(p,w, 1.50140941f);
  } else {
    w = sqrtf(w) - 3.0f;
    p = -0.000200214257f;
    p = fmaf(p,w, 0.000100950558f);
    p = fmaf(p,w, 0.00134934322f);
    p = fmaf(p,w,-0.00367342844f);
    p = fmaf(p,w, 0.00573950773f);
    p = fmaf(p,w,-0.0076224613f);
    p = fmaf(p,w, 0.00943887047f);
    p = fmaf(p,w, 1.00167406f);
    p = fmaf(p,w, 2.83297682f);
  }
  return p*x;
}

// noise[i] = 0.8 * sqrt(2)*erfinv(uniform(-1,1)) with jax bit semantics
__device__ __forceinline__ float noise_at(uint32_t idx, uint32_t half){
#if JAX_PARTITIONABLE
  (void)half;
  uint32_t x0 = 0u, x1 = idx;     // counter = (hi=0, lo=i)
  tf2x32(x0, x1);
  uint32_t bits = x0 ^ x1;        // partitionable 32-bit path: xor-fold of both words
#else
  uint32_t j  = (idx < half) ? idx : (idx - half);
  uint32_t x0 = j, x1 = j + half;
  tf2x32(x0, x1);
  uint32_t bits = (idx < half) ? x0 : x1;
#endif
  float f = __uint_as_float((bits >> 9) | 0x3f800000u) - 1.0f;      // [0,1)
  float u = fmaxf(-0.99999994f, fmaf(f, 2.0f, -0.99999994f));       // (-1,1)
  return (1.41421356f * erfinv_xla(u)) * 0.8f;
}

// jax.nn.gelu approximate=True — minimal-op form:
// inner = x*(c0 + c1*x^2); tanh = 1 - 2r, r = rcp(exp(2*inner)+1); gelu = x*(1-r)
__device__ __forceinline__ float gelu_f(float x){
  float t = x*x;
  float inner = x * fmaf(0.035677408136f, t, 0.7978845608028654f);
  float e = __expf(2.0f * inner);
  float r = __builtin_amdgcn_rcpf(e + 1.0f);
  return x - x*r;
}

// common per-particle geometry
__device__ __forceinline__ void particle_cell(const float* xsr, int i,
                                              float& sx, float& sy, float& sz,
                                              int& bx, int& by, int& bz,
                                              float& dx, float& dy, float& dz){
  sx = fminf(fmaxf(xsr[3*i+0], 0.0f), 1.0f);
  sy = fminf(fmaxf(xsr[3*i+1], 0.0f), 1.0f);
  sz = fminf(fmaxf(xsr[3*i+2], 0.0f), 1.0f);
  float cx = fminf(fmaxf(sx*127.0f, 0.0f), 126.999f);
  float cy = fminf(fmaxf(sy*127.0f, 0.0f), 126.999f);
  float cz = fminf(fmaxf(sz*127.0f, 0.0f), 126.999f);
  float bxf = floorf(cx), byf = floorf(cy), bzf = floorf(cz);
  bx = (int)bxf; by = (int)byf; bz = (int)bzf;
  dx = cx - bxf; dy = cy - byf; dz = cz - bzf;
}

__device__ __forceinline__ int qbin_of(float qx01, float qy01, float qz01){
  int bx = min((int)(qx01*127.0f), 127) >> 2;
  int by = min((int)(qy01*127.0f), 127) >> 2;
  int bz = min((int)(qz01*127.0f), 127) >> 2;
  return (((bx<<5)+by)<<5)+bz;
}

// ---------------- fused atomic p2g (packed f16 grid) + query coarse-bin histogram ----
// Replaces the whole sort pipeline (hist2/scan1/scan2q/scan3/scatter2/p2g_gather_pair):
// each particle fires 8 corners x {3x pk_add_f16 + 1x add_f32} = 32 fire-and-forget
// atomics into the 32 MB L2-resident packed grid. Low contention (0.24 particles/cell).
__global__ void __launch_bounds__(256) p2gq_atomic_kernel(
    const float* __restrict__ xsr, const float* __restrict__ xsc,
    const float* __restrict__ Wf,  const float* __restrict__ bf,
    const float* __restrict__ xq,
    uint32_t* __restrict__ gridh, int* __restrict__ qcnt, int N, int M)
{
  int i = blockIdx.x*256 + threadIdx.x;
  if (i < N){
    float sx,sy,sz,dx,dy,dz; int bx,by,bz;
    particle_cell(xsr,i,sx,sy,sz,bx,by,bz,dx,dy,dz);
    float ux = xsc[3*i+0] - sx;
    float uy = xsc[3*i+1] - sy;
    float uz = xsc[3*i+2] - sz;
    float F0 = gelu_f(ux*Wf[0] + uy*Wf[3] + uz*Wf[6] + bf[0]) * GRID_SCALE;
    float F1 = gelu_f(ux*Wf[1] + uy*Wf[4] + uz*Wf[7] + bf[1]) * GRID_SCALE;
    float F2 = gelu_f(ux*Wf[2] + uy*Wf[5] + uz*Wf[8] + bf[2]) * GRID_SCALE;
    float U0 = ux * GRID_SCALE, U1 = uy * GRID_SCALE, U2 = uz * GRID_SCALE;
    float ex = 1.0f - dx, ey = 1.0f - dy, ez = 1.0f - dz;
    auto splat = [&](int xi, int yi, int zi, float w){
      uint32_t* p = gridh + ((size_t)((((xi<<7)+yi)<<7)+zi) << 2);
      unsafeAtomicAdd(reinterpret_cast<__half2*>(p+0),
                      __halves2half2(__float2half(F0*w), __float2half(F1*w)));
      unsafeAtomicAdd(reinterpret_cast<__half2*>(p+1),
                      __halves2half2(__float2half(F2*w), __float2half(U0*w)));
      unsafeAtomicAdd(reinterpret_cast<__half2*>(p+2),
                      __halves2half2(__float2half(U1*w), __float2half(U2*w)));
      unsafeAtomicAdd(reinterpret_cast<float*>(p+3), w);
    };
    splat(bx,  by,  bz,   ex*ey*ez);
    splat(bx,  by,  bz+1, ex*ey*dz);
    splat(bx,  by+1,bz,   ex*dy*ez);
    splat(bx,  by+1,bz+1, ex*dy*dz);
    splat(bx+1,by,  bz,   dx*ey*ez);
    splat(bx+1,by,  bz+1, dx*ey*dz);
    splat(bx+1,by+1,bz,   dx*dy*ez);
    splat(bx+1,by+1,bz+1, dx*dy*dz);
  }
  if (i < M){
    float qx01 = fminf(fmaxf(xq[3*i+0], 0.0f), 1.0f);
    float qy01 = fminf(fmaxf(xq[3*i+1], 0.0f), 1.0f);
    float qz01 = fminf(fmaxf(xq[3*i+2], 0.0f), 1.0f);
    atomicAdd(&qcnt[qbin_of(qx01,qy01,qz01)], 1);
  }
}

// exclusive scan of 32K query-bin counts (single 1024-thread block, 32 bins/thread)
__global__ void __launch_bounds__(1024) qscan_kernel(const int* __restrict__ qcnt,
                                                     int* __restrict__ qcur){
  __shared__ int lds[1024];
  int t = threadIdx.x;
  int base = t*32;
  int loc[32];
  int s = 0;
#pragma unroll
  for (int j = 0; j < 32; ++j){ loc[j] = qcnt[base+j]; s += loc[j]; }
  lds[t] = s; __syncthreads();
  for (int off = 1; off < 1024; off <<= 1){
    int u = (t >= off) ? lds[t-off] : 0;
    __syncthreads();
    lds[t] += u;
    __syncthreads();
  }
  int run = lds[t] - s;
#pragma unroll
  for (int j = 0; j < 32; ++j){ qcur[base+j] = run; run += loc[j]; }
}

// query coarse-sorted stash (bump-alloc via qcur)
__global__ void __launch_bounds__(256) scatterq_kernel(
    const float* __restrict__ xq, int* __restrict__ qcur,
    float* __restrict__ qs, int* __restrict__ qidx, int M){
  int i = blockIdx.x*256 + threadIdx.x;
  if (i >= M) return;
  float qx01 = fminf(fmaxf(xq[3*i+0], 0.0f), 1.0f);
  float qy01 = fminf(fmaxf(xq[3*i+1], 0.0f), 1.0f);
  float qz01 = fminf(fmaxf(xq[3*i+2], 0.0f), 1.0f);
  int pos = atomicAdd(&qcur[qbin_of(qx01,qy01,qz01)], 1);
  qs[3*pos+0] = qx01; qs[3*pos+1] = qy01; qs[3*pos+2] = qz01;
  qidx[pos] = i;
}

// ---------------- fused gather + MFMA MLP (K=16 chained, f16 grid) ----------------
// UNCHANGED from round 6 (135 us, VALUBusy 86%, FETCH 26.5 MB - issue-bound).
__global__ void __launch_bounds__(256, 4) gather_mlp_sorted_kernel(
    const float* __restrict__ qs,  const int* __restrict__ qidx,
    const uint4* __restrict__ gridh,
    const float* __restrict__ W1,  const float* __restrict__ b1,
    const float* __restrict__ W2,  const float* __restrict__ b2,
    const float* __restrict__ W3,  const float* __restrict__ b3,
    float* __restrict__ out, int M, int nblk)
{
  __shared__ __align__(16) f16  decs[4][64*DSTR]; // per-wave DEC^T [q][k<=32], 20 KB
  __shared__ __align__(16) f16  w1t[64*WSTR];     // W1^T [o][k], k padded 24->32, 5 KB
  __shared__ __align__(16) f16  w2t[64*W2STR];    // W2^T [o][k], 9 KB
  __shared__ __align__(16) float b1s[64], b2s[64];
  __shared__ __align__(16) float w3s[64*4];       // W3 rows padded to 4 floats, 1 KB

  // stage weights (block-cooperative)
  for (int i = threadIdx.x; i < 64*32; i += 256){
    int n = i >> 5, k = i & 31;
    w1t[n*WSTR + k] = (k < 24) ? (f16)W1[k*64 + n] : (f16)0.0f;
  }
  for (int i = threadIdx.x; i < 64*64; i += 256){
    int n = i >> 6, k = i & 63;
    w2t[n*W2STR + k] = (f16)W2[k*64 + n];
  }
  if (threadIdx.x < 64){ b1s[threadIdx.x] = b1[threadIdx.x]; b2s[threadIdx.x] = b2[threadIdx.x]; }
  for (int i = threadIdx.x; i < 192; i += 256){
    w3s[(i/3)*4 + (i - (i/3)*3)] = W3[i];
  }
  __syncthreads();

  int b = blockIdx.x;
  int nb8 = (nblk >> 3) << 3;
  int c = (b < nb8) ? ((b & 7)*(nblk >> 3) + (b >> 3)) : b;   // XCD-contiguous chunks
  int t = c*256 + (int)threadIdx.x;
  bool active = (t < M);
  int tc = active ? t : (M - 1);
  int m = qidx[tc];

  float qx01 = qs[3*tc+0], qy01 = qs[3*tc+1], qz01 = qs[3*tc+2];
  float qx = qx01*127.0f, qy = qy01*127.0f, qz = qz01*127.0f;

  // ---- gather: 8 MC paths, trilerp over packed f16 grid ----
  float r0=0.f,r1=0.f,r2=0.f,r3=0.f,r4=0.f,r5=0.f,r6=0.f;
  const uint32_t KSTRIDE = 3u*(uint32_t)M;
  const uint32_t HALF    = 4u*KSTRIDE;
  uint32_t m3 = 3u*(uint32_t)m;

  for (int k = 0; k < 8; ++k) {
    uint32_t base = (uint32_t)k*KSTRIDE + m3;
    float px = qx + noise_at(base+0u, HALF);
    float py = qy + noise_at(base+1u, HALF);
    float pz = qz + noise_at(base+2u, HALF);
    float fxf = floorf(px), fyf = floorf(py), fzf = floorf(pz);
    float fx = px - fxf, fy = py - fyf, fz = pz - fzf;
    int lx = (int)fxf, ly = (int)fyf, lz = (int)fzf;
    int x0i = min(max(lx,0),127),   x1i = min(max(lx+1,0),127);
    int y0i = min(max(ly,0),127),   y1i = min(max(ly+1,0),127);
    int z0i = min(max(lz,0),127),   z1i = min(max(lz+1,0),127);
    float ex = 1.0f-fx, ey = 1.0f-fy, ez = 1.0f-fz;

    auto corner = [&](int xi,int yi,int zi,float w){
      uint4 q4 = gridh[(((xi<<7)+yi)<<7)+zi];
      union { uint32_t u; f16 h[2]; } c0, c1, c2;
      c0.u = q4.x; c1.u = q4.y; c2.u = q4.z;
      r0 = fmaf((float)c0.h[0], w, r0);
      r1 = fmaf((float)c0.h[1], w, r1);
      r2 = fmaf((float)c1.h[0], w, r2);
      r4 = fmaf((float)c1.h[1], w, r4);
      r5 = fmaf((float)c2.h[0], w, r5);
      r6 = fmaf((float)c2.h[1], w, r6);
      r3 = fmaf(__uint_as_float(q4.w), w, r3);
    };
    corner(x0i,y0i,z0i, ex*ey*ez);
    corner(x0i,y0i,z1i, ex*ey*fz);
    corner(x0i,y1i,z0i, ex*fy*ez);
    corner(x0i,y1i,z1i, ex*fy*fz);
    corner(x1i,y0i,z0i, fx*ey*ez);
    corner(x1i,y0i,z1i, fx*ey*fz);
    corner(x1i,y1i,z0i, fx*fy*ez);
    corner(x1i,y1i,z1i, fx*fy*fz);
  }

  // d-channel is f32 -> mask decision window identical to the all-f32 kernel
  float dmean = r3*0.125f;
  float denom = fmaxf(dmean, 1e-5f);
  float maskf = (dmean > 1e-5f) ? 1.0f : 0.0f;
  float s   = 0.125f/denom*maskf;
  float sfu = s * GRID_ISCALE;   // exact /1024 for the scaled f16 channels
  float un0 = r4*sfu, un1 = r5*sfu, un2 = r6*sfu;

  float dec[24];
  dec[0]=r0*sfu; dec[1]=r1*sfu; dec[2]=r2*sfu; dec[3]=un0; dec[4]=un1; dec[5]=un2;
  dec[6]  = __builtin_amdgcn_sinf(0.5f*qx01);   // v_sin input is revolutions
  dec[7]  = __builtin_amdgcn_sinf(0.5f*qy01);
  dec[8]  = __builtin_amdgcn_sinf(0.5f*qz01);
  dec[9]  = __builtin_amdgcn_cosf(0.5f*qx01);
  dec[10] = __builtin_amdgcn_cosf(0.5f*qy01);
  dec[11] = __builtin_amdgcn_cosf(0.5f*qz01);
  dec[12] = __builtin_amdgcn_sinf(qx01);
  dec[13] = __builtin_amdgcn_sinf(qy01);
  dec[14] = __builtin_amdgcn_sinf(qz01);
  dec[15] = __builtin_amdgcn_cosf(qx01);
  dec[16] = __builtin_amdgcn_cosf(qy01);
  dec[17] = __builtin_amdgcn_cosf(qz01);
  dec[18] = __builtin_amdgcn_sinf(2.0f*qx01);
  dec[19] = __builtin_amdgcn_sinf(2.0f*qy01);
  dec[20] = __builtin_amdgcn_sinf(2.0f*qz01);
  dec[21] = __builtin_amdgcn_cosf(2.0f*qx01);
  dec[22] = __builtin_amdgcn_cosf(2.0f*qy01);
  dec[23] = __builtin_amdgcn_cosf(2.0f*qz01);

  // ---- MLP via chained 16x16x16 MFMAs (verified rounds 5/6) ----
  int lane = threadIdx.x & 63;
  int wv   = threadIdx.x >> 6;
  f16* hb = &decs[wv][0];
  int lo = lane & 15;           // C col / frag m-n index
  int hi = lane >> 4;           // quad id: frag k base = 4*hi; C row base = 4*hi

  // stage dec (fp16, k padded to 32) into hb[row=lane][k]: 4x b128
  {
    half8 dh;
#pragma unroll
    for (int c4 = 0; c4 < 3; ++c4){
#pragma unroll
      for (int j = 0; j < 8; ++j) dh[j] = (f16)dec[c4*8 + j];
      *reinterpret_cast<half8*>(&hb[lane*DSTR + c4*8]) = dh;
    }
#pragma unroll
    for (int j = 0; j < 8; ++j) dh[j] = (f16)0.0f;
    *reinterpret_cast<half8*>(&hb[lane*DSTR + 24]) = dh;
  }

  half4 w1f[4][2];
#pragma unroll
  for (int a = 0; a < 4; ++a)
#pragma unroll
    for (int kb = 0; kb < 2; ++kb)
      w1f[a][kb] = *reinterpret_cast<const half4*>(&w1t[(16*a + lo)*WSTR + 16*kb + 4*hi]);

  half4 dff[4][2];
#pragma unroll
  for (int bq = 0; bq < 4; ++bq)
#pragma unroll
    for (int kb = 0; kb < 2; ++kb)
      dff[bq][kb] = *reinterpret_cast<const half4*>(&hb[(16*bq + lo)*DSTR + 16*kb + 4*hi]);

  // layer 1: H^T = W1^T @ DEC^T, C-init = bias; hv[a][bq] is layer-2 B-frag (kb=a)
  half4 hv[4][4];
#pragma unroll
  for (int a = 0; a < 4; ++a){
    f32x4 zb = *reinterpret_cast<const f32x4*>(&b1s[16*a + 4*hi]);
#pragma unroll
    for (int bq = 0; bq < 4; ++bq){
      f32x4 z = __builtin_amdgcn_mfma_f32_16x16x16f16(w1f[a][0], dff[bq][0], zb, 0, 0, 0);
      z       = __builtin_amdgcn_mfma_f32_16x16x16f16(w1f[a][1], dff[bq][1], z,  0, 0, 0);
      half4 hvv;
#pragma unroll
      for (int p = 0; p < 4; ++p) hvv[p] = (f16)gelu_f(z[p]);
      hv[a][bq] = hvv;
    }
  }

  // layer 2 + 3: G^T = W2^T @ H^T (4 chained K=16), gelu + partial W3 dots in regs
  float part[4][3];
#pragma unroll
  for (int bq = 0; bq < 4; ++bq){ part[bq][0]=0.f; part[bq][1]=0.f; part[bq][2]=0.f; }

#pragma unroll
  for (int a2 = 0; a2 < 4; ++a2){
    half4 w2f[4];
#pragma unroll
    for (int kb = 0; kb < 4; ++kb)
      w2f[kb] = *reinterpret_cast<const half4*>(&w2t[(16*a2 + lo)*W2STR + 16*kb + 4*hi]);
    f32x4 zb2 = *reinterpret_cast<const f32x4*>(&b2s[16*a2 + 4*hi]);
#pragma unroll
    for (int bq = 0; bq < 4; ++bq){
      f32x4 z = __builtin_amdgcn_mfma_f32_16x16x16f16(w2f[0], hv[0][bq], zb2, 0, 0, 0);
      z       = __builtin_amdgcn_mfma_f32_16x16x16f16(w2f[1], hv[1][bq], z,   0, 0, 0);
      z       = __builtin_amdgcn_mfma_f32_16x16x16f16(w2f[2], hv[2][bq], z,   0, 0, 0);
      z       = __builtin_amdgcn_mfma_f32_16x16x16f16(w2f[3], hv[3][bq], z,   0, 0, 0);
#pragma unroll
      for (int p = 0; p < 4; ++p){
        f32x4 w3v = *reinterpret_cast<const f32x4*>(&w3s[(16*a2 + 4*hi + p)*4]);
        float g = gelu_f(z[p]);
        part[bq][0] = fmaf(g, w3v[0], part[bq][0]);
        part[bq][1] = fmaf(g, w3v[1], part[bq][1]);
        part[bq][2] = fmaf(g, w3v[2], part[bq][2]);
      }
    }
  }

  // reduce partials across the 4 quad-groups (lanes lo+16*hi')
#pragma unroll
  for (int bq = 0; bq < 4; ++bq)
#pragma unroll
    for (int cc = 0; cc < 3; ++cc){
      float v = part[bq][cc];
      v += __shfl_xor(v, 16, 64);
      v += __shfl_xor(v, 32, 64);
      part[bq][cc] = v;
    }

  // lane L owns query q* = 16*hi + lo = L  -> select bq == hi (static select chain)
  float o0 = (hi==0) ? part[0][0] : (hi==1) ? part[1][0] : (hi==2) ? part[2][0] : part[3][0];
  float o1 = (hi==0) ? part[0][1] : (hi==1) ? part[1][1] : (hi==2) ? part[2][1] : part[3][1];
  float o2 = (hi==0) ? part[0][2] : (hi==1) ? part[1][2] : (hi==2) ? part[2][2] : part[3][2];
  o0 += b3[0]; o1 += b3[1]; o2 += b3[2];

  if (active){
    out[3*m+0] = fminf(fmaxf(un0 + o0, 0.001f), 0.999f);
    out[3*m+1] = fminf(fmaxf(un1 + o1, 0.001f), 0.999f);
    out[3*m+2] = fminf(fmaxf(un2 + o2, 0.001f), 0.999f);
  }
}

extern "C" void kernel_launch(void* const* d_in, const int* in_sizes, int n_in,
                              void* d_out, int out_size, void* d_ws, size_t ws_size,
                              hipStream_t stream)
{
  const float* xq  = (const float*)d_in[0];
  const float* xsr = (const float*)d_in[1];
  const float* xsc = (const float*)d_in[2];
  const float* Wf  = (const float*)d_in[3];
  const float* bf  = (const float*)d_in[4];
  const float* W1  = (const float*)d_in[5];
  const float* b1  = (const float*)d_in[6];
  const float* W2  = (const float*)d_in[7];
  const float* b2  = (const float*)d_in[8];
  const float* W3  = (const float*)d_in[9];
  const float* b3  = (const float*)d_in[10];
  float* out  = (float*)d_out;
  int M = in_sizes[0]/3;
  int N = in_sizes[1]/3;

  // workspace layout (256B-aligned chunks); gridh and qcnt adjacent -> single memset
  char* W = (char*)d_ws;
  size_t off = 0;
  auto alloc = [&](size_t bytes){ size_t o = off; off = (off + bytes + 255) & ~(size_t)255; return o; };
  size_t o_gridh = alloc((size_t)NCELLS * 16);           // 32 MiB packed f16 grid
  size_t o_qcnt  = alloc((size_t)NQBINS * sizeof(int));  // 128 KB (directly after gridh)
  size_t o_qcur  = alloc((size_t)NQBINS * sizeof(int));  // 128 KB
  size_t o_qs    = alloc((size_t)M * 3 * sizeof(float)); // 6 MB
  size_t o_qidx  = alloc((size_t)M * sizeof(int));       // 2 MB
  (void)ws_size;

  uint32_t* gridh = (uint32_t*)(W + o_gridh);
  int*      qcnt  = (int*)(W + o_qcnt);
  int*      qcur  = (int*)(W + o_qcur);
  float*    qs    = (float*)(W + o_qs);
  int*      qidx  = (int*)(W + o_qidx);

  int nthr = (N > M) ? N : M;
  int nblkNM = (nthr + 255) / 256;

  hipMemsetAsync(gridh, 0, (size_t)NCELLS * 16 + (size_t)NQBINS * sizeof(int), stream);
  p2gq_atomic_kernel<<<nblkNM, 256, 0, stream>>>(xsr, xsc, Wf, bf, xq, gridh, qcnt, N, M);
  qscan_kernel<<<1, 1024, 0, stream>>>(qcnt, qcur);
  scatterq_kernel<<<(M+255)/256, 256, 0, stream>>>(xq, qcur, qs, qidx, M);

  int nblk = (M + 255) / 256;
  gather_mlp_sorted_kernel<<<nblk, 256, 0, stream>>>(qs, qidx, (const uint4*)gridh,
                                                     W1,b1,W2,b2,W3,b3, out, M, nblk);
}

// Round 8
// 381.093 us; speedup vs baseline: 2.8113x; 2.8113x over previous
//
#include <hip/hip_runtime.h>
#include <cstdint>

#ifndef JAX_PARTITIONABLE
#define JAX_PARTITIONABLE 1   // modern JAX (>=0.5) default threefry_partitionable
#endif

#define NCELLS (128*128*128)          // 2,097,152
#define SCAN_BLOCKS 1024              // NCELLS / 2048
#define NQBINS (32*32*32)             // coarse query bins (4x4x4 cells each)

typedef _Float16 f16;
typedef f16  half8 __attribute__((ext_vector_type(8)));
typedef f16  half4 __attribute__((ext_vector_type(4)));
typedef float f32x4 __attribute__((ext_vector_type(4)));

#define WSTR 40   // row stride (halfs) for [64][32] W1^T tile
#define DSTR 40   // row stride (halfs) for per-wave [64][32] DEC tile
#define W2STR 72  // row stride (halfs) for [64][64] W2^T tile

// Packed grid cell (16B): u32[0]=(f0,f1) u32[1]=(f2,u0) u32[2]=(u1,u2) as f16 x1024;
// u32[3] = d in f32. d stays f32: the dmean>1e-5 mask boundary amplifies
// d-perturbations (round-2 lesson class). x1024 (exact pow2) lifts f/u out of f16
// subnormals and cancels exactly via sfu = s/1024.
// NOTE (round-7 lesson): device-scope atomics on gfx950 write through to HBM
// (~32B/atomic, no L2 accumulation) — never use atomics as a bulk accumulation path.
#define GRID_SCALE 1024.0f
#define GRID_ISCALE 0.0009765625f

// ---------------- Threefry-2x32, key = (0, 42)  (jax.random.key(42)) ----------------
__device__ __forceinline__ uint32_t rotl32(uint32_t v, int s){ return (v << s) | (v >> (32 - s)); }

__device__ __forceinline__ void tf2x32(uint32_t& x0, uint32_t& x1){
  const uint32_t k0 = 0u, k1 = 42u;
  const uint32_t k2 = 0x1BD11BDAu ^ k0 ^ k1;
  x0 += k0; x1 += k1;
#define TFR(r) { x0 += x1; x1 = rotl32(x1,(r)); x1 ^= x0; }
  TFR(13) TFR(15) TFR(26) TFR(6)
  x0 += k1; x1 += k2 + 1u;
  TFR(17) TFR(29) TFR(16) TFR(24)
  x0 += k2; x1 += k0 + 2u;
  TFR(13) TFR(15) TFR(26) TFR(6)
  x0 += k0; x1 += k1 + 3u;
  TFR(17) TFR(29) TFR(16) TFR(24)
  x0 += k1; x1 += k2 + 4u;
  TFR(13) TFR(15) TFR(26) TFR(6)
  x0 += k2; x1 += k0 + 5u;
#undef TFR
}

// XLA f32 ErfInv (Giles) — exact coefficient match with jax/XLA.
// NOTE: must stay BIT-EXACT (log1pf, not a log2 rewrite): noise feeds
// f_norm = r0/max(r3,1e-5), whose derivative -f_norm/r3 amplifies ~1e-6
// noise shifts to ~1e-2 output error in sparse regions (round-2 fail).
__device__ __forceinline__ float erfinv_xla(float x){
  float w = -log1pf(-x*x);
  float p;
  if (w < 5.0f){
    w -= 2.5f;
    p =  2.81022636e-08f;
    p = fmaf(p,w, 3.43273939e-07f);
    p = fmaf(p,w,-3.5233877e-06f);
    p = fmaf(p,w,-4.39150654e-06f);
    p = fmaf(p,w, 0.00021858087f);
    p = fmaf(p,w,-0.00125372503f);
    p = fmaf(p,w,-0.00417768164f);
    p = fmaf(p,w, 0.246640727f);
    p = fmaf(p,w, 1.50140941f);
  } else {
    w = sqrtf(w) - 3.0f;
    p = -0.000200214257f;
    p = fmaf(p,w, 0.000100950558f);
    p = fmaf(p,w, 0.00134934322f);
    p = fmaf(p,w,-0.00367342844f);
    p = fmaf(p,w, 0.00573950773f);
    p = fmaf(p,w,-0.0076224613f);
    p = fmaf(p,w, 0.00943887047f);
    p = fmaf(p,w, 1.00167406f);
    p = fmaf(p,w, 2.83297682f);
  }
  return p*x;
}

// noise[i] = 0.8 * sqrt(2)*erfinv(uniform(-1,1)) with jax bit semantics
__device__ __forceinline__ float noise_at(uint32_t idx, uint32_t half){
#if JAX_PARTITIONABLE
  (void)half;
  uint32_t x0 = 0u, x1 = idx;     // counter = (hi=0, lo=i)
  tf2x32(x0, x1);
  uint32_t bits = x0 ^ x1;        // partitionable 32-bit path: xor-fold of both words
#else
  uint32_t j  = (idx < half) ? idx : (idx - half);
  uint32_t x0 = j, x1 = j + half;
  tf2x32(x0, x1);
  uint32_t bits = (idx < half) ? x0 : x1;
#endif
  float f = __uint_as_float((bits >> 9) | 0x3f800000u) - 1.0f;      // [0,1)
  float u = fmaxf(-0.99999994f, fmaf(f, 2.0f, -0.99999994f));       // (-1,1)
  return (1.41421356f * erfinv_xla(u)) * 0.8f;
}

// jax.nn.gelu approximate=True — exp2-folded minimal form:
// exp(2*inner) = exp2(x * (c0*2log2e + c1*2log2e*x^2)); gelu = x - x*rcp(e+1)
__device__ __forceinline__ float gelu_f(float x){
  float t = x*x;
  float inner = x * fmaf(0.10294322f, t, 2.30220775f);   // pre-scaled by 2*log2(e)
  float e = exp2f(inner);
  float r = __builtin_amdgcn_rcpf(e + 1.0f);
  return x - x*r;
}

__device__ __forceinline__ uint32_t pack2h_scaled(float a, float b){
  union { f16 h[2]; uint32_t u; } c;
  c.h[0] = (f16)(a * GRID_SCALE);
  c.h[1] = (f16)(b * GRID_SCALE);
  return c.u;
}
__device__ __forceinline__ uint32_t pack2h_raw(float a, float b){
  union { f16 h[2]; uint32_t u; } c;
  c.h[0] = (f16)a;
  c.h[1] = (f16)b;
  return c.u;
}

// common per-particle geometry
__device__ __forceinline__ void particle_cell(const float* xsr, int i,
                                              float& sx, float& sy, float& sz,
                                              int& bx, int& by, int& bz,
                                              float& dx, float& dy, float& dz){
  sx = fminf(fmaxf(xsr[3*i+0], 0.0f), 1.0f);
  sy = fminf(fmaxf(xsr[3*i+1], 0.0f), 1.0f);
  sz = fminf(fmaxf(xsr[3*i+2], 0.0f), 1.0f);
  float cx = fminf(fmaxf(sx*127.0f, 0.0f), 126.999f);
  float cy = fminf(fmaxf(sy*127.0f, 0.0f), 126.999f);
  float cz = fminf(fmaxf(sz*127.0f, 0.0f), 126.999f);
  float bxf = floorf(cx), byf = floorf(cy), bzf = floorf(cz);
  bx = (int)bxf; by = (int)byf; bz = (int)bzf;
  dx = cx - bxf; dy = cy - byf; dz = cz - bzf;
}

__device__ __forceinline__ int qbin_of(float qx01, float qy01, float qz01){
  int bx = min((int)(qx01*127.0f), 127) >> 2;
  int by = min((int)(qy01*127.0f), 127) >> 2;
  int bz = min((int)(qz01*127.0f), 127) >> 2;
  return (((bx<<5)+by)<<5)+bz;
}

// ---------------- fused histogram: particle cells + query coarse bins ----------------
__global__ void __launch_bounds__(256) hist2_kernel(
    const float* __restrict__ xsr, const float* __restrict__ xq,
    int* __restrict__ cnt, int* __restrict__ qcnt, int N, int M){
  int i = blockIdx.x*256 + threadIdx.x;
  if (i < N){
    float sx,sy,sz,dx,dy,dz; int bx,by,bz;
    particle_cell(xsr,i,sx,sy,sz,bx,by,bz,dx,dy,dz);
    atomicAdd(&cnt[(((bx<<7)+by)<<7)+bz], 1);
  }
  if (i < M){
    float qx01 = fminf(fmaxf(xq[3*i+0], 0.0f), 1.0f);
    float qy01 = fminf(fmaxf(xq[3*i+1], 0.0f), 1.0f);
    float qz01 = fminf(fmaxf(xq[3*i+2], 0.0f), 1.0f);
    atomicAdd(&qcnt[qbin_of(qx01,qy01,qz01)], 1);
  }
}

// exclusive scan stage 1: 1024 blocks x 256 thr x 8 elems
__global__ void __launch_bounds__(256) scan1_kernel(const int* __restrict__ cnt,
                                                    int* __restrict__ offs,
                                                    int* __restrict__ bsum){
  __shared__ int lds[256];
  int t = threadIdx.x;
  int base = blockIdx.x*2048 + t*8;
  const int4* c4 = reinterpret_cast<const int4*>(cnt + base);
  int4 a0 = c4[0], a1 = c4[1];
  int s = a0.x+a0.y+a0.z+a0.w + a1.x+a1.y+a1.z+a1.w;
  lds[t] = s; __syncthreads();
  for (int off = 1; off < 256; off <<= 1){
    int v = (t >= off) ? lds[t-off] : 0;
    __syncthreads();
    lds[t] += v;
    __syncthreads();
  }
  int run = lds[t] - s;
  if (t == 255) bsum[blockIdx.x] = lds[255];
  int* o = offs + base;
  o[0]=run; run+=a0.x; o[1]=run; run+=a0.y; o[2]=run; run+=a0.z; o[3]=run; run+=a0.w;
  o[4]=run; run+=a1.x; o[5]=run; run+=a1.y; o[6]=run; run+=a1.z; o[7]=run;
}

// fused: scan block sums (particles) + full exclusive scan of 32K query-bin counts
__global__ void __launch_bounds__(1024) scan2q_kernel(int* __restrict__ bsum,
                                                      const int* __restrict__ qcnt,
                                                      int* __restrict__ qcur){
  __shared__ int lds[1024];
  int t = threadIdx.x;
  int v = bsum[t];
  lds[t] = v; __syncthreads();
  for (int off = 1; off < 1024; off <<= 1){
    int u = (t >= off) ? lds[t-off] : 0;
    __syncthreads();
    lds[t] += u;
    __syncthreads();
  }
  bsum[t] = lds[t] - v;
  if (t == 1023) bsum[1024] = lds[1023];
  __syncthreads();
  int base = t*32;
  int loc[32];
  int s = 0;
#pragma unroll
  for (int j = 0; j < 32; ++j){ loc[j] = qcnt[base+j]; s += loc[j]; }
  lds[t] = s; __syncthreads();
  for (int off = 1; off < 1024; off <<= 1){
    int u = (t >= off) ? lds[t-off] : 0;
    __syncthreads();
    lds[t] += u;
    __syncthreads();
  }
  int run = lds[t] - s;
#pragma unroll
  for (int j = 0; j < 32; ++j){ qcur[base+j] = run; run += loc[j]; }
}

// stage 3: add block offsets, init cursor, write sentinel
__global__ void __launch_bounds__(256) scan3_kernel(int* __restrict__ offs,
                                                    const int* __restrict__ bsum,
                                                    int* __restrict__ cursor){
  int i = blockIdx.x*256 + threadIdx.x;
  int o = offs[i] + bsum[i >> 11];
  offs[i] = o; cursor[i] = o;
  if (i == 0) offs[NCELLS] = bsum[SCAN_BLOCKS];
}

// fused scatter: packed f16 particle payload bump-alloc + query float4 stash
// payload half8 = (f0,f1,f2,u0,u1,u2)x1024 + (dx,dy); dz separate f32 (mask-critical
// d-channel weights stay f32 through accumulation).
__global__ void __launch_bounds__(256) scatter2_kernel(
    const float* __restrict__ xsr, const float* __restrict__ xsc,
    const float* __restrict__ Wf,  const float* __restrict__ bf,
    const float* __restrict__ xq,
    int* __restrict__ cursor, int* __restrict__ qcur,
    half8* __restrict__ pp, float* __restrict__ pz,
    float4* __restrict__ qpk, int N, int M){
  int i = blockIdx.x*256 + threadIdx.x;
  if (i < N){
    float sx,sy,sz,dx,dy,dz; int bx,by,bz;
    particle_cell(xsr,i,sx,sy,sz,bx,by,bz,dx,dy,dz);
    float ux = xsc[3*i+0] - sx;
    float uy = xsc[3*i+1] - sy;
    float uz = xsc[3*i+2] - sz;
    float f0 = gelu_f(ux*Wf[0] + uy*Wf[3] + uz*Wf[6] + bf[0]);
    float f1 = gelu_f(ux*Wf[1] + uy*Wf[4] + uz*Wf[7] + bf[1]);
    float f2 = gelu_f(ux*Wf[2] + uy*Wf[5] + uz*Wf[8] + bf[2]);
    int bin = (((bx<<7)+by)<<7)+bz;
    int pos = atomicAdd(&cursor[bin], 1);
    half8 ph;
    ph[0] = (f16)(f0*GRID_SCALE); ph[1] = (f16)(f1*GRID_SCALE); ph[2] = (f16)(f2*GRID_SCALE);
    ph[3] = (f16)(ux*GRID_SCALE); ph[4] = (f16)(uy*GRID_SCALE); ph[5] = (f16)(uz*GRID_SCALE);
    ph[6] = (f16)dx; ph[7] = (f16)dy;
    pp[pos] = ph;
    pz[pos] = dz;
  }
  if (i < M){
    float qx01 = fminf(fmaxf(xq[3*i+0], 0.0f), 1.0f);
    float qy01 = fminf(fmaxf(xq[3*i+1], 0.0f), 1.0f);
    float qz01 = fminf(fmaxf(xq[3*i+2], 0.0f), 1.0f);
    int pos = atomicAdd(&qcur[qbin_of(qx01,qy01,qz01)], 1);
    qpk[pos] = make_float4(qx01, qy01, qz01, __int_as_float(i));
  }
}

// z-pair per-cell gather (packed f16 payload) -> packed f16 grid (16B/cell)
__global__ void __launch_bounds__(256) p2g_gather_pair_kernel(
    const int* __restrict__ offs,
    const half8* __restrict__ pp, const float* __restrict__ pz,
    uint4* __restrict__ gridh){
  int tid = blockIdx.x*256 + threadIdx.x;   // exactly NCELLS/2 threads
  int zg = tid & 63, y = (tid >> 6) & 127, x = tid >> 13;
  int z0 = zg << 1;
  float a0[2]={0,0},a1[2]={0,0},a2[2]={0,0},a3[2]={0,0},a4[2]={0,0},a5[2]={0,0},a6[2]={0,0};
#pragma unroll
  for (int ox = 0; ox < 2; ++ox){
    int bx = x - ox; if (bx < 0) continue;
#pragma unroll
    for (int oy = 0; oy < 2; ++oy){
      int by = y - oy; if (by < 0) continue;
      int b0 = ((((bx<<7)+by)<<7)) + z0;
      int em = offs[b0];
      int sm = (z0 > 0) ? offs[b0-1] : em;
      int e0 = offs[b0+1];
      int e1 = offs[b0+2];
      for (int p = sm; p < e1; ++p){
        half8 P = pp[p]; float dz = pz[p];
        float pdx = (float)P[6], pdy = (float)P[7];
        float wx = ox ? pdx : 1.0f - pdx;
        float wy = oy ? pdy : 1.0f - pdy;
        float wxy = wx*wy;
        float omdz = 1.0f - dz;
        float w0 = (p < em) ? dz : ((p < e0) ? omdz : 0.0f);
        float w1 = (p < em) ? 0.0f : ((p < e0) ? dz : omdz);
        w0 *= wxy; w1 *= wxy;
        float v0=(float)P[0], v1=(float)P[1], v2=(float)P[2];
        float v3=(float)P[3], v4=(float)P[4], v5=(float)P[5];
        a0[0]=fmaf(v0,w0,a0[0]); a1[0]=fmaf(v1,w0,a1[0]); a2[0]=fmaf(v2,w0,a2[0]);
        a3[0]+=w0; a4[0]=fmaf(v3,w0,a4[0]); a5[0]=fmaf(v4,w0,a5[0]); a6[0]=fmaf(v5,w0,a6[0]);
        a0[1]=fmaf(v0,w1,a0[1]); a1[1]=fmaf(v1,w1,a1[1]); a2[1]=fmaf(v2,w1,a2[1]);
        a3[1]+=w1; a4[1]=fmaf(v3,w1,a4[1]); a5[1]=fmaf(v4,w1,a5[1]); a6[1]=fmaf(v5,w1,a6[1]);
      }
    }
  }
  int cell0 = ((((x<<7)+y)<<7)) + z0;
  uint4 g0, g1;
  g0.x = pack2h_raw(a0[0], a1[0]); g0.y = pack2h_raw(a2[0], a4[0]);
  g0.z = pack2h_raw(a5[0], a6[0]); g0.w = __float_as_uint(a3[0]);
  g1.x = pack2h_raw(a0[1], a1[1]); g1.y = pack2h_raw(a2[1], a4[1]);
  g1.z = pack2h_raw(a5[1], a6[1]); g1.w = __float_as_uint(a3[1]);
  uint4* g = gridh + cell0;
  g[0] = g0; g[1] = g1;
}

// ---------------- fused gather + MFMA MLP (K=16 chained, f16 grid) ----------------
// Verified round 6: 135 us, VALUBusy 86%, FETCH 26.5 MB — issue-bound.
__global__ void __launch_bounds__(256, 4) gather_mlp_sorted_kernel(
    const float4* __restrict__ qpk,
    const uint4* __restrict__ gridh,
    const float* __restrict__ W1,  const float* __restrict__ b1,
    const float* __restrict__ W2,  const float* __restrict__ b2,
    const float* __restrict__ W3,  const float* __restrict__ b3,
    float* __restrict__ out, int M, int nblk)
{
  __shared__ __align__(16) f16  decs[4][64*DSTR]; // per-wave DEC^T [q][k<=32], 20 KB
  __shared__ __align__(16) f16  w1t[64*WSTR];     // W1^T [o][k], k padded 24->32, 5 KB
  __shared__ __align__(16) f16  w2t[64*W2STR];    // W2^T [o][k], 9 KB
  __shared__ __align__(16) float b1s[64], b2s[64];
  __shared__ __align__(16) float w3s[64*4];       // W3 rows padded to 4 floats, 1 KB

  // stage weights (block-cooperative)
  for (int i = threadIdx.x; i < 64*32; i += 256){
    int n = i >> 5, k = i & 31;
    w1t[n*WSTR + k] = (k < 24) ? (f16)W1[k*64 + n] : (f16)0.0f;
  }
  for (int i = threadIdx.x; i < 64*64; i += 256){
    int n = i >> 6, k = i & 63;
    w2t[n*W2STR + k] = (f16)W2[k*64 + n];
  }
  if (threadIdx.x < 64){ b1s[threadIdx.x] = b1[threadIdx.x]; b2s[threadIdx.x] = b2[threadIdx.x]; }
  for (int i = threadIdx.x; i < 192; i += 256){
    w3s[(i/3)*4 + (i - (i/3)*3)] = W3[i];
  }
  __syncthreads();

  int b = blockIdx.x;
  int nb8 = (nblk >> 3) << 3;
  int c = (b < nb8) ? ((b & 7)*(nblk >> 3) + (b >> 3)) : b;   // XCD-contiguous chunks
  int t = c*256 + (int)threadIdx.x;
  bool active = (t < M);
  int tc = active ? t : (M - 1);

  float4 qv = qpk[tc];
  float qx01 = qv.x, qy01 = qv.y, qz01 = qv.z;
  int m = __float_as_int(qv.w);
  float qx = qx01*127.0f, qy = qy01*127.0f, qz = qz01*127.0f;

  // ---- gather: 8 MC paths, trilerp over packed f16 grid ----
  float r0=0.f,r1=0.f,r2=0.f,r3=0.f,r4=0.f,r5=0.f,r6=0.f;
  const uint32_t KSTRIDE = 3u*(uint32_t)M;
  const uint32_t HALF    = 4u*KSTRIDE;
  uint32_t m3 = 3u*(uint32_t)m;

  for (int k = 0; k < 8; ++k) {
    uint32_t base = (uint32_t)k*KSTRIDE + m3;
    float px = qx + noise_at(base+0u, HALF);
    float py = qy + noise_at(base+1u, HALF);
    float pz = qz + noise_at(base+2u, HALF);
    float fxf = floorf(px), fyf = floorf(py), fzf = floorf(pz);
    float fx = px - fxf, fy = py - fyf, fz = pz - fzf;
    int lx = (int)fxf, ly = (int)fyf, lz = (int)fzf;
    int x0i = min(max(lx,0),127),   x1i = min(max(lx+1,0),127);
    int y0i = min(max(ly,0),127),   y1i = min(max(ly+1,0),127);
    int z0i = min(max(lz,0),127),   z1i = min(max(lz+1,0),127);
    float ex = 1.0f-fx, ey = 1.0f-fy, ez = 1.0f-fz;

    auto corner = [&](int xi,int yi,int zi,float w){
      uint4 q4 = gridh[(((xi<<7)+yi)<<7)+zi];
      union { uint32_t u; f16 h[2]; } c0, c1, c2;
      c0.u = q4.x; c1.u = q4.y; c2.u = q4.z;
      r0 = fmaf((float)c0.h[0], w, r0);
      r1 = fmaf((float)c0.h[1], w, r1);
      r2 = fmaf((float)c1.h[0], w, r2);
      r4 = fmaf((float)c1.h[1], w, r4);
      r5 = fmaf((float)c2.h[0], w, r5);
      r6 = fmaf((float)c2.h[1], w, r6);
      r3 = fmaf(__uint_as_float(q4.w), w, r3);
    };
    corner(x0i,y0i,z0i, ex*ey*ez);
    corner(x0i,y0i,z1i, ex*ey*fz);
    corner(x0i,y1i,z0i, ex*fy*ez);
    corner(x0i,y1i,z1i, ex*fy*fz);
    corner(x1i,y0i,z0i, fx*ey*ez);
    corner(x1i,y0i,z1i, fx*ey*fz);
    corner(x1i,y1i,z0i, fx*fy*ez);
    corner(x1i,y1i,z1i, fx*fy*fz);
  }

  // d-channel is f32 -> mask decision window identical to the all-f32 kernel
  float dmean = r3*0.125f;
  float denom = fmaxf(dmean, 1e-5f);
  float maskf = (dmean > 1e-5f) ? 1.0f : 0.0f;
  float s   = 0.125f/denom*maskf;
  float sfu = s * GRID_ISCALE;   // exact /1024 for the scaled f16 channels
  float un0 = r4*sfu, un1 = r5*sfu, un2 = r6*sfu;

  float dec[24];
  dec[0]=r0*sfu; dec[1]=r1*sfu; dec[2]=r2*sfu; dec[3]=un0; dec[4]=un1; dec[5]=un2;
  dec[6]  = __builtin_amdgcn_sinf(0.5f*qx01);   // v_sin input is revolutions
  dec[7]  = __builtin_amdgcn_sinf(0.5f*qy01);
  dec[8]  = __builtin_amdgcn_sinf(0.5f*qz01);
  dec[9]  = __builtin_amdgcn_cosf(0.5f*qx01);
  dec[10] = __builtin_amdgcn_cosf(0.5f*qy01);
  dec[11] = __builtin_amdgcn_cosf(0.5f*qz01);
  dec[12] = __builtin_amdgcn_sinf(qx01);
  dec[13] = __builtin_amdgcn_sinf(qy01);
  dec[14] = __builtin_amdgcn_sinf(qz01);
  dec[15] = __builtin_amdgcn_cosf(qx01);
  dec[16] = __builtin_amdgcn_cosf(qy01);
  dec[17] = __builtin_amdgcn_cosf(qz01);
  dec[18] = __builtin_amdgcn_sinf(2.0f*qx01);
  dec[19] = __builtin_amdgcn_sinf(2.0f*qy01);
  dec[20] = __builtin_amdgcn_sinf(2.0f*qz01);
  dec[21] = __builtin_amdgcn_cosf(2.0f*qx01);
  dec[22] = __builtin_amdgcn_cosf(2.0f*qy01);
  dec[23] = __builtin_amdgcn_cosf(2.0f*qz01);

  // ---- MLP via chained 16x16x16 MFMAs (verified rounds 5/6) ----
  int lane = threadIdx.x & 63;
  int wv   = threadIdx.x >> 6;
  f16* hb = &decs[wv][0];
  int lo = lane & 15;           // C col / frag m-n index
  int hi = lane >> 4;           // quad id: frag k base = 4*hi; C row base = 4*hi

  // stage dec (fp16, k padded to 32) into hb[row=lane][k]: 4x b128
  {
    half8 dh;
#pragma unroll
    for (int c4 = 0; c4 < 3; ++c4){
#pragma unroll
      for (int j = 0; j < 8; ++j) dh[j] = (f16)dec[c4*8 + j];
      *reinterpret_cast<half8*>(&hb[lane*DSTR + c4*8]) = dh;
    }
#pragma unroll
    for (int j = 0; j < 8; ++j) dh[j] = (f16)0.0f;
    *reinterpret_cast<half8*>(&hb[lane*DSTR + 24]) = dh;
  }

  half4 w1f[4][2];
#pragma unroll
  for (int a = 0; a < 4; ++a)
#pragma unroll
    for (int kb = 0; kb < 2; ++kb)
      w1f[a][kb] = *reinterpret_cast<const half4*>(&w1t[(16*a + lo)*WSTR + 16*kb + 4*hi]);

  half4 dff[4][2];
#pragma unroll
  for (int bq = 0; bq < 4; ++bq)
#pragma unroll
    for (int kb = 0; kb < 2; ++kb)
      dff[bq][kb] = *reinterpret_cast<const half4*>(&hb[(16*bq + lo)*DSTR + 16*kb + 4*hi]);

  // layer 1: H^T = W1^T @ DEC^T, C-init = bias; hv[a][bq] is layer-2 B-frag (kb=a)
  half4 hv[4][4];
#pragma unroll
  for (int a = 0; a < 4; ++a){
    f32x4 zb = *reinterpret_cast<const f32x4*>(&b1s[16*a + 4*hi]);
#pragma unroll
    for (int bq = 0; bq < 4; ++bq){
      f32x4 z = __builtin_amdgcn_mfma_f32_16x16x16f16(w1f[a][0], dff[bq][0], zb, 0, 0, 0);
      z       = __builtin_amdgcn_mfma_f32_16x16x16f16(w1f[a][1], dff[bq][1], z,  0, 0, 0);
      half4 hvv;
#pragma unroll
      for (int p = 0; p < 4; ++p) hvv[p] = (f16)gelu_f(z[p]);
      hv[a][bq] = hvv;
    }
  }

  // layer 2 + 3: G^T = W2^T @ H^T (4 chained K=16), gelu + partial W3 dots in regs
  float part[4][3];
#pragma unroll
  for (int bq = 0; bq < 4; ++bq){ part[bq][0]=0.f; part[bq][1]=0.f; part[bq][2]=0.f; }

#pragma unroll
  for (int a2 = 0; a2 < 4; ++a2){
    half4 w2f[4];
#pragma unroll
    for (int kb = 0; kb < 4; ++kb)
      w2f[kb] = *reinterpret_cast<const half4*>(&w2t[(16*a2 + lo)*W2STR + 16*kb + 4*hi]);
    f32x4 zb2 = *reinterpret_cast<const f32x4*>(&b2s[16*a2 + 4*hi]);
#pragma unroll
    for (int bq = 0; bq < 4; ++bq){
      f32x4 z = __builtin_amdgcn_mfma_f32_16x16x16f16(w2f[0], hv[0][bq], zb2, 0, 0, 0);
      z       = __builtin_amdgcn_mfma_f32_16x16x16f16(w2f[1], hv[1][bq], z,   0, 0, 0);
      z       = __builtin_amdgcn_mfma_f32_16x16x16f16(w2f[2], hv[2][bq], z,   0, 0, 0);
      z       = __builtin_amdgcn_mfma_f32_16x16x16f16(w2f[3], hv[3][bq], z,   0, 0, 0);
#pragma unroll
      for (int p = 0; p < 4; ++p){
        f32x4 w3v = *reinterpret_cast<const f32x4*>(&w3s[(16*a2 + 4*hi + p)*4]);
        float g = gelu_f(z[p]);
        part[bq][0] = fmaf(g, w3v[0], part[bq][0]);
        part[bq][1] = fmaf(g, w3v[1], part[bq][1]);
        part[bq][2] = fmaf(g, w3v[2], part[bq][2]);
      }
    }
  }

  // reduce partials across the 4 quad-groups (lanes lo+16*hi')
#pragma unroll
  for (int bq = 0; bq < 4; ++bq)
#pragma unroll
    for (int cc = 0; cc < 3; ++cc){
      float v = part[bq][cc];
      v += __shfl_xor(v, 16, 64);
      v += __shfl_xor(v, 32, 64);
      part[bq][cc] = v;
    }

  // lane L owns query q* = 16*hi + lo = L  -> select bq == hi (static select chain)
  float o0 = (hi==0) ? part[0][0] : (hi==1) ? part[1][0] : (hi==2) ? part[2][0] : part[3][0];
  float o1 = (hi==0) ? part[0][1] : (hi==1) ? part[1][1] : (hi==2) ? part[2][1] : part[3][1];
  float o2 = (hi==0) ? part[0][2] : (hi==1) ? part[1][2] : (hi==2) ? part[2][2] : part[3][2];
  o0 += b3[0]; o1 += b3[1]; o2 += b3[2];

  if (active){
    out[3*m+0] = fminf(fmaxf(un0 + o0, 0.001f), 0.999f);
    out[3*m+1] = fminf(fmaxf(un1 + o1, 0.001f), 0.999f);
    out[3*m+2] = fminf(fmaxf(un2 + o2, 0.001f), 0.999f);
  }
}

// ---------------- fallbacks (ws too small; not used in practice) ----------------
__global__ void __launch_bounds__(256) p2g_atomic_kernel(
    const float* __restrict__ xsr, const float* __restrict__ xsc,
    const float* __restrict__ Wf,  const float* __restrict__ bf,
    float* __restrict__ grid, int N)
{
  int i = blockIdx.x*256 + threadIdx.x;
  if (i >= N) return;
  float sx,sy,sz,dx,dy,dz; int bx,by,bz;
  particle_cell(xsr,i,sx,sy,sz,bx,by,bz,dx,dy,dz);
  float ux = xsc[3*i+0] - sx;
  float uy = xsc[3*i+1] - sy;
  float uz = xsc[3*i+2] - sz;
  float f0 = gelu_f(ux*Wf[0] + uy*Wf[3] + uz*Wf[6] + bf[0]);
  float f1 = gelu_f(ux*Wf[1] + uy*Wf[4] + uz*Wf[7] + bf[1]);
  float f2 = gelu_f(ux*Wf[2] + uy*Wf[5] + uz*Wf[8] + bf[2]);
  float ex = 1.0f - dx, ey = 1.0f - dy, ez = 1.0f - dz;
  auto splat = [&](int xi, int yi, int zi, float w){
    float* p = grid + ((size_t)((((xi<<7)+yi)<<7)+zi) << 3);
    unsafeAtomicAdd(p+0, f0*w);
    unsafeAtomicAdd(p+1, f1*w);
    unsafeAtomicAdd(p+2, f2*w);
    unsafeAtomicAdd(p+3, w);
    unsafeAtomicAdd(p+4, ux*w);
    unsafeAtomicAdd(p+5, uy*w);
    unsafeAtomicAdd(p+6, uz*w);
  };
  splat(bx,  by,  bz,   ex*ey*ez);
  splat(bx,  by,  bz+1, ex*ey*dz);
  splat(bx,  by+1,bz,   ex*dy*ez);
  splat(bx,  by+1,bz+1, ex*dy*dz);
  splat(bx+1,by,  bz,   dx*ey*ez);
  splat(bx+1,by,  bz+1, dx*ey*dz);
  splat(bx+1,by+1,bz,   dx*dy*ez);
  splat(bx+1,by+1,bz+1, dx*dy*dz);
}

// fallback: convert f32 grid (8 floats/cell, unscaled) -> packed f16 grid
__global__ void __launch_bounds__(256) grid2half_kernel(
    const float* __restrict__ grid, uint4* __restrict__ gridh){
  int i = blockIdx.x*256 + threadIdx.x;   // NCELLS threads
  const float4* p = reinterpret_cast<const float4*>(grid + ((size_t)i << 3));
  float4 A = p[0], B = p[1];
  uint4 g;
  g.x = pack2h_scaled(A.x, A.y);
  g.y = pack2h_scaled(A.z, B.x);
  g.z = pack2h_scaled(B.y, B.z);
  g.w = __float_as_uint(A.w);
  gridh[i] = g;
}

__global__ void __launch_bounds__(256) qident_kernel(
    const float* __restrict__ xq, float4* __restrict__ qpk, int M){
  int i = blockIdx.x*256 + threadIdx.x;
  if (i >= M) return;
  float qx01 = fminf(fmaxf(xq[3*i+0], 0.0f), 1.0f);
  float qy01 = fminf(fmaxf(xq[3*i+1], 0.0f), 1.0f);
  float qz01 = fminf(fmaxf(xq[3*i+2], 0.0f), 1.0f);
  qpk[i] = make_float4(qx01, qy01, qz01, __int_as_float(i));
}

extern "C" void kernel_launch(void* const* d_in, const int* in_sizes, int n_in,
                              void* d_out, int out_size, void* d_ws, size_t ws_size,
                              hipStream_t stream)
{
  const float* xq  = (const float*)d_in[0];
  const float* xsr = (const float*)d_in[1];
  const float* xsc = (const float*)d_in[2];
  const float* Wf  = (const float*)d_in[3];
  const float* bf  = (const float*)d_in[4];
  const float* W1  = (const float*)d_in[5];
  const float* b1  = (const float*)d_in[6];
  const float* W2  = (const float*)d_in[7];
  const float* b2  = (const float*)d_in[8];
  const float* W3  = (const float*)d_in[9];
  const float* b3  = (const float*)d_in[10];
  float* out  = (float*)d_out;
  int M = in_sizes[0]/3;
  int N = in_sizes[1]/3;

  // workspace layout (256B-aligned chunks); cnt and qcnt adjacent -> single memset.
  // qpk placed BEFORE cnt so the fallback's 32MB gridh (at o_cnt) doesn't alias it.
  char* W = (char*)d_ws;
  size_t off = 0;
  auto alloc = [&](size_t bytes){ size_t o = off; off = (off + bytes + 255) & ~(size_t)255; return o; };
  size_t o_grid   = alloc((size_t)NCELLS * 8 * sizeof(float));   // 64 MiB (f32 fallback; main uses first 32 MiB as f16 grid)
  size_t o_qpk    = alloc((size_t)M * sizeof(float4));           // 8 MB
  size_t o_cnt    = alloc((size_t)NCELLS * sizeof(int));         // 8 MiB
  size_t o_qcnt   = alloc((size_t)NQBINS * sizeof(int));         // 128 KB (directly after cnt)
  size_t o_offs   = alloc(((size_t)NCELLS + 1) * sizeof(int));   // 8 MiB
  size_t o_cursor = alloc((size_t)NCELLS * sizeof(int));         // 8 MiB
  size_t o_bsum   = alloc((size_t)(SCAN_BLOCKS + 1) * sizeof(int));
  size_t o_qcur   = alloc((size_t)NQBINS * sizeof(int));         // 128 KB
  size_t o_pp     = alloc((size_t)N * sizeof(half8));            // 8 MB packed payload
  size_t o_pz     = alloc((size_t)N * sizeof(float));            // 2 MB
  size_t full_end = off;

  float*  grid   = (float*)(W + o_grid);
  float4* qpk    = (float4*)(W + o_qpk);
  int*    cnt    = (int*)(W + o_cnt);
  int*    qcnt   = (int*)(W + o_qcnt);
  int*    offs   = (int*)(W + o_offs);
  int*    cursor = (int*)(W + o_cursor);
  int*    bsum   = (int*)(W + o_bsum);
  int*    qcur   = (int*)(W + o_qcur);
  half8*  pp     = (half8*)(W + o_pp);
  float*  pz     = (float*)(W + o_pz);

  int nthr = (N > M) ? N : M;
  int nblkNM = (nthr + 255) / 256;
  uint4* gridh;

  if (full_end <= ws_size) {
    gridh = (uint4*)(W + o_grid);   // 32 MiB packed f16 grid in the grid region
    hipMemsetAsync(cnt, 0, (size_t)NCELLS * sizeof(int) + (size_t)NQBINS * sizeof(int), stream);
    hist2_kernel<<<nblkNM, 256, 0, stream>>>(xsr, xq, cnt, qcnt, N, M);
    scan1_kernel<<<SCAN_BLOCKS, 256, 0, stream>>>(cnt, offs, bsum);
    scan2q_kernel<<<1, 1024, 0, stream>>>(bsum, qcnt, qcur);
    scan3_kernel<<<NCELLS/256, 256, 0, stream>>>(offs, bsum, cursor);
    scatter2_kernel<<<nblkNM, 256, 0, stream>>>(xsr, xsc, Wf, bf, xq, cursor, qcur,
                                                pp, pz, qpk, N, M);
    p2g_gather_pair_kernel<<<(NCELLS/2)/256, 256, 0, stream>>>(offs, pp, pz, gridh);
  } else {
    // fallback: f32 atomic grid (o_grid), then convert into the scan-buffer region
    // (cnt..pz spans ~34 MB contiguous, unused on this path)
    gridh = (uint4*)(W + o_cnt);
    hipMemsetAsync(grid, 0, (size_t)NCELLS * 8 * sizeof(float), stream);
    p2g_atomic_kernel<<<(N+255)/256, 256, 0, stream>>>(xsr, xsc, Wf, bf, grid, N);
    grid2half_kernel<<<NCELLS/256, 256, 0, stream>>>(grid, gridh);
    qident_kernel<<<(M+255)/256, 256, 0, stream>>>(xq, qpk, M);
  }

  int nblk = (M + 255) / 256;
  gather_mlp_sorted_kernel<<<nblk, 256, 0, stream>>>(qpk, gridh, W1,b1,W2,b2,W3,b3, out, M, nblk);
}

// Round 9
// 373.854 us; speedup vs baseline: 2.8657x; 1.0194x over previous
//
#include <hip/hip_runtime.h>
#include <cstdint>

#ifndef JAX_PARTITIONABLE
#define JAX_PARTITIONABLE 1   // modern JAX (>=0.5) default threefry_partitionable
#endif

#define NCELLS (128*128*128)          // 2,097,152
#define SCAN_BLOCKS 1024              // NCELLS / 2048
#define NQBINS (32*32*32)             // coarse query bins (4x4x4 cells each)

typedef _Float16 f16;
typedef f16  half8 __attribute__((ext_vector_type(8)));
typedef f16  half4 __attribute__((ext_vector_type(4)));
typedef float f32x4 __attribute__((ext_vector_type(4)));

#define WSTR 40   // row stride (halfs) for [64][32] W1^T tile
#define DSTR 40   // row stride (halfs) for per-wave [64][32] DEC tile
#define W2STR 72  // row stride (halfs) for [64][64] W2^T tile

// Packed grid cell (16B): u32[0]=(f0,f1) u32[1]=(f2,u0) u32[2]=(u1,u2) as f16 x1024;
// u32[3] = d in f32. d stays f32: the dmean>1e-5 mask boundary amplifies
// d-perturbations (round-2 lesson class). x1024 (exact pow2) lifts f/u out of f16
// subnormals and cancels exactly via sfu = s/1024.
// NOTE (round-7 lesson): device-scope atomics on gfx950 write through to HBM
// (~32B/atomic, no L2 accumulation) — never use atomics as a bulk accumulation path.
#define GRID_SCALE 1024.0f
#define GRID_ISCALE 0.0009765625f

// ---------------- Threefry-2x32, key = (0, 42)  (jax.random.key(42)) ----------------
__device__ __forceinline__ uint32_t rotl32(uint32_t v, int s){ return (v << s) | (v >> (32 - s)); }

__device__ __forceinline__ void tf2x32(uint32_t& x0, uint32_t& x1){
  const uint32_t k0 = 0u, k1 = 42u;
  const uint32_t k2 = 0x1BD11BDAu ^ k0 ^ k1;
  x0 += k0; x1 += k1;
#define TFR(r) { x0 += x1; x1 = rotl32(x1,(r)); x1 ^= x0; }
  TFR(13) TFR(15) TFR(26) TFR(6)
  x0 += k1; x1 += k2 + 1u;
  TFR(17) TFR(29) TFR(16) TFR(24)
  x0 += k2; x1 += k0 + 2u;
  TFR(13) TFR(15) TFR(26) TFR(6)
  x0 += k0; x1 += k1 + 3u;
  TFR(17) TFR(29) TFR(16) TFR(24)
  x0 += k1; x1 += k2 + 4u;
  TFR(13) TFR(15) TFR(26) TFR(6)
  x0 += k2; x1 += k0 + 5u;
#undef TFR
}

// XLA f32 ErfInv (Giles) — exact coefficient match with jax/XLA.
// NOTE: must stay BIT-EXACT (log1pf, not a log2 rewrite): noise feeds
// f_norm = r0/max(r3,1e-5), whose derivative -f_norm/r3 amplifies ~1e-6
// noise shifts to ~1e-2 output error in sparse regions (round-2 fail).
__device__ __forceinline__ float erfinv_xla(float x){
  float w = -log1pf(-x*x);
  float p;
  if (w < 5.0f){
    w -= 2.5f;
    p =  2.81022636e-08f;
    p = fmaf(p,w, 3.43273939e-07f);
    p = fmaf(p,w,-3.5233877e-06f);
    p = fmaf(p,w,-4.39150654e-06f);
    p = fmaf(p,w, 0.00021858087f);
    p = fmaf(p,w,-0.00125372503f);
    p = fmaf(p,w,-0.00417768164f);
    p = fmaf(p,w, 0.246640727f);
    p = fmaf(p,w, 1.50140941f);
  } else {
    w = sqrtf(w) - 3.0f;
    p = -0.000200214257f;
    p = fmaf(p,w, 0.000100950558f);
    p = fmaf(p,w, 0.00134934322f);
    p = fmaf(p,w,-0.00367342844f);
    p = fmaf(p,w, 0.00573950773f);
    p = fmaf(p,w,-0.0076224613f);
    p = fmaf(p,w, 0.00943887047f);
    p = fmaf(p,w, 1.00167406f);
    p = fmaf(p,w, 2.83297682f);
  }
  return p*x;
}

// noise[i] = 0.8 * sqrt(2)*erfinv(uniform(-1,1)) with jax bit semantics
__device__ __forceinline__ float noise_at(uint32_t idx, uint32_t half){
#if JAX_PARTITIONABLE
  (void)half;
  uint32_t x0 = 0u, x1 = idx;     // counter = (hi=0, lo=i)
  tf2x32(x0, x1);
  uint32_t bits = x0 ^ x1;        // partitionable 32-bit path: xor-fold of both words
#else
  uint32_t j  = (idx < half) ? idx : (idx - half);
  uint32_t x0 = j, x1 = j + half;
  tf2x32(x0, x1);
  uint32_t bits = (idx < half) ? x0 : x1;
#endif
  float f = __uint_as_float((bits >> 9) | 0x3f800000u) - 1.0f;      // [0,1)
  float u = fmaxf(-0.99999994f, fmaf(f, 2.0f, -0.99999994f));       // (-1,1)
  return (1.41421356f * erfinv_xla(u)) * 0.8f;
}

// jax.nn.gelu approximate=True — minimal-op form (round-6 verified; the round-8
// exp2f rewrite used the PRECISE ocml entry and regressed — keep __expf).
__device__ __forceinline__ float gelu_f(float x){
  float t = x*x;
  float inner = x * fmaf(0.035677408136f, t, 0.7978845608028654f);
  float e = __expf(2.0f * inner);
  float r = __builtin_amdgcn_rcpf(e + 1.0f);
  return x - x*r;
}

__device__ __forceinline__ uint32_t pack2h_scaled(float a, float b){
  union { f16 h[2]; uint32_t u; } c;
  c.h[0] = (f16)(a * GRID_SCALE);
  c.h[1] = (f16)(b * GRID_SCALE);
  return c.u;
}
__device__ __forceinline__ uint32_t pack2h_raw(float a, float b){
  union { f16 h[2]; uint32_t u; } c;
  c.h[0] = (f16)a;
  c.h[1] = (f16)b;
  return c.u;
}

// common per-particle geometry
__device__ __forceinline__ void particle_cell(const float* xsr, int i,
                                              float& sx, float& sy, float& sz,
                                              int& bx, int& by, int& bz,
                                              float& dx, float& dy, float& dz){
  sx = fminf(fmaxf(xsr[3*i+0], 0.0f), 1.0f);
  sy = fminf(fmaxf(xsr[3*i+1], 0.0f), 1.0f);
  sz = fminf(fmaxf(xsr[3*i+2], 0.0f), 1.0f);
  float cx = fminf(fmaxf(sx*127.0f, 0.0f), 126.999f);
  float cy = fminf(fmaxf(sy*127.0f, 0.0f), 126.999f);
  float cz = fminf(fmaxf(sz*127.0f, 0.0f), 126.999f);
  float bxf = floorf(cx), byf = floorf(cy), bzf = floorf(cz);
  bx = (int)bxf; by = (int)byf; bz = (int)bzf;
  dx = cx - bxf; dy = cy - byf; dz = cz - bzf;
}

__device__ __forceinline__ int qbin_of(float qx01, float qy01, float qz01){
  int bx = min((int)(qx01*127.0f), 127) >> 2;
  int by = min((int)(qy01*127.0f), 127) >> 2;
  int bz = min((int)(qz01*127.0f), 127) >> 2;
  return (((bx<<5)+by)<<5)+bz;
}

// ---------------- fused histogram: particle cells + query coarse bins ----------------
__global__ void __launch_bounds__(256) hist2_kernel(
    const float* __restrict__ xsr, const float* __restrict__ xq,
    int* __restrict__ cells, int* __restrict__ qcnt, int N, int M){
  int i = blockIdx.x*256 + threadIdx.x;
  if (i < N){
    float sx,sy,sz,dx,dy,dz; int bx,by,bz;
    particle_cell(xsr,i,sx,sy,sz,bx,by,bz,dx,dy,dz);
    atomicAdd(&cells[(((bx<<7)+by)<<7)+bz], 1);
  }
  if (i < M){
    float qx01 = fminf(fmaxf(xq[3*i+0], 0.0f), 1.0f);
    float qy01 = fminf(fmaxf(xq[3*i+1], 0.0f), 1.0f);
    float qz01 = fminf(fmaxf(xq[3*i+2], 0.0f), 1.0f);
    atomicAdd(&qcnt[qbin_of(qx01,qy01,qz01)], 1);
  }
}

// scan stage 1, IN-PLACE: cells[i] (counts) -> per-block-local exclusive scans;
// bsum[blk] = block total. Safe in place: each thread reads/writes only its own 8.
__global__ void __launch_bounds__(256) scan1_kernel(int* __restrict__ cells,
                                                    int* __restrict__ bsum){
  __shared__ int lds[256];
  int t = threadIdx.x;
  int base = blockIdx.x*2048 + t*8;
  const int4* c4 = reinterpret_cast<const int4*>(cells + base);
  int4 a0 = c4[0], a1 = c4[1];
  int s = a0.x+a0.y+a0.z+a0.w + a1.x+a1.y+a1.z+a1.w;
  lds[t] = s; __syncthreads();
  for (int off = 1; off < 256; off <<= 1){
    int v = (t >= off) ? lds[t-off] : 0;
    __syncthreads();
    lds[t] += v;
    __syncthreads();
  }
  int run = lds[t] - s;
  if (t == 255) bsum[blockIdx.x] = lds[255];
  int* o = cells + base;
  o[0]=run; run+=a0.x; o[1]=run; run+=a0.y; o[2]=run; run+=a0.z; o[3]=run; run+=a0.w;
  o[4]=run; run+=a1.x; o[5]=run; run+=a1.y; o[6]=run; run+=a1.z; o[7]=run;
}

// fused: exclusive scan of bsum (particle block sums) + full exclusive scan of qcnt
__global__ void __launch_bounds__(1024) scan2q_kernel(int* __restrict__ bsum,
                                                      const int* __restrict__ qcnt,
                                                      int* __restrict__ qcur){
  __shared__ int lds[1024];
  int t = threadIdx.x;
  int v = bsum[t];
  lds[t] = v; __syncthreads();
  for (int off = 1; off < 1024; off <<= 1){
    int u = (t >= off) ? lds[t-off] : 0;
    __syncthreads();
    lds[t] += u;
    __syncthreads();
  }
  bsum[t] = lds[t] - v;
  __syncthreads();
  int base = t*32;
  int loc[32];
  int s = 0;
#pragma unroll
  for (int j = 0; j < 32; ++j){ loc[j] = qcnt[base+j]; s += loc[j]; }
  lds[t] = s; __syncthreads();
  for (int off = 1; off < 1024; off <<= 1){
    int u = (t >= off) ? lds[t-off] : 0;
    __syncthreads();
    lds[t] += u;
    __syncthreads();
  }
  int run = lds[t] - s;
#pragma unroll
  for (int j = 0; j < 32; ++j){ qcur[base+j] = run; run += loc[j]; }
}

// fused scatter: packed f16 particle payload bump-alloc + query float4 stash.
// Position = atomicAdd on the local-scan cells[] + bsum[blk] in-register
// (scan3 pass + cursor array eliminated). After this kernel:
//   cells[b] = local_excl[b] + cnt[b], so E(b) := cells[b]+bsum[b>>11] = global END of bin b.
__global__ void __launch_bounds__(256) scatter2_kernel(
    const float* __restrict__ xsr, const float* __restrict__ xsc,
    const float* __restrict__ Wf,  const float* __restrict__ bf,
    const float* __restrict__ xq,
    int* __restrict__ cells, const int* __restrict__ bsum, int* __restrict__ qcur,
    half8* __restrict__ pp, float* __restrict__ pz,
    float4* __restrict__ qpk, int N, int M){
  int i = blockIdx.x*256 + threadIdx.x;
  if (i < N){
    float sx,sy,sz,dx,dy,dz; int bx,by,bz;
    particle_cell(xsr,i,sx,sy,sz,bx,by,bz,dx,dy,dz);
    float ux = xsc[3*i+0] - sx;
    float uy = xsc[3*i+1] - sy;
    float uz = xsc[3*i+2] - sz;
    float f0 = gelu_f(ux*Wf[0] + uy*Wf[3] + uz*Wf[6] + bf[0]);
    float f1 = gelu_f(ux*Wf[1] + uy*Wf[4] + uz*Wf[7] + bf[1]);
    float f2 = gelu_f(ux*Wf[2] + uy*Wf[5] + uz*Wf[8] + bf[2]);
    int bin = (((bx<<7)+by)<<7)+bz;
    int pos = atomicAdd(&cells[bin], 1) + bsum[bin >> 11];
    half8 ph;
    ph[0] = (f16)(f0*GRID_SCALE); ph[1] = (f16)(f1*GRID_SCALE); ph[2] = (f16)(f2*GRID_SCALE);
    ph[3] = (f16)(ux*GRID_SCALE); ph[4] = (f16)(uy*GRID_SCALE); ph[5] = (f16)(uz*GRID_SCALE);
    ph[6] = (f16)dx; ph[7] = (f16)dy;
    pp[pos] = ph;
    pz[pos] = dz;
  }
  if (i < M){
    float qx01 = fminf(fmaxf(xq[3*i+0], 0.0f), 1.0f);
    float qy01 = fminf(fmaxf(xq[3*i+1], 0.0f), 1.0f);
    float qz01 = fminf(fmaxf(xq[3*i+2], 0.0f), 1.0f);
    int pos = atomicAdd(&qcur[qbin_of(qx01,qy01,qz01)], 1);
    qpk[pos] = make_float4(qx01, qy01, qz01, __int_as_float(i));
  }
}

// z-pair per-cell gather (packed f16 payload) -> packed f16 grid (16B/cell).
// Bin ranges reconstructed from bumped cells[] + bsum[]:
//   E(b) = cells[b]+bsum[b>>11] = end(b) = start(b+1);  start(b0)=E(b0-1) (b0>0 else 0).
//   sm = start(b0-1) = E(b0-2)  [z0>0 => b0>=2];  em = start(b0);  e0 = E(b0);  e1 = E(b0+1).
__global__ void __launch_bounds__(256) p2g_gather_pair_kernel(
    const int* __restrict__ cells, const int* __restrict__ bsum,
    const half8* __restrict__ pp, const float* __restrict__ pz,
    uint4* __restrict__ gridh){
  int tid = blockIdx.x*256 + threadIdx.x;   // exactly NCELLS/2 threads
  int zg = tid & 63, y = (tid >> 6) & 127, x = tid >> 13;
  int z0 = zg << 1;
  auto E = [&](int b){ return cells[b] + bsum[b >> 11]; };
  float a0[2]={0,0},a1[2]={0,0},a2[2]={0,0},a3[2]={0,0},a4[2]={0,0},a5[2]={0,0},a6[2]={0,0};
#pragma unroll
  for (int ox = 0; ox < 2; ++ox){
    int bx = x - ox; if (bx < 0) continue;
#pragma unroll
    for (int oy = 0; oy < 2; ++oy){
      int by = y - oy; if (by < 0) continue;
      int b0 = ((((bx<<7)+by)<<7)) + z0;
      int em = (b0 > 0) ? E(b0-1) : 0;
      int sm = (z0 > 0) ? E(b0-2) : em;
      int e0 = E(b0);
      int e1 = E(b0+1);
      for (int p = sm; p < e1; ++p){
        half8 P = pp[p]; float dz = pz[p];
        float pdx = (float)P[6], pdy = (float)P[7];
        float wx = ox ? pdx : 1.0f - pdx;
        float wy = oy ? pdy : 1.0f - pdy;
        float wxy = wx*wy;
        float omdz = 1.0f - dz;
        float w0 = (p < em) ? dz : ((p < e0) ? omdz : 0.0f);
        float w1 = (p < em) ? 0.0f : ((p < e0) ? dz : omdz);
        w0 *= wxy; w1 *= wxy;
        float v0=(float)P[0], v1=(float)P[1], v2=(float)P[2];
        float v3=(float)P[3], v4=(float)P[4], v5=(float)P[5];
        a0[0]=fmaf(v0,w0,a0[0]); a1[0]=fmaf(v1,w0,a1[0]); a2[0]=fmaf(v2,w0,a2[0]);
        a3[0]+=w0; a4[0]=fmaf(v3,w0,a4[0]); a5[0]=fmaf(v4,w0,a5[0]); a6[0]=fmaf(v5,w0,a6[0]);
        a0[1]=fmaf(v0,w1,a0[1]); a1[1]=fmaf(v1,w1,a1[1]); a2[1]=fmaf(v2,w1,a2[1]);
        a3[1]+=w1; a4[1]=fmaf(v3,w1,a4[1]); a5[1]=fmaf(v4,w1,a5[1]); a6[1]=fmaf(v5,w1,a6[1]);
      }
    }
  }
  int cell0 = ((((x<<7)+y)<<7)) + z0;
  uint4 g0, g1;
  g0.x = pack2h_raw(a0[0], a1[0]); g0.y = pack2h_raw(a2[0], a4[0]);
  g0.z = pack2h_raw(a5[0], a6[0]); g0.w = __float_as_uint(a3[0]);
  g1.x = pack2h_raw(a0[1], a1[1]); g1.y = pack2h_raw(a2[1], a4[1]);
  g1.z = pack2h_raw(a5[1], a6[1]); g1.w = __float_as_uint(a3[1]);
  uint4* g = gridh + cell0;
  g[0] = g0; g[1] = g1;
}

// ---------------- fused gather + MFMA MLP (K=16 chained, f16 grid) ----------------
// Verified round 6: 135 us, VALUBusy 86%, FETCH 26.5 MB — issue-bound.
__global__ void __launch_bounds__(256, 4) gather_mlp_sorted_kernel(
    const float4* __restrict__ qpk,
    const uint4* __restrict__ gridh,
    const float* __restrict__ W1,  const float* __restrict__ b1,
    const float* __restrict__ W2,  const float* __restrict__ b2,
    const float* __restrict__ W3,  const float* __restrict__ b3,
    float* __restrict__ out, int M, int nblk)
{
  __shared__ __align__(16) f16  decs[4][64*DSTR]; // per-wave DEC^T [q][k<=32], 20 KB
  __shared__ __align__(16) f16  w1t[64*WSTR];     // W1^T [o][k], k padded 24->32, 5 KB
  __shared__ __align__(16) f16  w2t[64*W2STR];    // W2^T [o][k], 9 KB
  __shared__ __align__(16) float b1s[64], b2s[64];
  __shared__ __align__(16) float w3s[64*4];       // W3 rows padded to 4 floats, 1 KB

  // stage weights (block-cooperative)
  for (int i = threadIdx.x; i < 64*32; i += 256){
    int n = i >> 5, k = i & 31;
    w1t[n*WSTR + k] = (k < 24) ? (f16)W1[k*64 + n] : (f16)0.0f;
  }
  for (int i = threadIdx.x; i < 64*64; i += 256){
    int n = i >> 6, k = i & 63;
    w2t[n*W2STR + k] = (f16)W2[k*64 + n];
  }
  if (threadIdx.x < 64){ b1s[threadIdx.x] = b1[threadIdx.x]; b2s[threadIdx.x] = b2[threadIdx.x]; }
  for (int i = threadIdx.x; i < 192; i += 256){
    w3s[(i/3)*4 + (i - (i/3)*3)] = W3[i];
  }
  __syncthreads();

  int b = blockIdx.x;
  int nb8 = (nblk >> 3) << 3;
  int c = (b < nb8) ? ((b & 7)*(nblk >> 3) + (b >> 3)) : b;   // XCD-contiguous chunks
  int t = c*256 + (int)threadIdx.x;
  bool active = (t < M);
  int tc = active ? t : (M - 1);

  float4 qv = qpk[tc];
  float qx01 = qv.x, qy01 = qv.y, qz01 = qv.z;
  int m = __float_as_int(qv.w);
  float qx = qx01*127.0f, qy = qy01*127.0f, qz = qz01*127.0f;

  // ---- gather: 8 MC paths, trilerp over packed f16 grid ----
  float r0=0.f,r1=0.f,r2=0.f,r3=0.f,r4=0.f,r5=0.f,r6=0.f;
  const uint32_t KSTRIDE = 3u*(uint32_t)M;
  const uint32_t HALF    = 4u*KSTRIDE;
  uint32_t m3 = 3u*(uint32_t)m;

  for (int k = 0; k < 8; ++k) {
    uint32_t base = (uint32_t)k*KSTRIDE + m3;
    float px = qx + noise_at(base+0u, HALF);
    float py = qy + noise_at(base+1u, HALF);
    float pz = qz + noise_at(base+2u, HALF);
    float fxf = floorf(px), fyf = floorf(py), fzf = floorf(pz);
    float fx = px - fxf, fy = py - fyf, fz = pz - fzf;
    int lx = (int)fxf, ly = (int)fyf, lz = (int)fzf;
    int x0i = min(max(lx,0),127),   x1i = min(max(lx+1,0),127);
    int y0i = min(max(ly,0),127),   y1i = min(max(ly+1,0),127);
    int z0i = min(max(lz,0),127),   z1i = min(max(lz+1,0),127);
    float ex = 1.0f-fx, ey = 1.0f-fy, ez = 1.0f-fz;

    auto corner = [&](int xi,int yi,int zi,float w){
      uint4 q4 = gridh[(((xi<<7)+yi)<<7)+zi];
      union { uint32_t u; f16 h[2]; } c0, c1, c2;
      c0.u = q4.x; c1.u = q4.y; c2.u = q4.z;
      r0 = fmaf((float)c0.h[0], w, r0);
      r1 = fmaf((float)c0.h[1], w, r1);
      r2 = fmaf((float)c1.h[0], w, r2);
      r4 = fmaf((float)c1.h[1], w, r4);
      r5 = fmaf((float)c2.h[0], w, r5);
      r6 = fmaf((float)c2.h[1], w, r6);
      r3 = fmaf(__uint_as_float(q4.w), w, r3);
    };
    corner(x0i,y0i,z0i, ex*ey*ez);
    corner(x0i,y0i,z1i, ex*ey*fz);
    corner(x0i,y1i,z0i, ex*fy*ez);
    corner(x0i,y1i,z1i, ex*fy*fz);
    corner(x1i,y0i,z0i, fx*ey*ez);
    corner(x1i,y0i,z1i, fx*ey*fz);
    corner(x1i,y1i,z0i, fx*fy*ez);
    corner(x1i,y1i,z1i, fx*fy*fz);
  }

  // d-channel is f32 -> mask decision window identical to the all-f32 kernel
  float dmean = r3*0.125f;
  float denom = fmaxf(dmean, 1e-5f);
  float maskf = (dmean > 1e-5f) ? 1.0f : 0.0f;
  float s   = 0.125f/denom*maskf;
  float sfu = s * GRID_ISCALE;   // exact /1024 for the scaled f16 channels
  float un0 = r4*sfu, un1 = r5*sfu, un2 = r6*sfu;

  float dec[24];
  dec[0]=r0*sfu; dec[1]=r1*sfu; dec[2]=r2*sfu; dec[3]=un0; dec[4]=un1; dec[5]=un2;
  dec[6]  = __builtin_amdgcn_sinf(0.5f*qx01);   // v_sin input is revolutions
  dec[7]  = __builtin_amdgcn_sinf(0.5f*qy01);
  dec[8]  = __builtin_amdgcn_sinf(0.5f*qz01);
  dec[9]  = __builtin_amdgcn_cosf(0.5f*qx01);
  dec[10] = __builtin_amdgcn_cosf(0.5f*qy01);
  dec[11] = __builtin_amdgcn_cosf(0.5f*qz01);
  dec[12] = __builtin_amdgcn_sinf(qx01);
  dec[13] = __builtin_amdgcn_sinf(qy01);
  dec[14] = __builtin_amdgcn_sinf(qz01);
  dec[15] = __builtin_amdgcn_cosf(qx01);
  dec[16] = __builtin_amdgcn_cosf(qy01);
  dec[17] = __builtin_amdgcn_cosf(qz01);
  dec[18] = __builtin_amdgcn_sinf(2.0f*qx01);
  dec[19] = __builtin_amdgcn_sinf(2.0f*qy01);
  dec[20] = __builtin_amdgcn_sinf(2.0f*qz01);
  dec[21] = __builtin_amdgcn_cosf(2.0f*qx01);
  dec[22] = __builtin_amdgcn_cosf(2.0f*qy01);
  dec[23] = __builtin_amdgcn_cosf(2.0f*qz01);

  // ---- MLP via chained 16x16x16 MFMAs (verified rounds 5/6) ----
  int lane = threadIdx.x & 63;
  int wv   = threadIdx.x >> 6;
  f16* hb = &decs[wv][0];
  int lo = lane & 15;           // C col / frag m-n index
  int hi = lane >> 4;           // quad id: frag k base = 4*hi; C row base = 4*hi

  // stage dec (fp16, k padded to 32) into hb[row=lane][k]: 4x b128
  {
    half8 dh;
#pragma unroll
    for (int c4 = 0; c4 < 3; ++c4){
#pragma unroll
      for (int j = 0; j < 8; ++j) dh[j] = (f16)dec[c4*8 + j];
      *reinterpret_cast<half8*>(&hb[lane*DSTR + c4*8]) = dh;
    }
#pragma unroll
    for (int j = 0; j < 8; ++j) dh[j] = (f16)0.0f;
    *reinterpret_cast<half8*>(&hb[lane*DSTR + 24]) = dh;
  }

  half4 w1f[4][2];
#pragma unroll
  for (int a = 0; a < 4; ++a)
#pragma unroll
    for (int kb = 0; kb < 2; ++kb)
      w1f[a][kb] = *reinterpret_cast<const half4*>(&w1t[(16*a + lo)*WSTR + 16*kb + 4*hi]);

  half4 dff[4][2];
#pragma unroll
  for (int bq = 0; bq < 4; ++bq)
#pragma unroll
    for (int kb = 0; kb < 2; ++kb)
      dff[bq][kb] = *reinterpret_cast<const half4*>(&hb[(16*bq + lo)*DSTR + 16*kb + 4*hi]);

  // layer 1: H^T = W1^T @ DEC^T, C-init = bias; hv[a][bq] is layer-2 B-frag (kb=a)
  half4 hv[4][4];
#pragma unroll
  for (int a = 0; a < 4; ++a){
    f32x4 zb = *reinterpret_cast<const f32x4*>(&b1s[16*a + 4*hi]);
#pragma unroll
    for (int bq = 0; bq < 4; ++bq){
      f32x4 z = __builtin_amdgcn_mfma_f32_16x16x16f16(w1f[a][0], dff[bq][0], zb, 0, 0, 0);
      z       = __builtin_amdgcn_mfma_f32_16x16x16f16(w1f[a][1], dff[bq][1], z,  0, 0, 0);
      half4 hvv;
#pragma unroll
      for (int p = 0; p < 4; ++p) hvv[p] = (f16)gelu_f(z[p]);
      hv[a][bq] = hvv;
    }
  }

  // layer 2 + 3: G^T = W2^T @ H^T (4 chained K=16), gelu + partial W3 dots in regs
  float part[4][3];
#pragma unroll
  for (int bq = 0; bq < 4; ++bq){ part[bq][0]=0.f; part[bq][1]=0.f; part[bq][2]=0.f; }

#pragma unroll
  for (int a2 = 0; a2 < 4; ++a2){
    half4 w2f[4];
#pragma unroll
    for (int kb = 0; kb < 4; ++kb)
      w2f[kb] = *reinterpret_cast<const half4*>(&w2t[(16*a2 + lo)*W2STR + 16*kb + 4*hi]);
    f32x4 zb2 = *reinterpret_cast<const f32x4*>(&b2s[16*a2 + 4*hi]);
#pragma unroll
    for (int bq = 0; bq < 4; ++bq){
      f32x4 z = __builtin_amdgcn_mfma_f32_16x16x16f16(w2f[0], hv[0][bq], zb2, 0, 0, 0);
      z       = __builtin_amdgcn_mfma_f32_16x16x16f16(w2f[1], hv[1][bq], z,   0, 0, 0);
      z       = __builtin_amdgcn_mfma_f32_16x16x16f16(w2f[2], hv[2][bq], z,   0, 0, 0);
      z       = __builtin_amdgcn_mfma_f32_16x16x16f16(w2f[3], hv[3][bq], z,   0, 0, 0);
#pragma unroll
      for (int p = 0; p < 4; ++p){
        f32x4 w3v = *reinterpret_cast<const f32x4*>(&w3s[(16*a2 + 4*hi + p)*4]);
        float g = gelu_f(z[p]);
        part[bq][0] = fmaf(g, w3v[0], part[bq][0]);
        part[bq][1] = fmaf(g, w3v[1], part[bq][1]);
        part[bq][2] = fmaf(g, w3v[2], part[bq][2]);
      }
    }
  }

  // reduce partials across the 4 quad-groups (lanes lo+16*hi')
#pragma unroll
  for (int bq = 0; bq < 4; ++bq)
#pragma unroll
    for (int cc = 0; cc < 3; ++cc){
      float v = part[bq][cc];
      v += __shfl_xor(v, 16, 64);
      v += __shfl_xor(v, 32, 64);
      part[bq][cc] = v;
    }

  // lane L owns query q* = 16*hi + lo = L  -> select bq == hi (static select chain)
  float o0 = (hi==0) ? part[0][0] : (hi==1) ? part[1][0] : (hi==2) ? part[2][0] : part[3][0];
  float o1 = (hi==0) ? part[0][1] : (hi==1) ? part[1][1] : (hi==2) ? part[2][1] : part[3][1];
  float o2 = (hi==0) ? part[0][2] : (hi==1) ? part[1][2] : (hi==2) ? part[2][2] : part[3][2];
  o0 += b3[0]; o1 += b3[1]; o2 += b3[2];

  if (active){
    out[3*m+0] = fminf(fmaxf(un0 + o0, 0.001f), 0.999f);
    out[3*m+1] = fminf(fmaxf(un1 + o1, 0.001f), 0.999f);
    out[3*m+2] = fminf(fmaxf(un2 + o2, 0.001f), 0.999f);
  }
}

// ---------------- fallbacks (ws too small; not used in practice) ----------------
__global__ void __launch_bounds__(256) p2g_atomic_kernel(
    const float* __restrict__ xsr, const float* __restrict__ xsc,
    const float* __restrict__ Wf,  const float* __restrict__ bf,
    float* __restrict__ grid, int N)
{
  int i = blockIdx.x*256 + threadIdx.x;
  if (i >= N) return;
  float sx,sy,sz,dx,dy,dz; int bx,by,bz;
  particle_cell(xsr,i,sx,sy,sz,bx,by,bz,dx,dy,dz);
  float ux = xsc[3*i+0] - sx;
  float uy = xsc[3*i+1] - sy;
  float uz = xsc[3*i+2] - sz;
  float f0 = gelu_f(ux*Wf[0] + uy*Wf[3] + uz*Wf[6] + bf[0]);
  float f1 = gelu_f(ux*Wf[1] + uy*Wf[4] + uz*Wf[7] + bf[1]);
  float f2 = gelu_f(ux*Wf[2] + uy*Wf[5] + uz*Wf[8] + bf[2]);
  float ex = 1.0f - dx, ey = 1.0f - dy, ez = 1.0f - dz;
  auto splat = [&](int xi, int yi, int zi, float w){
    float* p = grid + ((size_t)((((xi<<7)+yi)<<7)+zi) << 3);
    unsafeAtomicAdd(p+0, f0*w);
    unsafeAtomicAdd(p+1, f1*w);
    unsafeAtomicAdd(p+2, f2*w);
    unsafeAtomicAdd(p+3, w);
    unsafeAtomicAdd(p+4, ux*w);
    unsafeAtomicAdd(p+5, uy*w);
    unsafeAtomicAdd(p+6, uz*w);
  };
  splat(bx,  by,  bz,   ex*ey*ez);
  splat(bx,  by,  bz+1, ex*ey*dz);
  splat(bx,  by+1,bz,   ex*dy*ez);
  splat(bx,  by+1,bz+1, ex*dy*dz);
  splat(bx+1,by,  bz,   dx*ey*ez);
  splat(bx+1,by,  bz+1, dx*ey*dz);
  splat(bx+1,by+1,bz,   dx*dy*ez);
  splat(bx+1,by+1,bz+1, dx*dy*dz);
}

// fallback: convert f32 grid (8 floats/cell, unscaled) -> packed f16 grid
__global__ void __launch_bounds__(256) grid2half_kernel(
    const float* __restrict__ grid, uint4* __restrict__ gridh){
  int i = blockIdx.x*256 + threadIdx.x;   // NCELLS threads
  const float4* p = reinterpret_cast<const float4*>(grid + ((size_t)i << 3));
  float4 A = p[0], B = p[1];
  uint4 g;
  g.x = pack2h_scaled(A.x, A.y);
  g.y = pack2h_scaled(A.z, B.x);
  g.z = pack2h_scaled(B.y, B.z);
  g.w = __float_as_uint(A.w);
  gridh[i] = g;
}

__global__ void __launch_bounds__(256) qident_kernel(
    const float* __restrict__ xq, float4* __restrict__ qpk, int M){
  int i = blockIdx.x*256 + threadIdx.x;
  if (i >= M) return;
  float qx01 = fminf(fmaxf(xq[3*i+0], 0.0f), 1.0f);
  float qy01 = fminf(fmaxf(xq[3*i+1], 0.0f), 1.0f);
  float qz01 = fminf(fmaxf(xq[3*i+2], 0.0f), 1.0f);
  qpk[i] = make_float4(qx01, qy01, qz01, __int_as_float(i));
}

extern "C" void kernel_launch(void* const* d_in, const int* in_sizes, int n_in,
                              void* d_out, int out_size, void* d_ws, size_t ws_size,
                              hipStream_t stream)
{
  const float* xq  = (const float*)d_in[0];
  const float* xsr = (const float*)d_in[1];
  const float* xsc = (const float*)d_in[2];
  const float* Wf  = (const float*)d_in[3];
  const float* bf  = (const float*)d_in[4];
  const float* W1  = (const float*)d_in[5];
  const float* b1  = (const float*)d_in[6];
  const float* W2  = (const float*)d_in[7];
  const float* b2  = (const float*)d_in[8];
  const float* W3  = (const float*)d_in[9];
  const float* b3  = (const float*)d_in[10];
  float* out  = (float*)d_out;
  int M = in_sizes[0]/3;
  int N = in_sizes[1]/3;

  // workspace layout: gridh (packed f16) + qpk always live; union region holds
  // EITHER the main path's sort buffers (~18.3 MB) OR the fallback's 64 MB f32 grid.
  char* W = (char*)d_ws;
  size_t off = 0;
  auto alloc = [&](size_t bytes){ size_t o = off; off = (off + bytes + 255) & ~(size_t)255; return o; };
  size_t o_gridh = alloc((size_t)NCELLS * 16);            // 32 MiB packed f16 grid
  size_t o_qpk   = alloc((size_t)M * sizeof(float4));     // 8 MB
  size_t o_union = off;
  // main-path sub-offsets within the union region:
  size_t o_cells = alloc((size_t)NCELLS * sizeof(int));   // 8 MiB (cnt -> local scan -> bumped)
  size_t o_qcnt  = alloc((size_t)NQBINS * sizeof(int));   // 128 KB (directly after cells)
  size_t o_bsum  = alloc((size_t)SCAN_BLOCKS * sizeof(int));
  size_t o_qcur  = alloc((size_t)NQBINS * sizeof(int));   // 128 KB
  size_t o_pp    = alloc((size_t)N * sizeof(half8));      // 8 MB packed payload
  size_t o_pz    = alloc((size_t)N * sizeof(float));      // 2 MB
  size_t main_end = off;
  size_t full_end = (o_union + (size_t)NCELLS * 8 * sizeof(float) > main_end)
                  ? (o_union + (size_t)NCELLS * 8 * sizeof(float)) : main_end;

  uint4*  gridh = (uint4*)(W + o_gridh);
  float4* qpk   = (float4*)(W + o_qpk);
  int*    cells = (int*)(W + o_cells);
  int*    qcnt  = (int*)(W + o_qcnt);
  int*    bsum  = (int*)(W + o_bsum);
  int*    qcur  = (int*)(W + o_qcur);
  half8*  pp    = (half8*)(W + o_pp);
  float*  pz    = (float*)(W + o_pz);
  float*  gridf = (float*)(W + o_union);   // fallback f32 grid (aliases sort buffers)

  int nthr = (N > M) ? N : M;
  int nblkNM = (nthr + 255) / 256;

  if (main_end <= ws_size) {
    hipMemsetAsync(cells, 0, (size_t)NCELLS * sizeof(int) + (size_t)NQBINS * sizeof(int), stream);
    hist2_kernel<<<nblkNM, 256, 0, stream>>>(xsr, xq, cells, qcnt, N, M);
    scan1_kernel<<<SCAN_BLOCKS, 256, 0, stream>>>(cells, bsum);
    scan2q_kernel<<<1, 1024, 0, stream>>>(bsum, qcnt, qcur);
    scatter2_kernel<<<nblkNM, 256, 0, stream>>>(xsr, xsc, Wf, bf, xq, cells, bsum, qcur,
                                                pp, pz, qpk, N, M);
    p2g_gather_pair_kernel<<<(NCELLS/2)/256, 256, 0, stream>>>(cells, bsum, pp, pz, gridh);
  } else {
    // fallback: f32 atomic grid in the union region, convert to packed gridh
    (void)full_end;
    hipMemsetAsync(gridf, 0, (size_t)NCELLS * 8 * sizeof(float), stream);
    p2g_atomic_kernel<<<(N+255)/256, 256, 0, stream>>>(xsr, xsc, Wf, bf, gridf, N);
    grid2half_kernel<<<NCELLS/256, 256, 0, stream>>>(gridf, gridh);
    qident_kernel<<<(M+255)/256, 256, 0, stream>>>(xq, qpk, M);
  }

  int nblk = (M + 255) / 256;
  gather_mlp_sorted_kernel<<<nblk, 256, 0, stream>>>(qpk, gridh, W1,b1,W2,b2,W3,b3, out, M, nblk);
}

// Round 10
// 364.206 us; speedup vs baseline: 2.9416x; 1.0265x over previous
//
#include <hip/hip_runtime.h>
#include <cstdint>

#ifndef JAX_PARTITIONABLE
#define JAX_PARTITIONABLE 1   // modern JAX (>=0.5) default threefry_partitionable
#endif

#define NCELLS (128*128*128)          // 2,097,152
#define SCAN_BLOCKS 1024              // NCELLS / 2048
#define NQBINS (32*32*32)             // coarse query bins (4x4x4 cells each)

typedef _Float16 f16;
typedef f16  half8 __attribute__((ext_vector_type(8)));
typedef f16  half4 __attribute__((ext_vector_type(4)));
typedef float f32x4 __attribute__((ext_vector_type(4)));

#define WSTR 40   // row stride (halfs) for [64][32] W1^T tile
#define DSTR 40   // row stride (halfs) for per-wave [64][32] DEC tile
#define W2STR 72  // row stride (halfs) for [64][64] W2^T tile

// Packed grid cell (16B): u32[0]=(f0,f1) u32[1]=(f2,u0) u32[2]=(u1,u2) as f16 x1024;
// u32[3] = d in f32. d stays f32: the dmean>1e-5 mask boundary amplifies
// d-perturbations (round-2 lesson class). x1024 (exact pow2) lifts f/u out of f16
// subnormals and cancels exactly via sfu = s/1024.
// NOTE (round-7 lesson): device-scope atomics on gfx950 write through to HBM
// (~32B/atomic, no L2 accumulation) — never use atomics as a bulk accumulation path.
#define GRID_SCALE 1024.0f
#define GRID_ISCALE 0.0009765625f

// ---------------- Threefry-2x32, key = (0, 42)  (jax.random.key(42)) ----------------
__device__ __forceinline__ uint32_t rotl32(uint32_t v, int s){ return (v << s) | (v >> (32 - s)); }

__device__ __forceinline__ void tf2x32(uint32_t& x0, uint32_t& x1){
  const uint32_t k0 = 0u, k1 = 42u;
  const uint32_t k2 = 0x1BD11BDAu ^ k0 ^ k1;
  x0 += k0; x1 += k1;
#define TFR(r) { x0 += x1; x1 = rotl32(x1,(r)); x1 ^= x0; }
  TFR(13) TFR(15) TFR(26) TFR(6)
  x0 += k1; x1 += k2 + 1u;
  TFR(17) TFR(29) TFR(16) TFR(24)
  x0 += k2; x1 += k0 + 2u;
  TFR(13) TFR(15) TFR(26) TFR(6)
  x0 += k0; x1 += k1 + 3u;
  TFR(17) TFR(29) TFR(16) TFR(24)
  x0 += k1; x1 += k2 + 4u;
  TFR(13) TFR(15) TFR(26) TFR(6)
  x0 += k2; x1 += k0 + 5u;
#undef TFR
}

// XLA f32 ErfInv (Giles) — exact coefficient match with jax/XLA.
// NOTE: must stay BIT-EXACT (log1pf, not a log2 rewrite): noise feeds
// f_norm = r0/max(r3,1e-5), whose derivative -f_norm/r3 amplifies ~1e-6
// noise shifts to ~1e-2 output error in sparse regions (round-2 fail).
__device__ __forceinline__ float erfinv_xla(float x){
  float w = -log1pf(-x*x);
  float p;
  if (w < 5.0f){
    w -= 2.5f;
    p =  2.81022636e-08f;
    p = fmaf(p,w, 3.43273939e-07f);
    p = fmaf(p,w,-3.5233877e-06f);
    p = fmaf(p,w,-4.39150654e-06f);
    p = fmaf(p,w, 0.00021858087f);
    p = fmaf(p,w,-0.00125372503f);
    p = fmaf(p,w,-0.00417768164f);
    p = fmaf(p,w, 0.246640727f);
    p = fmaf(p,w, 1.50140941f);
  } else {
    w = sqrtf(w) - 3.0f;
    p = -0.000200214257f;
    p = fmaf(p,w, 0.000100950558f);
    p = fmaf(p,w, 0.00134934322f);
    p = fmaf(p,w,-0.00367342844f);
    p = fmaf(p,w, 0.00573950773f);
    p = fmaf(p,w,-0.0076224613f);
    p = fmaf(p,w, 0.00943887047f);
    p = fmaf(p,w, 1.00167406f);
    p = fmaf(p,w, 2.83297682f);
  }
  return p*x;
}

// noise[i] = 0.8 * sqrt(2)*erfinv(uniform(-1,1)) with jax bit semantics
__device__ __forceinline__ float noise_at(uint32_t idx, uint32_t half){
#if JAX_PARTITIONABLE
  (void)half;
  uint32_t x0 = 0u, x1 = idx;     // counter = (hi=0, lo=i)
  tf2x32(x0, x1);
  uint32_t bits = x0 ^ x1;        // partitionable 32-bit path: xor-fold of both words
#else
  uint32_t j  = (idx < half) ? idx : (idx - half);
  uint32_t x0 = j, x1 = j + half;
  tf2x32(x0, x1);
  uint32_t bits = (idx < half) ? x0 : x1;
#endif
  float f = __uint_as_float((bits >> 9) | 0x3f800000u) - 1.0f;      // [0,1)
  float u = fmaxf(-0.99999994f, fmaf(f, 2.0f, -0.99999994f));       // (-1,1)
  return (1.41421356f * erfinv_xla(u)) * 0.8f;
}

// jax.nn.gelu approximate=True — minimal-op form (round-6 verified; the round-8
// exp2f rewrite used the PRECISE ocml entry and regressed — keep __expf).
__device__ __forceinline__ float gelu_f(float x){
  float t = x*x;
  float inner = x * fmaf(0.035677408136f, t, 0.7978845608028654f);
  float e = __expf(2.0f * inner);
  float r = __builtin_amdgcn_rcpf(e + 1.0f);
  return x - x*r;
}

__device__ __forceinline__ uint32_t pack2h_scaled(float a, float b){
  union { f16 h[2]; uint32_t u; } c;
  c.h[0] = (f16)(a * GRID_SCALE);
  c.h[1] = (f16)(b * GRID_SCALE);
  return c.u;
}
__device__ __forceinline__ uint32_t pack2h_raw(float a, float b){
  union { f16 h[2]; uint32_t u; } c;
  c.h[0] = (f16)a;
  c.h[1] = (f16)b;
  return c.u;
}

// common per-particle geometry
__device__ __forceinline__ void particle_cell(const float* xsr, int i,
                                              float& sx, float& sy, float& sz,
                                              int& bx, int& by, int& bz,
                                              float& dx, float& dy, float& dz){
  sx = fminf(fmaxf(xsr[3*i+0], 0.0f), 1.0f);
  sy = fminf(fmaxf(xsr[3*i+1], 0.0f), 1.0f);
  sz = fminf(fmaxf(xsr[3*i+2], 0.0f), 1.0f);
  float cx = fminf(fmaxf(sx*127.0f, 0.0f), 126.999f);
  float cy = fminf(fmaxf(sy*127.0f, 0.0f), 126.999f);
  float cz = fminf(fmaxf(sz*127.0f, 0.0f), 126.999f);
  float bxf = floorf(cx), byf = floorf(cy), bzf = floorf(cz);
  bx = (int)bxf; by = (int)byf; bz = (int)bzf;
  dx = cx - bxf; dy = cy - byf; dz = cz - bzf;
}

__device__ __forceinline__ int qbin_of(float qx01, float qy01, float qz01){
  int bx = min((int)(qx01*127.0f), 127) >> 2;
  int by = min((int)(qy01*127.0f), 127) >> 2;
  int bz = min((int)(qz01*127.0f), 127) >> 2;
  return (((bx<<5)+by)<<5)+bz;
}

// ---------------- fused histogram: particle cells + query coarse bins ----------------
__global__ void __launch_bounds__(256) hist2_kernel(
    const float* __restrict__ xsr, const float* __restrict__ xq,
    int* __restrict__ cells, int* __restrict__ qcnt, int N, int M){
  int i = blockIdx.x*256 + threadIdx.x;
  if (i < N){
    float sx,sy,sz,dx,dy,dz; int bx,by,bz;
    particle_cell(xsr,i,sx,sy,sz,bx,by,bz,dx,dy,dz);
    atomicAdd(&cells[(((bx<<7)+by)<<7)+bz], 1);
  }
  if (i < M){
    float qx01 = fminf(fmaxf(xq[3*i+0], 0.0f), 1.0f);
    float qy01 = fminf(fmaxf(xq[3*i+1], 0.0f), 1.0f);
    float qz01 = fminf(fmaxf(xq[3*i+2], 0.0f), 1.0f);
    atomicAdd(&qcnt[qbin_of(qx01,qy01,qz01)], 1);
  }
}

// scan stage 1, IN-PLACE: cells[i] (counts) -> per-block-local exclusive scans;
// bsum[blk] = block total. Safe in place: each thread reads/writes only its own 8.
__global__ void __launch_bounds__(256) scan1_kernel(int* __restrict__ cells,
                                                    int* __restrict__ bsum){
  __shared__ int lds[256];
  int t = threadIdx.x;
  int base = blockIdx.x*2048 + t*8;
  const int4* c4 = reinterpret_cast<const int4*>(cells + base);
  int4 a0 = c4[0], a1 = c4[1];
  int s = a0.x+a0.y+a0.z+a0.w + a1.x+a1.y+a1.z+a1.w;
  lds[t] = s; __syncthreads();
  for (int off = 1; off < 256; off <<= 1){
    int v = (t >= off) ? lds[t-off] : 0;
    __syncthreads();
    lds[t] += v;
    __syncthreads();
  }
  int run = lds[t] - s;
  if (t == 255) bsum[blockIdx.x] = lds[255];
  int* o = cells + base;
  o[0]=run; run+=a0.x; o[1]=run; run+=a0.y; o[2]=run; run+=a0.z; o[3]=run; run+=a0.w;
  o[4]=run; run+=a1.x; o[5]=run; run+=a1.y; o[6]=run; run+=a1.z; o[7]=run;
}

// fused: exclusive scan of bsum (particle block sums) + full exclusive scan of qcnt
__global__ void __launch_bounds__(1024) scan2q_kernel(int* __restrict__ bsum,
                                                      const int* __restrict__ qcnt,
                                                      int* __restrict__ qcur){
  __shared__ int lds[1024];
  int t = threadIdx.x;
  int v = bsum[t];
  lds[t] = v; __syncthreads();
  for (int off = 1; off < 1024; off <<= 1){
    int u = (t >= off) ? lds[t-off] : 0;
    __syncthreads();
    lds[t] += u;
    __syncthreads();
  }
  bsum[t] = lds[t] - v;
  __syncthreads();
  int base = t*32;
  int loc[32];
  int s = 0;
#pragma unroll
  for (int j = 0; j < 32; ++j){ loc[j] = qcnt[base+j]; s += loc[j]; }
  lds[t] = s; __syncthreads();
  for (int off = 1; off < 1024; off <<= 1){
    int u = (t >= off) ? lds[t-off] : 0;
    __syncthreads();
    lds[t] += u;
    __syncthreads();
  }
  int run = lds[t] - s;
#pragma unroll
  for (int j = 0; j < 32; ++j){ qcur[base+j] = run; run += loc[j]; }
}

// fused scatter: packed f16 particle payload bump-alloc + query float4 stash.
// Position = atomicAdd on the local-scan cells[] + bsum[blk] in-register.
// After this kernel: E(b) := cells[b]+bsum[b>>11] = global END of bin b.
__global__ void __launch_bounds__(256) scatter2_kernel(
    const float* __restrict__ xsr, const float* __restrict__ xsc,
    const float* __restrict__ Wf,  const float* __restrict__ bf,
    const float* __restrict__ xq,
    int* __restrict__ cells, const int* __restrict__ bsum, int* __restrict__ qcur,
    half8* __restrict__ pp, float* __restrict__ pz,
    float4* __restrict__ qpk, int N, int M){
  int i = blockIdx.x*256 + threadIdx.x;
  if (i < N){
    float sx,sy,sz,dx,dy,dz; int bx,by,bz;
    particle_cell(xsr,i,sx,sy,sz,bx,by,bz,dx,dy,dz);
    float ux = xsc[3*i+0] - sx;
    float uy = xsc[3*i+1] - sy;
    float uz = xsc[3*i+2] - sz;
    float f0 = gelu_f(ux*Wf[0] + uy*Wf[3] + uz*Wf[6] + bf[0]);
    float f1 = gelu_f(ux*Wf[1] + uy*Wf[4] + uz*Wf[7] + bf[1]);
    float f2 = gelu_f(ux*Wf[2] + uy*Wf[5] + uz*Wf[8] + bf[2]);
    int bin = (((bx<<7)+by)<<7)+bz;
    int pos = atomicAdd(&cells[bin], 1) + bsum[bin >> 11];
    half8 ph;
    ph[0] = (f16)(f0*GRID_SCALE); ph[1] = (f16)(f1*GRID_SCALE); ph[2] = (f16)(f2*GRID_SCALE);
    ph[3] = (f16)(ux*GRID_SCALE); ph[4] = (f16)(uy*GRID_SCALE); ph[5] = (f16)(uz*GRID_SCALE);
    ph[6] = (f16)dx; ph[7] = (f16)dy;
    pp[pos] = ph;
    pz[pos] = dz;
  }
  if (i < M){
    float qx01 = fminf(fmaxf(xq[3*i+0], 0.0f), 1.0f);
    float qy01 = fminf(fmaxf(xq[3*i+1], 0.0f), 1.0f);
    float qz01 = fminf(fmaxf(xq[3*i+2], 0.0f), 1.0f);
    int pos = atomicAdd(&qcur[qbin_of(qx01,qy01,qz01)], 1);
    qpk[pos] = make_float4(qx01, qy01, qz01, __int_as_float(i));
  }
}

// z-pair per-cell gather (packed f16 payload) -> packed f16 grid (16B/cell).
// Bin ranges reconstructed from bumped cells[] + bsum[] (scan3-free, round-9 verified).
__global__ void __launch_bounds__(256) p2g_gather_pair_kernel(
    const int* __restrict__ cells, const int* __restrict__ bsum,
    const half8* __restrict__ pp, const float* __restrict__ pz,
    uint4* __restrict__ gridh){
  int tid = blockIdx.x*256 + threadIdx.x;   // exactly NCELLS/2 threads
  int zg = tid & 63, y = (tid >> 6) & 127, x = tid >> 13;
  int z0 = zg << 1;
  auto E = [&](int b){ return cells[b] + bsum[b >> 11]; };
  float a0[2]={0,0},a1[2]={0,0},a2[2]={0,0},a3[2]={0,0},a4[2]={0,0},a5[2]={0,0},a6[2]={0,0};
#pragma unroll
  for (int ox = 0; ox < 2; ++ox){
    int bx = x - ox; if (bx < 0) continue;
#pragma unroll
    for (int oy = 0; oy < 2; ++oy){
      int by = y - oy; if (by < 0) continue;
      int b0 = ((((bx<<7)+by)<<7)) + z0;
      int em = (b0 > 0) ? E(b0-1) : 0;
      int sm = (z0 > 0) ? E(b0-2) : em;
      int e0 = E(b0);
      int e1 = E(b0+1);
      for (int p = sm; p < e1; ++p){
        half8 P = pp[p]; float dz = pz[p];
        float pdx = (float)P[6], pdy = (float)P[7];
        float wx = ox ? pdx : 1.0f - pdx;
        float wy = oy ? pdy : 1.0f - pdy;
        float wxy = wx*wy;
        float omdz = 1.0f - dz;
        float w0 = (p < em) ? dz : ((p < e0) ? omdz : 0.0f);
        float w1 = (p < em) ? 0.0f : ((p < e0) ? dz : omdz);
        w0 *= wxy; w1 *= wxy;
        float v0=(float)P[0], v1=(float)P[1], v2=(float)P[2];
        float v3=(float)P[3], v4=(float)P[4], v5=(float)P[5];
        a0[0]=fmaf(v0,w0,a0[0]); a1[0]=fmaf(v1,w0,a1[0]); a2[0]=fmaf(v2,w0,a2[0]);
        a3[0]+=w0; a4[0]=fmaf(v3,w0,a4[0]); a5[0]=fmaf(v4,w0,a5[0]); a6[0]=fmaf(v5,w0,a6[0]);
        a0[1]=fmaf(v0,w1,a0[1]); a1[1]=fmaf(v1,w1,a1[1]); a2[1]=fmaf(v2,w1,a2[1]);
        a3[1]+=w1; a4[1]=fmaf(v3,w1,a4[1]); a5[1]=fmaf(v4,w1,a5[1]); a6[1]=fmaf(v5,w1,a6[1]);
      }
    }
  }
  int cell0 = ((((x<<7)+y)<<7)) + z0;
  uint4 g0, g1;
  g0.x = pack2h_raw(a0[0], a1[0]); g0.y = pack2h_raw(a2[0], a4[0]);
  g0.z = pack2h_raw(a5[0], a6[0]); g0.w = __float_as_uint(a3[0]);
  g1.x = pack2h_raw(a0[1], a1[1]); g1.y = pack2h_raw(a2[1], a4[1]);
  g1.z = pack2h_raw(a5[1], a6[1]); g1.w = __float_as_uint(a3[1]);
  uint4* g = gridh + cell0;
  g[0] = g0; g[1] = g1;
}

// ---------------- fused gather + MFMA MLP (K=16 chained, f16 grid) ----------------
// Latency-hiding restructure: ALL 24 threefry/erfinv chains computed first (pure
// VALU burst), then the 8 trilerps fully unrolled — corner loads of path k+1 can
// issue while path k's fmafs drain (was: serial noise->load->fma chain per path,
// VALUBusy 78-86% = 14-22% latency-idle).
__global__ void __launch_bounds__(256, 4) gather_mlp_sorted_kernel(
    const float4* __restrict__ qpk,
    const uint4* __restrict__ gridh,
    const float* __restrict__ W1,  const float* __restrict__ b1,
    const float* __restrict__ W2,  const float* __restrict__ b2,
    const float* __restrict__ W3,  const float* __restrict__ b3,
    float* __restrict__ out, int M, int nblk)
{
  __shared__ __align__(16) f16  decs[4][64*DSTR]; // per-wave DEC^T [q][k<=32], 20 KB
  __shared__ __align__(16) f16  w1t[64*WSTR];     // W1^T [o][k], k padded 24->32, 5 KB
  __shared__ __align__(16) f16  w2t[64*W2STR];    // W2^T [o][k], 9 KB
  __shared__ __align__(16) float b1s[64], b2s[64];
  __shared__ __align__(16) float w3s[64*4];       // W3 rows padded to 4 floats, 1 KB

  // stage weights (block-cooperative)
  for (int i = threadIdx.x; i < 64*32; i += 256){
    int n = i >> 5, k = i & 31;
    w1t[n*WSTR + k] = (k < 24) ? (f16)W1[k*64 + n] : (f16)0.0f;
  }
  for (int i = threadIdx.x; i < 64*64; i += 256){
    int n = i >> 6, k = i & 63;
    w2t[n*W2STR + k] = (f16)W2[k*64 + n];
  }
  if (threadIdx.x < 64){ b1s[threadIdx.x] = b1[threadIdx.x]; b2s[threadIdx.x] = b2[threadIdx.x]; }
  for (int i = threadIdx.x; i < 192; i += 256){
    w3s[(i/3)*4 + (i - (i/3)*3)] = W3[i];
  }
  __syncthreads();

  int b = blockIdx.x;
  int nb8 = (nblk >> 3) << 3;
  int c = (b < nb8) ? ((b & 7)*(nblk >> 3) + (b >> 3)) : b;   // XCD-contiguous chunks
  int t = c*256 + (int)threadIdx.x;
  bool active = (t < M);
  int tc = active ? t : (M - 1);

  float4 qv = qpk[tc];
  float qx01 = qv.x, qy01 = qv.y, qz01 = qv.z;
  int m = __float_as_int(qv.w);
  float qx = qx01*127.0f, qy = qy01*127.0f, qz = qz01*127.0f;

  // ---- phase 1: all 24 noise values (pure VALU, unrolled/static) ----
  const uint32_t KSTRIDE = 3u*(uint32_t)M;
  const uint32_t HALF    = 4u*KSTRIDE;
  uint32_t m3 = 3u*(uint32_t)m;
  float nx[8], ny[8], nz[8];
#pragma unroll
  for (int k = 0; k < 8; ++k) {
    uint32_t base = (uint32_t)k*KSTRIDE + m3;
    nx[k] = noise_at(base+0u, HALF);
    ny[k] = noise_at(base+1u, HALF);
    nz[k] = noise_at(base+2u, HALF);
  }

  // ---- phase 2: 8 trilerps, fully unrolled (loads overlap across paths) ----
  float r0=0.f,r1=0.f,r2=0.f,r3=0.f,r4=0.f,r5=0.f,r6=0.f;
#pragma unroll
  for (int k = 0; k < 8; ++k) {
    float px = qx + nx[k];
    float py = qy + ny[k];
    float pz = qz + nz[k];
    float fxf = floorf(px), fyf = floorf(py), fzf = floorf(pz);
    float fx = px - fxf, fy = py - fyf, fz = pz - fzf;
    int lx = (int)fxf, ly = (int)fyf, lz = (int)fzf;
    int x0i = min(max(lx,0),127),   x1i = min(max(lx+1,0),127);
    int y0i = min(max(ly,0),127),   y1i = min(max(ly+1,0),127);
    int z0i = min(max(lz,0),127),   z1i = min(max(lz+1,0),127);
    float ex = 1.0f-fx, ey = 1.0f-fy, ez = 1.0f-fz;

    auto corner = [&](int xi,int yi,int zi,float w){
      uint4 q4 = gridh[(((xi<<7)+yi)<<7)+zi];
      union { uint32_t u; f16 h[2]; } c0, c1, c2;
      c0.u = q4.x; c1.u = q4.y; c2.u = q4.z;
      r0 = fmaf((float)c0.h[0], w, r0);
      r1 = fmaf((float)c0.h[1], w, r1);
      r2 = fmaf((float)c1.h[0], w, r2);
      r4 = fmaf((float)c1.h[1], w, r4);
      r5 = fmaf((float)c2.h[0], w, r5);
      r6 = fmaf((float)c2.h[1], w, r6);
      r3 = fmaf(__uint_as_float(q4.w), w, r3);
    };
    corner(x0i,y0i,z0i, ex*ey*ez);
    corner(x0i,y0i,z1i, ex*ey*fz);
    corner(x0i,y1i,z0i, ex*fy*ez);
    corner(x0i,y1i,z1i, ex*fy*fz);
    corner(x1i,y0i,z0i, fx*ey*ez);
    corner(x1i,y0i,z1i, fx*ey*fz);
    corner(x1i,y1i,z0i, fx*fy*ez);
    corner(x1i,y1i,z1i, fx*fy*fz);
  }

  // d-channel is f32 -> mask decision window identical to the all-f32 kernel
  float dmean = r3*0.125f;
  float denom = fmaxf(dmean, 1e-5f);
  float maskf = (dmean > 1e-5f) ? 1.0f : 0.0f;
  float s   = 0.125f/denom*maskf;
  float sfu = s * GRID_ISCALE;   // exact /1024 for the scaled f16 channels
  float un0 = r4*sfu, un1 = r5*sfu, un2 = r6*sfu;

  float dec[24];
  dec[0]=r0*sfu; dec[1]=r1*sfu; dec[2]=r2*sfu; dec[3]=un0; dec[4]=un1; dec[5]=un2;
  dec[6]  = __builtin_amdgcn_sinf(0.5f*qx01);   // v_sin input is revolutions
  dec[7]  = __builtin_amdgcn_sinf(0.5f*qy01);
  dec[8]  = __builtin_amdgcn_sinf(0.5f*qz01);
  dec[9]  = __builtin_amdgcn_cosf(0.5f*qx01);
  dec[10] = __builtin_amdgcn_cosf(0.5f*qy01);
  dec[11] = __builtin_amdgcn_cosf(0.5f*qz01);
  dec[12] = __builtin_amdgcn_sinf(qx01);
  dec[13] = __builtin_amdgcn_sinf(qy01);
  dec[14] = __builtin_amdgcn_sinf(qz01);
  dec[15] = __builtin_amdgcn_cosf(qx01);
  dec[16] = __builtin_amdgcn_cosf(qy01);
  dec[17] = __builtin_amdgcn_cosf(qz01);
  dec[18] = __builtin_amdgcn_sinf(2.0f*qx01);
  dec[19] = __builtin_amdgcn_sinf(2.0f*qy01);
  dec[20] = __builtin_amdgcn_sinf(2.0f*qz01);
  dec[21] = __builtin_amdgcn_cosf(2.0f*qx01);
  dec[22] = __builtin_amdgcn_cosf(2.0f*qy01);
  dec[23] = __builtin_amdgcn_cosf(2.0f*qz01);

  // ---- MLP via chained 16x16x16 MFMAs (verified rounds 5/6) ----
  int lane = threadIdx.x & 63;
  int wv   = threadIdx.x >> 6;
  f16* hb = &decs[wv][0];
  int lo = lane & 15;           // C col / frag m-n index
  int hi = lane >> 4;           // quad id: frag k base = 4*hi; C row base = 4*hi

  // stage dec (fp16, k padded to 32) into hb[row=lane][k]: 4x b128
  {
    half8 dh;
#pragma unroll
    for (int c4 = 0; c4 < 3; ++c4){
#pragma unroll
      for (int j = 0; j < 8; ++j) dh[j] = (f16)dec[c4*8 + j];
      *reinterpret_cast<half8*>(&hb[lane*DSTR + c4*8]) = dh;
    }
#pragma unroll
    for (int j = 0; j < 8; ++j) dh[j] = (f16)0.0f;
    *reinterpret_cast<half8*>(&hb[lane*DSTR + 24]) = dh;
  }

  half4 w1f[4][2];
#pragma unroll
  for (int a = 0; a < 4; ++a)
#pragma unroll
    for (int kb = 0; kb < 2; ++kb)
      w1f[a][kb] = *reinterpret_cast<const half4*>(&w1t[(16*a + lo)*WSTR + 16*kb + 4*hi]);

  half4 dff[4][2];
#pragma unroll
  for (int bq = 0; bq < 4; ++bq)
#pragma unroll
    for (int kb = 0; kb < 2; ++kb)
      dff[bq][kb] = *reinterpret_cast<const half4*>(&hb[(16*bq + lo)*DSTR + 16*kb + 4*hi]);

  // layer 1: H^T = W1^T @ DEC^T, C-init = bias; hv[a][bq] is layer-2 B-frag (kb=a)
  half4 hv[4][4];
#pragma unroll
  for (int a = 0; a < 4; ++a){
    f32x4 zb = *reinterpret_cast<const f32x4*>(&b1s[16*a + 4*hi]);
#pragma unroll
    for (int bq = 0; bq < 4; ++bq){
      f32x4 z = __builtin_amdgcn_mfma_f32_16x16x16f16(w1f[a][0], dff[bq][0], zb, 0, 0, 0);
      z       = __builtin_amdgcn_mfma_f32_16x16x16f16(w1f[a][1], dff[bq][1], z,  0, 0, 0);
      half4 hvv;
#pragma unroll
      for (int p = 0; p < 4; ++p) hvv[p] = (f16)gelu_f(z[p]);
      hv[a][bq] = hvv;
    }
  }

  // layer 2 + 3: G^T = W2^T @ H^T (4 chained K=16), gelu + partial W3 dots in regs
  float part[4][3];
#pragma unroll
  for (int bq = 0; bq < 4; ++bq){ part[bq][0]=0.f; part[bq][1]=0.f; part[bq][2]=0.f; }

#pragma unroll
  for (int a2 = 0; a2 < 4; ++a2){
    half4 w2f[4];
#pragma unroll
    for (int kb = 0; kb < 4; ++kb)
      w2f[kb] = *reinterpret_cast<const half4*>(&w2t[(16*a2 + lo)*W2STR + 16*kb + 4*hi]);
    f32x4 zb2 = *reinterpret_cast<const f32x4*>(&b2s[16*a2 + 4*hi]);
#pragma unroll
    for (int bq = 0; bq < 4; ++bq){
      f32x4 z = __builtin_amdgcn_mfma_f32_16x16x16f16(w2f[0], hv[0][bq], zb2, 0, 0, 0);
      z       = __builtin_amdgcn_mfma_f32_16x16x16f16(w2f[1], hv[1][bq], z,   0, 0, 0);
      z       = __builtin_amdgcn_mfma_f32_16x16x16f16(w2f[2], hv[2][bq], z,   0, 0, 0);
      z       = __builtin_amdgcn_mfma_f32_16x16x16f16(w2f[3], hv[3][bq], z,   0, 0, 0);
#pragma unroll
      for (int p = 0; p < 4; ++p){
        f32x4 w3v = *reinterpret_cast<const f32x4*>(&w3s[(16*a2 + 4*hi + p)*4]);
        float g = gelu_f(z[p]);
        part[bq][0] = fmaf(g, w3v[0], part[bq][0]);
        part[bq][1] = fmaf(g, w3v[1], part[bq][1]);
        part[bq][2] = fmaf(g, w3v[2], part[bq][2]);
      }
    }
  }

  // reduce partials across the 4 quad-groups (lanes lo+16*hi')
#pragma unroll
  for (int bq = 0; bq < 4; ++bq)
#pragma unroll
    for (int cc = 0; cc < 3; ++cc){
      float v = part[bq][cc];
      v += __shfl_xor(v, 16, 64);
      v += __shfl_xor(v, 32, 64);
      part[bq][cc] = v;
    }

  // lane L owns query q* = 16*hi + lo = L  -> select bq == hi (static select chain)
  float o0 = (hi==0) ? part[0][0] : (hi==1) ? part[1][0] : (hi==2) ? part[2][0] : part[3][0];
  float o1 = (hi==0) ? part[0][1] : (hi==1) ? part[1][1] : (hi==2) ? part[2][1] : part[3][1];
  float o2 = (hi==0) ? part[0][2] : (hi==1) ? part[1][2] : (hi==2) ? part[2][2] : part[3][2];
  o0 += b3[0]; o1 += b3[1]; o2 += b3[2];

  if (active){
    out[3*m+0] = fminf(fmaxf(un0 + o0, 0.001f), 0.999f);
    out[3*m+1] = fminf(fmaxf(un1 + o1, 0.001f), 0.999f);
    out[3*m+2] = fminf(fmaxf(un2 + o2, 0.001f), 0.999f);
  }
}

// ---------------- fallbacks (ws too small; not used in practice) ----------------
__global__ void __launch_bounds__(256) p2g_atomic_kernel(
    const float* __restrict__ xsr, const float* __restrict__ xsc,
    const float* __restrict__ Wf,  const float* __restrict__ bf,
    float* __restrict__ grid, int N)
{
  int i = blockIdx.x*256 + threadIdx.x;
  if (i >= N) return;
  float sx,sy,sz,dx,dy,dz; int bx,by,bz;
  particle_cell(xsr,i,sx,sy,sz,bx,by,bz,dx,dy,dz);
  float ux = xsc[3*i+0] - sx;
  float uy = xsc[3*i+1] - sy;
  float uz = xsc[3*i+2] - sz;
  float f0 = gelu_f(ux*Wf[0] + uy*Wf[3] + uz*Wf[6] + bf[0]);
  float f1 = gelu_f(ux*Wf[1] + uy*Wf[4] + uz*Wf[7] + bf[1]);
  float f2 = gelu_f(ux*Wf[2] + uy*Wf[5] + uz*Wf[8] + bf[2]);
  float ex = 1.0f - dx, ey = 1.0f - dy, ez = 1.0f - dz;
  auto splat = [&](int xi, int yi, int zi, float w){
    float* p = grid + ((size_t)((((xi<<7)+yi)<<7)+zi) << 3);
    unsafeAtomicAdd(p+0, f0*w);
    unsafeAtomicAdd(p+1, f1*w);
    unsafeAtomicAdd(p+2, f2*w);
    unsafeAtomicAdd(p+3, w);
    unsafeAtomicAdd(p+4, ux*w);
    unsafeAtomicAdd(p+5, uy*w);
    unsafeAtomicAdd(p+6, uz*w);
  };
  splat(bx,  by,  bz,   ex*ey*ez);
  splat(bx,  by,  bz+1, ex*ey*dz);
  splat(bx,  by+1,bz,   ex*dy*ez);
  splat(bx,  by+1,bz+1, ex*dy*dz);
  splat(bx+1,by,  bz,   dx*ey*ez);
  splat(bx+1,by,  bz+1, dx*ey*dz);
  splat(bx+1,by+1,bz,   dx*dy*ez);
  splat(bx+1,by+1,bz+1, dx*dy*dz);
}

// fallback: convert f32 grid (8 floats/cell, unscaled) -> packed f16 grid
__global__ void __launch_bounds__(256) grid2half_kernel(
    const float* __restrict__ grid, uint4* __restrict__ gridh){
  int i = blockIdx.x*256 + threadIdx.x;   // NCELLS threads
  const float4* p = reinterpret_cast<const float4*>(grid + ((size_t)i << 3));
  float4 A = p[0], B = p[1];
  uint4 g;
  g.x = pack2h_scaled(A.x, A.y);
  g.y = pack2h_scaled(A.z, B.x);
  g.z = pack2h_scaled(B.y, B.z);
  g.w = __float_as_uint(A.w);
  gridh[i] = g;
}

__global__ void __launch_bounds__(256) qident_kernel(
    const float* __restrict__ xq, float4* __restrict__ qpk, int M){
  int i = blockIdx.x*256 + threadIdx.x;
  if (i >= M) return;
  float qx01 = fminf(fmaxf(xq[3*i+0], 0.0f), 1.0f);
  float qy01 = fminf(fmaxf(xq[3*i+1], 0.0f), 1.0f);
  float qz01 = fminf(fmaxf(xq[3*i+2], 0.0f), 1.0f);
  qpk[i] = make_float4(qx01, qy01, qz01, __int_as_float(i));
}

extern "C" void kernel_launch(void* const* d_in, const int* in_sizes, int n_in,
                              void* d_out, int out_size, void* d_ws, size_t ws_size,
                              hipStream_t stream)
{
  const float* xq  = (const float*)d_in[0];
  const float* xsr = (const float*)d_in[1];
  const float* xsc = (const float*)d_in[2];
  const float* Wf  = (const float*)d_in[3];
  const float* bf  = (const float*)d_in[4];
  const float* W1  = (const float*)d_in[5];
  const float* b1  = (const float*)d_in[6];
  const float* W2  = (const float*)d_in[7];
  const float* b2  = (const float*)d_in[8];
  const float* W3  = (const float*)d_in[9];
  const float* b3  = (const float*)d_in[10];
  float* out  = (float*)d_out;
  int M = in_sizes[0]/3;
  int N = in_sizes[1]/3;

  // workspace layout: gridh (packed f16) + qpk always live; union region holds
  // EITHER the main path's sort buffers (~18.3 MB) OR the fallback's 64 MB f32 grid.
  char* W = (char*)d_ws;
  size_t off = 0;
  auto alloc = [&](size_t bytes){ size_t o = off; off = (off + bytes + 255) & ~(size_t)255; return o; };
  size_t o_gridh = alloc((size_t)NCELLS * 16);            // 32 MiB packed f16 grid
  size_t o_qpk   = alloc((size_t)M * sizeof(float4));     // 8 MB
  size_t o_union = off;
  // main-path sub-offsets within the union region:
  size_t o_cells = alloc((size_t)NCELLS * sizeof(int));   // 8 MiB (cnt -> local scan -> bumped)
  size_t o_qcnt  = alloc((size_t)NQBINS * sizeof(int));   // 128 KB (directly after cells)
  size_t o_bsum  = alloc((size_t)SCAN_BLOCKS * sizeof(int));
  size_t o_qcur  = alloc((size_t)NQBINS * sizeof(int));   // 128 KB
  size_t o_pp    = alloc((size_t)N * sizeof(half8));      // 8 MB packed payload
  size_t o_pz    = alloc((size_t)N * sizeof(float));      // 2 MB
  size_t main_end = off;
  size_t full_end = (o_union + (size_t)NCELLS * 8 * sizeof(float) > main_end)
                  ? (o_union + (size_t)NCELLS * 8 * sizeof(float)) : main_end;

  uint4*  gridh = (uint4*)(W + o_gridh);
  float4* qpk   = (float4*)(W + o_qpk);
  int*    cells = (int*)(W + o_cells);
  int*    qcnt  = (int*)(W + o_qcnt);
  int*    bsum  = (int*)(W + o_bsum);
  int*    qcur  = (int*)(W + o_qcur);
  half8*  pp    = (half8*)(W + o_pp);
  float*  pz    = (float*)(W + o_pz);
  float*  gridf = (float*)(W + o_union);   // fallback f32 grid (aliases sort buffers)

  int nthr = (N > M) ? N : M;
  int nblkNM = (nthr + 255) / 256;

  if (main_end <= ws_size) {
    hipMemsetAsync(cells, 0, (size_t)NCELLS * sizeof(int) + (size_t)NQBINS * sizeof(int), stream);
    hist2_kernel<<<nblkNM, 256, 0, stream>>>(xsr, xq, cells, qcnt, N, M);
    scan1_kernel<<<SCAN_BLOCKS, 256, 0, stream>>>(cells, bsum);
    scan2q_kernel<<<1, 1024, 0, stream>>>(bsum, qcnt, qcur);
    scatter2_kernel<<<nblkNM, 256, 0, stream>>>(xsr, xsc, Wf, bf, xq, cells, bsum, qcur,
                                                pp, pz, qpk, N, M);
    p2g_gather_pair_kernel<<<(NCELLS/2)/256, 256, 0, stream>>>(cells, bsum, pp, pz, gridh);
  } else {
    // fallback: f32 atomic grid in the union region, convert to packed gridh
    (void)full_end;
    hipMemsetAsync(gridf, 0, (size_t)NCELLS * 8 * sizeof(float), stream);
    p2g_atomic_kernel<<<(N+255)/256, 256, 0, stream>>>(xsr, xsc, Wf, bf, gridf, N);
    grid2half_kernel<<<NCELLS/256, 256, 0, stream>>>(gridf, gridh);
    qident_kernel<<<(M+255)/256, 256, 0, stream>>>(xq, qpk, M);
  }

  int nblk = (M + 255) / 256;
  gather_mlp_sorted_kernel<<<nblk, 256, 0, stream>>>(qpk, gridh, W1,b1,W2,b2,W3,b3, out, M, nblk);
}

// Round 11
// 311.450 us; speedup vs baseline: 3.4399x; 1.1694x over previous
//
#include <hip/hip_runtime.h>
#include <cstdint>

#ifndef JAX_PARTITIONABLE
#define JAX_PARTITIONABLE 1   // modern JAX (>=0.5) default threefry_partitionable
#endif

#define NCELLS (128*128*128)          // 2,097,152
#define SCAN_BLOCKS 1024              // NCELLS / 2048
#define NQBINS (32*32*32)             // coarse query bins (4x4x4 cells each)

typedef _Float16 f16;
typedef f16  half8 __attribute__((ext_vector_type(8)));
typedef f16  half4 __attribute__((ext_vector_type(4)));
typedef float f32x4 __attribute__((ext_vector_type(4)));

#define WSTR 40   // row stride (halfs) for [64][32] W1^T tile
#define DSTR 40   // row stride (halfs) for per-wave [64][32] DEC tile
#define W2STR 72  // row stride (halfs) for [64][64] W2^T tile

// Packed grid cell (16B): u32[0]=(f0,f1) u32[1]=(f2,u0) u32[2]=(u1,u2) as f16 x1024;
// u32[3] = d in f32. d stays f32: the dmean>1e-5 mask boundary amplifies
// d-perturbations (round-2 lesson class). x1024 (exact pow2) lifts f/u out of f16
// subnormals and cancels exactly via sfu = s/1024.
// NOTE (round-7 lesson): device-scope atomics on gfx950 write through to HBM
// (~32B/atomic, no L2 accumulation) — minimize atomics. Round-11: scatter2 is
// atomic-FREE (ranks captured from hist2's atomic return value).
#define GRID_SCALE 1024.0f
#define GRID_ISCALE 0.0009765625f

// ---------------- Threefry-2x32, key = (0, 42)  (jax.random.key(42)) ----------------
__device__ __forceinline__ uint32_t rotl32(uint32_t v, int s){ return (v << s) | (v >> (32 - s)); }

__device__ __forceinline__ void tf2x32(uint32_t& x0, uint32_t& x1){
  const uint32_t k0 = 0u, k1 = 42u;
  const uint32_t k2 = 0x1BD11BDAu ^ k0 ^ k1;
  x0 += k0; x1 += k1;
#define TFR(r) { x0 += x1; x1 = rotl32(x1,(r)); x1 ^= x0; }
  TFR(13) TFR(15) TFR(26) TFR(6)
  x0 += k1; x1 += k2 + 1u;
  TFR(17) TFR(29) TFR(16) TFR(24)
  x0 += k2; x1 += k0 + 2u;
  TFR(13) TFR(15) TFR(26) TFR(6)
  x0 += k0; x1 += k1 + 3u;
  TFR(17) TFR(29) TFR(16) TFR(24)
  x0 += k1; x1 += k2 + 4u;
  TFR(13) TFR(15) TFR(26) TFR(6)
  x0 += k2; x1 += k0 + 5u;
#undef TFR
}

// XLA f32 ErfInv (Giles) — exact coefficient match with jax/XLA.
// NOTE: must stay BIT-EXACT (log1pf, not a log2 rewrite): noise feeds
// f_norm = r0/max(r3,1e-5), whose derivative -f_norm/r3 amplifies ~1e-6
// noise shifts to ~1e-2 output error in sparse regions (round-2 fail).
__device__ __forceinline__ float erfinv_xla(float x){
  float w = -log1pf(-x*x);
  float p;
  if (w < 5.0f){
    w -= 2.5f;
    p =  2.81022636e-08f;
    p = fmaf(p,w, 3.43273939e-07f);
    p = fmaf(p,w,-3.5233877e-06f);
    p = fmaf(p,w,-4.39150654e-06f);
    p = fmaf(p,w, 0.00021858087f);
    p = fmaf(p,w,-0.00125372503f);
    p = fmaf(p,w,-0.00417768164f);
    p = fmaf(p,w, 0.246640727f);
    p = fmaf(p,w, 1.50140941f);
  } else {
    w = sqrtf(w) - 3.0f;
    p = -0.000200214257f;
    p = fmaf(p,w, 0.000100950558f);
    p = fmaf(p,w, 0.00134934322f);
    p = fmaf(p,w,-0.00367342844f);
    p = fmaf(p,w, 0.00573950773f);
    p = fmaf(p,w,-0.0076224613f);
    p = fmaf(p,w, 0.00943887047f);
    p = fmaf(p,w, 1.00167406f);
    p = fmaf(p,w, 2.83297682f);
  }
  return p*x;
}

// noise[i] = 0.8 * sqrt(2)*erfinv(uniform(-1,1)) with jax bit semantics
__device__ __forceinline__ float noise_at(uint32_t idx, uint32_t half){
#if JAX_PARTITIONABLE
  (void)half;
  uint32_t x0 = 0u, x1 = idx;     // counter = (hi=0, lo=i)
  tf2x32(x0, x1);
  uint32_t bits = x0 ^ x1;        // partitionable 32-bit path: xor-fold of both words
#else
  uint32_t j  = (idx < half) ? idx : (idx - half);
  uint32_t x0 = j, x1 = j + half;
  tf2x32(x0, x1);
  uint32_t bits = (idx < half) ? x0 : x1;
#endif
  float f = __uint_as_float((bits >> 9) | 0x3f800000u) - 1.0f;      // [0,1)
  float u = fmaxf(-0.99999994f, fmaf(f, 2.0f, -0.99999994f));       // (-1,1)
  return (1.41421356f * erfinv_xla(u)) * 0.8f;
}

// jax.nn.gelu approximate=True — minimal-op form (round-6 verified; the round-8
// exp2f rewrite used the PRECISE ocml entry and regressed — keep __expf).
__device__ __forceinline__ float gelu_f(float x){
  float t = x*x;
  float inner = x * fmaf(0.035677408136f, t, 0.7978845608028654f);
  float e = __expf(2.0f * inner);
  float r = __builtin_amdgcn_rcpf(e + 1.0f);
  return x - x*r;
}

__device__ __forceinline__ uint32_t pack2h_scaled(float a, float b){
  union { f16 h[2]; uint32_t u; } c;
  c.h[0] = (f16)(a * GRID_SCALE);
  c.h[1] = (f16)(b * GRID_SCALE);
  return c.u;
}
__device__ __forceinline__ uint32_t pack2h_raw(float a, float b){
  union { f16 h[2]; uint32_t u; } c;
  c.h[0] = (f16)a;
  c.h[1] = (f16)b;
  return c.u;
}

// common per-particle geometry
__device__ __forceinline__ void particle_cell(const float* xsr, int i,
                                              float& sx, float& sy, float& sz,
                                              int& bx, int& by, int& bz,
                                              float& dx, float& dy, float& dz){
  sx = fminf(fmaxf(xsr[3*i+0], 0.0f), 1.0f);
  sy = fminf(fmaxf(xsr[3*i+1], 0.0f), 1.0f);
  sz = fminf(fmaxf(xsr[3*i+2], 0.0f), 1.0f);
  float cx = fminf(fmaxf(sx*127.0f, 0.0f), 126.999f);
  float cy = fminf(fmaxf(sy*127.0f, 0.0f), 126.999f);
  float cz = fminf(fmaxf(sz*127.0f, 0.0f), 126.999f);
  float bxf = floorf(cx), byf = floorf(cy), bzf = floorf(cz);
  bx = (int)bxf; by = (int)byf; bz = (int)bzf;
  dx = cx - bxf; dy = cy - byf; dz = cz - bzf;
}

__device__ __forceinline__ int qbin_of(float qx01, float qy01, float qz01){
  int bx = min((int)(qx01*127.0f), 127) >> 2;
  int by = min((int)(qy01*127.0f), 127) >> 2;
  int bz = min((int)(qz01*127.0f), 127) >> 2;
  return (((bx<<5)+by)<<5)+bz;
}

// ---------------- fused histogram + RANK CAPTURE ----------------
// The atomic's return value IS the particle's rank within its bin — pack it:
//   pcode = (bin<<11)|rank   (bin < 2^21; Poisson lam=0.24 -> max count ~8, margin 200x)
//   qcode = (qbin<<17)|rank  (qbin < 2^15; lam=15.6/bin, margin ~10^3)
// This makes scatter2 atomic-free (round-7 lesson: each atomic ~32B HBM write-through).
__global__ void __launch_bounds__(256) hist2_kernel(
    const float* __restrict__ xsr, const float* __restrict__ xq,
    int* __restrict__ cells, int* __restrict__ qcnt,
    uint32_t* __restrict__ pcode, uint32_t* __restrict__ qcode, int N, int M){
  int i = blockIdx.x*256 + threadIdx.x;
  if (i < N){
    float sx,sy,sz,dx,dy,dz; int bx,by,bz;
    particle_cell(xsr,i,sx,sy,sz,bx,by,bz,dx,dy,dz);
    int bin = (((bx<<7)+by)<<7)+bz;
    uint32_t rank = (uint32_t)atomicAdd(&cells[bin], 1);
    pcode[i] = ((uint32_t)bin << 11) | rank;
  }
  if (i < M){
    float qx01 = fminf(fmaxf(xq[3*i+0], 0.0f), 1.0f);
    float qy01 = fminf(fmaxf(xq[3*i+1], 0.0f), 1.0f);
    float qz01 = fminf(fmaxf(xq[3*i+2], 0.0f), 1.0f);
    int qb = qbin_of(qx01,qy01,qz01);
    uint32_t rank = (uint32_t)atomicAdd(&qcnt[qb], 1);
    qcode[i] = ((uint32_t)qb << 17) | rank;
  }
}

// scan stage 1, IN-PLACE: cells[i] (counts) -> per-block-local exclusive scans;
// bsum[blk] = block total. Safe in place: each thread reads/writes only its own 8.
__global__ void __launch_bounds__(256) scan1_kernel(int* __restrict__ cells,
                                                    int* __restrict__ bsum){
  __shared__ int lds[256];
  int t = threadIdx.x;
  int base = blockIdx.x*2048 + t*8;
  const int4* c4 = reinterpret_cast<const int4*>(cells + base);
  int4 a0 = c4[0], a1 = c4[1];
  int s = a0.x+a0.y+a0.z+a0.w + a1.x+a1.y+a1.z+a1.w;
  lds[t] = s; __syncthreads();
  for (int off = 1; off < 256; off <<= 1){
    int v = (t >= off) ? lds[t-off] : 0;
    __syncthreads();
    lds[t] += v;
    __syncthreads();
  }
  int run = lds[t] - s;
  if (t == 255) bsum[blockIdx.x] = lds[255];
  int* o = cells + base;
  o[0]=run; run+=a0.x; o[1]=run; run+=a0.y; o[2]=run; run+=a0.z; o[3]=run; run+=a0.w;
  o[4]=run; run+=a1.x; o[5]=run; run+=a1.y; o[6]=run; run+=a1.z; o[7]=run;
}

// fused: exclusive scan of bsum (particle block sums) + full exclusive scan of qcnt
// qstart[] = exclusive bin starts (read-only downstream — no bump).
__global__ void __launch_bounds__(1024) scan2q_kernel(int* __restrict__ bsum,
                                                      const int* __restrict__ qcnt,
                                                      int* __restrict__ qstart){
  __shared__ int lds[1024];
  int t = threadIdx.x;
  int v = bsum[t];
  lds[t] = v; __syncthreads();
  for (int off = 1; off < 1024; off <<= 1){
    int u = (t >= off) ? lds[t-off] : 0;
    __syncthreads();
    lds[t] += u;
    __syncthreads();
  }
  bsum[t] = lds[t] - v;
  __syncthreads();
  int base = t*32;
  int loc[32];
  int s = 0;
#pragma unroll
  for (int j = 0; j < 32; ++j){ loc[j] = qcnt[base+j]; s += loc[j]; }
  lds[t] = s; __syncthreads();
  for (int off = 1; off < 1024; off <<= 1){
    int u = (t >= off) ? lds[t-off] : 0;
    __syncthreads();
    lds[t] += u;
    __syncthreads();
  }
  int run = lds[t] - s;
#pragma unroll
  for (int j = 0; j < 32; ++j){ qstart[base+j] = run; run += loc[j]; }
}

// ATOMIC-FREE scatter: pos = S(bin) + rank (rank from hist2's pcode/qcode).
// cells[] stays the pure local exclusive scan — p2g reconstructs ranges from it.
__global__ void __launch_bounds__(256) scatter2_kernel(
    const float* __restrict__ xsr, const float* __restrict__ xsc,
    const float* __restrict__ Wf,  const float* __restrict__ bf,
    const float* __restrict__ xq,
    const int* __restrict__ cells, const int* __restrict__ bsum,
    const int* __restrict__ qstart,
    const uint32_t* __restrict__ pcode, const uint32_t* __restrict__ qcode,
    half8* __restrict__ pp, float* __restrict__ pz,
    float4* __restrict__ qpk, int N, int M){
  int i = blockIdx.x*256 + threadIdx.x;
  if (i < N){
    float sx,sy,sz,dx,dy,dz; int bx,by,bz;
    particle_cell(xsr,i,sx,sy,sz,bx,by,bz,dx,dy,dz);
    float ux = xsc[3*i+0] - sx;
    float uy = xsc[3*i+1] - sy;
    float uz = xsc[3*i+2] - sz;
    float f0 = gelu_f(ux*Wf[0] + uy*Wf[3] + uz*Wf[6] + bf[0]);
    float f1 = gelu_f(ux*Wf[1] + uy*Wf[4] + uz*Wf[7] + bf[1]);
    float f2 = gelu_f(ux*Wf[2] + uy*Wf[5] + uz*Wf[8] + bf[2]);
    uint32_t pc = pcode[i];
    int bin  = (int)(pc >> 11);
    int rank = (int)(pc & 2047u);
    int pos = cells[bin] + bsum[bin >> 11] + rank;
    half8 ph;
    ph[0] = (f16)(f0*GRID_SCALE); ph[1] = (f16)(f1*GRID_SCALE); ph[2] = (f16)(f2*GRID_SCALE);
    ph[3] = (f16)(ux*GRID_SCALE); ph[4] = (f16)(uy*GRID_SCALE); ph[5] = (f16)(uz*GRID_SCALE);
    ph[6] = (f16)dx; ph[7] = (f16)dy;
    pp[pos] = ph;
    pz[pos] = dz;
  }
  if (i < M){
    float qx01 = fminf(fmaxf(xq[3*i+0], 0.0f), 1.0f);
    float qy01 = fminf(fmaxf(xq[3*i+1], 0.0f), 1.0f);
    float qz01 = fminf(fmaxf(xq[3*i+2], 0.0f), 1.0f);
    uint32_t qc = qcode[i];
    int qb   = (int)(qc >> 17);
    int rank = (int)(qc & 131071u);
    int pos = qstart[qb] + rank;
    qpk[pos] = make_float4(qx01, qy01, qz01, __int_as_float(i));
  }
}

// z-pair per-cell gather (packed f16 payload) -> packed f16 grid (16B/cell).
// cells[] = pure local exclusive scan: S(b) = cells[b]+bsum[b>>11] = global START
// of bin b. Ranges: sm=S(b0-1) (z0>0), em=S(b0), e0=S(b0+1), e1=S(b0+2) or N.
__global__ void __launch_bounds__(256) p2g_gather_pair_kernel(
    const int* __restrict__ cells, const int* __restrict__ bsum,
    const half8* __restrict__ pp, const float* __restrict__ pz,
    uint4* __restrict__ gridh, int N){
  int tid = blockIdx.x*256 + threadIdx.x;   // exactly NCELLS/2 threads
  int zg = tid & 63, y = (tid >> 6) & 127, x = tid >> 13;
  int z0 = zg << 1;
  auto S = [&](int b){ return cells[b] + bsum[b >> 11]; };
  float a0[2]={0,0},a1[2]={0,0},a2[2]={0,0},a3[2]={0,0},a4[2]={0,0},a5[2]={0,0},a6[2]={0,0};
#pragma unroll
  for (int ox = 0; ox < 2; ++ox){
    int bx = x - ox; if (bx < 0) continue;
#pragma unroll
    for (int oy = 0; oy < 2; ++oy){
      int by = y - oy; if (by < 0) continue;
      int b0 = ((((bx<<7)+by)<<7)) + z0;
      int em = S(b0);
      int sm = (z0 > 0) ? S(b0-1) : em;
      int e0 = S(b0+1);
      int e1 = (b0+2 < NCELLS) ? S(b0+2) : N;
      for (int p = sm; p < e1; ++p){
        half8 P = pp[p]; float dz = pz[p];
        float pdx = (float)P[6], pdy = (float)P[7];
        float wx = ox ? pdx : 1.0f - pdx;
        float wy = oy ? pdy : 1.0f - pdy;
        float wxy = wx*wy;
        float omdz = 1.0f - dz;
        float w0 = (p < em) ? dz : ((p < e0) ? omdz : 0.0f);
        float w1 = (p < em) ? 0.0f : ((p < e0) ? dz : omdz);
        w0 *= wxy; w1 *= wxy;
        float v0=(float)P[0], v1=(float)P[1], v2=(float)P[2];
        float v3=(float)P[3], v4=(float)P[4], v5=(float)P[5];
        a0[0]=fmaf(v0,w0,a0[0]); a1[0]=fmaf(v1,w0,a1[0]); a2[0]=fmaf(v2,w0,a2[0]);
        a3[0]+=w0; a4[0]=fmaf(v3,w0,a4[0]); a5[0]=fmaf(v4,w0,a5[0]); a6[0]=fmaf(v5,w0,a6[0]);
        a0[1]=fmaf(v0,w1,a0[1]); a1[1]=fmaf(v1,w1,a1[1]); a2[1]=fmaf(v2,w1,a2[1]);
        a3[1]+=w1; a4[1]=fmaf(v3,w1,a4[1]); a5[1]=fmaf(v4,w1,a5[1]); a6[1]=fmaf(v5,w1,a6[1]);
      }
    }
  }
  int cell0 = ((((x<<7)+y)<<7)) + z0;
  uint4 g0, g1;
  g0.x = pack2h_raw(a0[0], a1[0]); g0.y = pack2h_raw(a2[0], a4[0]);
  g0.z = pack2h_raw(a5[0], a6[0]); g0.w = __float_as_uint(a3[0]);
  g1.x = pack2h_raw(a0[1], a1[1]); g1.y = pack2h_raw(a2[1], a4[1]);
  g1.z = pack2h_raw(a5[1], a6[1]); g1.w = __float_as_uint(a3[1]);
  uint4* g = gridh + cell0;
  g[0] = g0; g[1] = g1;
}

// ---------------- fused gather + MFMA MLP (K=16 chained, f16 grid) ----------------
// FROZEN (round-10 verified): noise phase-split, 125.7 us, VALUBusy 87-88%.
__global__ void __launch_bounds__(256, 4) gather_mlp_sorted_kernel(
    const float4* __restrict__ qpk,
    const uint4* __restrict__ gridh,
    const float* __restrict__ W1,  const float* __restrict__ b1,
    const float* __restrict__ W2,  const float* __restrict__ b2,
    const float* __restrict__ W3,  const float* __restrict__ b3,
    float* __restrict__ out, int M, int nblk)
{
  __shared__ __align__(16) f16  decs[4][64*DSTR]; // per-wave DEC^T [q][k<=32], 20 KB
  __shared__ __align__(16) f16  w1t[64*WSTR];     // W1^T [o][k], k padded 24->32, 5 KB
  __shared__ __align__(16) f16  w2t[64*W2STR];    // W2^T [o][k], 9 KB
  __shared__ __align__(16) float b1s[64], b2s[64];
  __shared__ __align__(16) float w3s[64*4];       // W3 rows padded to 4 floats, 1 KB

  // stage weights (block-cooperative)
  for (int i = threadIdx.x; i < 64*32; i += 256){
    int n = i >> 5, k = i & 31;
    w1t[n*WSTR + k] = (k < 24) ? (f16)W1[k*64 + n] : (f16)0.0f;
  }
  for (int i = threadIdx.x; i < 64*64; i += 256){
    int n = i >> 6, k = i & 63;
    w2t[n*W2STR + k] = (f16)W2[k*64 + n];
  }
  if (threadIdx.x < 64){ b1s[threadIdx.x] = b1[threadIdx.x]; b2s[threadIdx.x] = b2[threadIdx.x]; }
  for (int i = threadIdx.x; i < 192; i += 256){
    w3s[(i/3)*4 + (i - (i/3)*3)] = W3[i];
  }
  __syncthreads();

  int b = blockIdx.x;
  int nb8 = (nblk >> 3) << 3;
  int c = (b < nb8) ? ((b & 7)*(nblk >> 3) + (b >> 3)) : b;   // XCD-contiguous chunks
  int t = c*256 + (int)threadIdx.x;
  bool active = (t < M);
  int tc = active ? t : (M - 1);

  float4 qv = qpk[tc];
  float qx01 = qv.x, qy01 = qv.y, qz01 = qv.z;
  int m = __float_as_int(qv.w);
  float qx = qx01*127.0f, qy = qy01*127.0f, qz = qz01*127.0f;

  // ---- phase 1: all 24 noise values (pure VALU, unrolled/static) ----
  const uint32_t KSTRIDE = 3u*(uint32_t)M;
  const uint32_t HALF    = 4u*KSTRIDE;
  uint32_t m3 = 3u*(uint32_t)m;
  float nx[8], ny[8], nz[8];
#pragma unroll
  for (int k = 0; k < 8; ++k) {
    uint32_t base = (uint32_t)k*KSTRIDE + m3;
    nx[k] = noise_at(base+0u, HALF);
    ny[k] = noise_at(base+1u, HALF);
    nz[k] = noise_at(base+2u, HALF);
  }

  // ---- phase 2: 8 trilerps, fully unrolled (loads overlap across paths) ----
  float r0=0.f,r1=0.f,r2=0.f,r3=0.f,r4=0.f,r5=0.f,r6=0.f;
#pragma unroll
  for (int k = 0; k < 8; ++k) {
    float px = qx + nx[k];
    float py = qy + ny[k];
    float pz = qz + nz[k];
    float fxf = floorf(px), fyf = floorf(py), fzf = floorf(pz);
    float fx = px - fxf, fy = py - fyf, fz = pz - fzf;
    int lx = (int)fxf, ly = (int)fyf, lz = (int)fzf;
    int x0i = min(max(lx,0),127),   x1i = min(max(lx+1,0),127);
    int y0i = min(max(ly,0),127),   y1i = min(max(ly+1,0),127);
    int z0i = min(max(lz,0),127),   z1i = min(max(lz+1,0),127);
    float ex = 1.0f-fx, ey = 1.0f-fy, ez = 1.0f-fz;

    auto corner = [&](int xi,int yi,int zi,float w){
      uint4 q4 = gridh[(((xi<<7)+yi)<<7)+zi];
      union { uint32_t u; f16 h[2]; } c0, c1, c2;
      c0.u = q4.x; c1.u = q4.y; c2.u = q4.z;
      r0 = fmaf((float)c0.h[0], w, r0);
      r1 = fmaf((float)c0.h[1], w, r1);
      r2 = fmaf((float)c1.h[0], w, r2);
      r4 = fmaf((float)c1.h[1], w, r4);
      r5 = fmaf((float)c2.h[0], w, r5);
      r6 = fmaf((float)c2.h[1], w, r6);
      r3 = fmaf(__uint_as_float(q4.w), w, r3);
    };
    corner(x0i,y0i,z0i, ex*ey*ez);
    corner(x0i,y0i,z1i, ex*ey*fz);
    corner(x0i,y1i,z0i, ex*fy*ez);
    corner(x0i,y1i,z1i, ex*fy*fz);
    corner(x1i,y0i,z0i, fx*ey*ez);
    corner(x1i,y0i,z1i, fx*ey*fz);
    corner(x1i,y1i,z0i, fx*fy*ez);
    corner(x1i,y1i,z1i, fx*fy*fz);
  }

  // d-channel is f32 -> mask decision window identical to the all-f32 kernel
  float dmean = r3*0.125f;
  float denom = fmaxf(dmean, 1e-5f);
  float maskf = (dmean > 1e-5f) ? 1.0f : 0.0f;
  float s   = 0.125f/denom*maskf;
  float sfu = s * GRID_ISCALE;   // exact /1024 for the scaled f16 channels
  float un0 = r4*sfu, un1 = r5*sfu, un2 = r6*sfu;

  float dec[24];
  dec[0]=r0*sfu; dec[1]=r1*sfu; dec[2]=r2*sfu; dec[3]=un0; dec[4]=un1; dec[5]=un2;
  dec[6]  = __builtin_amdgcn_sinf(0.5f*qx01);   // v_sin input is revolutions
  dec[7]  = __builtin_amdgcn_sinf(0.5f*qy01);
  dec[8]  = __builtin_amdgcn_sinf(0.5f*qz01);
  dec[9]  = __builtin_amdgcn_cosf(0.5f*qx01);
  dec[10] = __builtin_amdgcn_cosf(0.5f*qy01);
  dec[11] = __builtin_amdgcn_cosf(0.5f*qz01);
  dec[12] = __builtin_amdgcn_sinf(qx01);
  dec[13] = __builtin_amdgcn_sinf(qy01);
  dec[14] = __builtin_amdgcn_sinf(qz01);
  dec[15] = __builtin_amdgcn_cosf(qx01);
  dec[16] = __builtin_amdgcn_cosf(qy01);
  dec[17] = __builtin_amdgcn_cosf(qz01);
  dec[18] = __builtin_amdgcn_sinf(2.0f*qx01);
  dec[19] = __builtin_amdgcn_sinf(2.0f*qy01);
  dec[20] = __builtin_amdgcn_sinf(2.0f*qz01);
  dec[21] = __builtin_amdgcn_cosf(2.0f*qx01);
  dec[22] = __builtin_amdgcn_cosf(2.0f*qy01);
  dec[23] = __builtin_amdgcn_cosf(2.0f*qz01);

  // ---- MLP via chained 16x16x16 MFMAs (verified rounds 5/6) ----
  int lane = threadIdx.x & 63;
  int wv   = threadIdx.x >> 6;
  f16* hb = &decs[wv][0];
  int lo = lane & 15;           // C col / frag m-n index
  int hi = lane >> 4;           // quad id: frag k base = 4*hi; C row base = 4*hi

  // stage dec (fp16, k padded to 32) into hb[row=lane][k]: 4x b128
  {
    half8 dh;
#pragma unroll
    for (int c4 = 0; c4 < 3; ++c4){
#pragma unroll
      for (int j = 0; j < 8; ++j) dh[j] = (f16)dec[c4*8 + j];
      *reinterpret_cast<half8*>(&hb[lane*DSTR + c4*8]) = dh;
    }
#pragma unroll
    for (int j = 0; j < 8; ++j) dh[j] = (f16)0.0f;
    *reinterpret_cast<half8*>(&hb[lane*DSTR + 24]) = dh;
  }

  half4 w1f[4][2];
#pragma unroll
  for (int a = 0; a < 4; ++a)
#pragma unroll
    for (int kb = 0; kb < 2; ++kb)
      w1f[a][kb] = *reinterpret_cast<const half4*>(&w1t[(16*a + lo)*WSTR + 16*kb + 4*hi]);

  half4 dff[4][2];
#pragma unroll
  for (int bq = 0; bq < 4; ++bq)
#pragma unroll
    for (int kb = 0; kb < 2; ++kb)
      dff[bq][kb] = *reinterpret_cast<const half4*>(&hb[(16*bq + lo)*DSTR + 16*kb + 4*hi]);

  // layer 1: H^T = W1^T @ DEC^T, C-init = bias; hv[a][bq] is layer-2 B-frag (kb=a)
  half4 hv[4][4];
#pragma unroll
  for (int a = 0; a < 4; ++a){
    f32x4 zb = *reinterpret_cast<const f32x4*>(&b1s[16*a + 4*hi]);
#pragma unroll
    for (int bq = 0; bq < 4; ++bq){
      f32x4 z = __builtin_amdgcn_mfma_f32_16x16x16f16(w1f[a][0], dff[bq][0], zb, 0, 0, 0);
      z       = __builtin_amdgcn_mfma_f32_16x16x16f16(w1f[a][1], dff[bq][1], z,  0, 0, 0);
      half4 hvv;
#pragma unroll
      for (int p = 0; p < 4; ++p) hvv[p] = (f16)gelu_f(z[p]);
      hv[a][bq] = hvv;
    }
  }

  // layer 2 + 3: G^T = W2^T @ H^T (4 chained K=16), gelu + partial W3 dots in regs
  float part[4][3];
#pragma unroll
  for (int bq = 0; bq < 4; ++bq){ part[bq][0]=0.f; part[bq][1]=0.f; part[bq][2]=0.f; }

#pragma unroll
  for (int a2 = 0; a2 < 4; ++a2){
    half4 w2f[4];
#pragma unroll
    for (int kb = 0; kb < 4; ++kb)
      w2f[kb] = *reinterpret_cast<const half4*>(&w2t[(16*a2 + lo)*W2STR + 16*kb + 4*hi]);
    f32x4 zb2 = *reinterpret_cast<const f32x4*>(&b2s[16*a2 + 4*hi]);
#pragma unroll
    for (int bq = 0; bq < 4; ++bq){
      f32x4 z = __builtin_amdgcn_mfma_f32_16x16x16f16(w2f[0], hv[0][bq], zb2, 0, 0, 0);
      z       = __builtin_amdgcn_mfma_f32_16x16x16f16(w2f[1], hv[1][bq], z,   0, 0, 0);
      z       = __builtin_amdgcn_mfma_f32_16x16x16f16(w2f[2], hv[2][bq], z,   0, 0, 0);
      z       = __builtin_amdgcn_mfma_f32_16x16x16f16(w2f[3], hv[3][bq], z,   0, 0, 0);
#pragma unroll
      for (int p = 0; p < 4; ++p){
        f32x4 w3v = *reinterpret_cast<const f32x4*>(&w3s[(16*a2 + 4*hi + p)*4]);
        float g = gelu_f(z[p]);
        part[bq][0] = fmaf(g, w3v[0], part[bq][0]);
        part[bq][1] = fmaf(g, w3v[1], part[bq][1]);
        part[bq][2] = fmaf(g, w3v[2], part[bq][2]);
      }
    }
  }

  // reduce partials across the 4 quad-groups (lanes lo+16*hi')
#pragma unroll
  for (int bq = 0; bq < 4; ++bq)
#pragma unroll
    for (int cc = 0; cc < 3; ++cc){
      float v = part[bq][cc];
      v += __shfl_xor(v, 16, 64);
      v += __shfl_xor(v, 32, 64);
      part[bq][cc] = v;
    }

  // lane L owns query q* = 16*hi + lo = L  -> select bq == hi (static select chain)
  float o0 = (hi==0) ? part[0][0] : (hi==1) ? part[1][0] : (hi==2) ? part[2][0] : part[3][0];
  float o1 = (hi==0) ? part[0][1] : (hi==1) ? part[1][1] : (hi==2) ? part[2][1] : part[3][1];
  float o2 = (hi==0) ? part[0][2] : (hi==1) ? part[1][2] : (hi==2) ? part[2][2] : part[3][2];
  o0 += b3[0]; o1 += b3[1]; o2 += b3[2];

  if (active){
    out[3*m+0] = fminf(fmaxf(un0 + o0, 0.001f), 0.999f);
    out[3*m+1] = fminf(fmaxf(un1 + o1, 0.001f), 0.999f);
    out[3*m+2] = fminf(fmaxf(un2 + o2, 0.001f), 0.999f);
  }
}

// ---------------- fallbacks (ws too small; not used in practice) ----------------
__global__ void __launch_bounds__(256) p2g_atomic_kernel(
    const float* __restrict__ xsr, const float* __restrict__ xsc,
    const float* __restrict__ Wf,  const float* __restrict__ bf,
    float* __restrict__ grid, int N)
{
  int i = blockIdx.x*256 + threadIdx.x;
  if (i >= N) return;
  float sx,sy,sz,dx,dy,dz; int bx,by,bz;
  particle_cell(xsr,i,sx,sy,sz,bx,by,bz,dx,dy,dz);
  float ux = xsc[3*i+0] - sx;
  float uy = xsc[3*i+1] - sy;
  float uz = xsc[3*i+2] - sz;
  float f0 = gelu_f(ux*Wf[0] + uy*Wf[3] + uz*Wf[6] + bf[0]);
  float f1 = gelu_f(ux*Wf[1] + uy*Wf[4] + uz*Wf[7] + bf[1]);
  float f2 = gelu_f(ux*Wf[2] + uy*Wf[5] + uz*Wf[8] + bf[2]);
  float ex = 1.0f - dx, ey = 1.0f - dy, ez = 1.0f - dz;
  auto splat = [&](int xi, int yi, int zi, float w){
    float* p = grid + ((size_t)((((xi<<7)+yi)<<7)+zi) << 3);
    unsafeAtomicAdd(p+0, f0*w);
    unsafeAtomicAdd(p+1, f1*w);
    unsafeAtomicAdd(p+2, f2*w);
    unsafeAtomicAdd(p+3, w);
    unsafeAtomicAdd(p+4, ux*w);
    unsafeAtomicAdd(p+5, uy*w);
    unsafeAtomicAdd(p+6, uz*w);
  };
  splat(bx,  by,  bz,   ex*ey*ez);
  splat(bx,  by,  bz+1, ex*ey*dz);
  splat(bx,  by+1,bz,   ex*dy*ez);
  splat(bx,  by+1,bz+1, ex*dy*dz);
  splat(bx+1,by,  bz,   dx*ey*ez);
  splat(bx+1,by,  bz+1, dx*ey*dz);
  splat(bx+1,by+1,bz,   dx*dy*ez);
  splat(bx+1,by+1,bz+1, dx*dy*dz);
}

// fallback: convert f32 grid (8 floats/cell, unscaled) -> packed f16 grid
__global__ void __launch_bounds__(256) grid2half_kernel(
    const float* __restrict__ grid, uint4* __restrict__ gridh){
  int i = blockIdx.x*256 + threadIdx.x;   // NCELLS threads
  const float4* p = reinterpret_cast<const float4*>(grid + ((size_t)i << 3));
  float4 A = p[0], B = p[1];
  uint4 g;
  g.x = pack2h_scaled(A.x, A.y);
  g.y = pack2h_scaled(A.z, B.x);
  g.z = pack2h_scaled(B.y, B.z);
  g.w = __float_as_uint(A.w);
  gridh[i] = g;
}

__global__ void __launch_bounds__(256) qident_kernel(
    const float* __restrict__ xq, float4* __restrict__ qpk, int M){
  int i = blockIdx.x*256 + threadIdx.x;
  if (i >= M) return;
  float qx01 = fminf(fmaxf(xq[3*i+0], 0.0f), 1.0f);
  float qy01 = fminf(fmaxf(xq[3*i+1], 0.0f), 1.0f);
  float qz01 = fminf(fmaxf(xq[3*i+2], 0.0f), 1.0f);
  qpk[i] = make_float4(qx01, qy01, qz01, __int_as_float(i));
}

extern "C" void kernel_launch(void* const* d_in, const int* in_sizes, int n_in,
                              void* d_out, int out_size, void* d_ws, size_t ws_size,
                              hipStream_t stream)
{
  const float* xq  = (const float*)d_in[0];
  const float* xsr = (const float*)d_in[1];
  const float* xsc = (const float*)d_in[2];
  const float* Wf  = (const float*)d_in[3];
  const float* bf  = (const float*)d_in[4];
  const float* W1  = (const float*)d_in[5];
  const float* b1  = (const float*)d_in[6];
  const float* W2  = (const float*)d_in[7];
  const float* b2  = (const float*)d_in[8];
  const float* W3  = (const float*)d_in[9];
  const float* b3  = (const float*)d_in[10];
  float* out  = (float*)d_out;
  int M = in_sizes[0]/3;
  int N = in_sizes[1]/3;

  // workspace layout: gridh (packed f16) + qpk always live; union region holds
  // EITHER the main path's sort buffers OR the fallback's 64 MB f32 grid.
  char* W = (char*)d_ws;
  size_t off = 0;
  auto alloc = [&](size_t bytes){ size_t o = off; off = (off + bytes + 255) & ~(size_t)255; return o; };
  size_t o_gridh = alloc((size_t)NCELLS * 16);            // 32 MiB packed f16 grid
  size_t o_qpk   = alloc((size_t)M * sizeof(float4));     // 8 MB
  size_t o_union = off;
  // main-path sub-offsets within the union region:
  size_t o_cells = alloc((size_t)NCELLS * sizeof(int));   // 8 MiB (cnt -> local excl scan)
  size_t o_qcnt  = alloc((size_t)NQBINS * sizeof(int));   // 128 KB (directly after cells)
  size_t o_bsum  = alloc((size_t)SCAN_BLOCKS * sizeof(int));
  size_t o_qstart= alloc((size_t)NQBINS * sizeof(int));   // 128 KB
  size_t o_pcode = alloc((size_t)N * sizeof(uint32_t));   // 2 MB
  size_t o_qcode = alloc((size_t)M * sizeof(uint32_t));   // 2 MB
  size_t o_pp    = alloc((size_t)N * sizeof(half8));      // 8 MB packed payload
  size_t o_pz    = alloc((size_t)N * sizeof(float));      // 2 MB
  size_t main_end = off;
  size_t full_end = (o_union + (size_t)NCELLS * 8 * sizeof(float) > main_end)
                  ? (o_union + (size_t)NCELLS * 8 * sizeof(float)) : main_end;

  uint4*    gridh  = (uint4*)(W + o_gridh);
  float4*   qpk    = (float4*)(W + o_qpk);
  int*      cells  = (int*)(W + o_cells);
  int*      qcnt   = (int*)(W + o_qcnt);
  int*      bsum   = (int*)(W + o_bsum);
  int*      qstart = (int*)(W + o_qstart);
  uint32_t* pcode  = (uint32_t*)(W + o_pcode);
  uint32_t* qcode  = (uint32_t*)(W + o_qcode);
  half8*    pp     = (half8*)(W + o_pp);
  float*    pz     = (float*)(W + o_pz);
  float*    gridf  = (float*)(W + o_union);   // fallback f32 grid (aliases sort buffers)

  int nthr = (N > M) ? N : M;
  int nblkNM = (nthr + 255) / 256;

  if (main_end <= ws_size) {
    hipMemsetAsync(cells, 0, (size_t)NCELLS * sizeof(int) + (size_t)NQBINS * sizeof(int), stream);
    hist2_kernel<<<nblkNM, 256, 0, stream>>>(xsr, xq, cells, qcnt, pcode, qcode, N, M);
    scan1_kernel<<<SCAN_BLOCKS, 256, 0, stream>>>(cells, bsum);
    scan2q_kernel<<<1, 1024, 0, stream>>>(bsum, qcnt, qstart);
    scatter2_kernel<<<nblkNM, 256, 0, stream>>>(xsr, xsc, Wf, bf, xq, cells, bsum, qstart,
                                                pcode, qcode, pp, pz, qpk, N, M);
    p2g_gather_pair_kernel<<<(NCELLS/2)/256, 256, 0, stream>>>(cells, bsum, pp, pz, gridh, N);
  } else {
    // fallback: f32 atomic grid in the union region, convert to packed gridh
    (void)full_end;
    hipMemsetAsync(gridf, 0, (size_t)NCELLS * 8 * sizeof(float), stream);
    p2g_atomic_kernel<<<(N+255)/256, 256, 0, stream>>>(xsr, xsc, Wf, bf, gridf, N);
    grid2half_kernel<<<NCELLS/256, 256, 0, stream>>>(gridf, gridh);
    qident_kernel<<<(M+255)/256, 256, 0, stream>>>(xq, qpk, M);
  }

  int nblk = (M + 255) / 256;
  gather_mlp_sorted_kernel<<<nblk, 256, 0, stream>>>(qpk, gridh, W1,b1,W2,b2,W3,b3, out, M, nblk);
}

// Round 12
// 311.041 us; speedup vs baseline: 3.4444x; 1.0013x over previous
//
#include <hip/hip_runtime.h>
#include <cstdint>

#ifndef JAX_PARTITIONABLE
#define JAX_PARTITIONABLE 1   // modern JAX (>=0.5) default threefry_partitionable
#endif

#define NCELLS (128*128*128)          // 2,097,152
#define SCAN_BLOCKS 1024              // NCELLS / 2048
#define NQBINS (32*32*32)             // coarse query bins (4x4x4 cells each)

typedef _Float16 f16;
typedef f16  half8 __attribute__((ext_vector_type(8)));
typedef f16  half4 __attribute__((ext_vector_type(4)));
typedef float f32x4 __attribute__((ext_vector_type(4)));

#define WSTR 40   // row stride (halfs) for [64][32] W1^T tile
#define DSTR 40   // row stride (halfs) for per-wave [64][32] DEC tile
#define W2STR 72  // row stride (halfs) for [64][64] W2^T tile

// Packed grid cell (16B): u32[0]=(f0,f1) u32[1]=(f2,u0) u32[2]=(u1,u2) as f16 x1024;
// u32[3] = d in f32. d stays f32: the dmean>1e-5 mask boundary amplifies
// d-perturbations (round-2 lesson class). x1024 (exact pow2) lifts f/u out of f16
// subnormals and cancels exactly via sfu = s/1024.
// NOTE (round-7 lesson): device-scope atomics on gfx950 write through to HBM
// (~32B/atomic, no L2 accumulation). Round-11: scatter atomic-free (hist ranks).
// Round-12: cell counters u16-packed 2-per-int (table 8->4MB, scan traffic halved);
// payload computed once in hist2, scatter2 = pure permute.
#define GRID_SCALE 1024.0f
#define GRID_ISCALE 0.0009765625f

// ---------------- Threefry-2x32, key = (0, 42)  (jax.random.key(42)) ----------------
__device__ __forceinline__ uint32_t rotl32(uint32_t v, int s){ return (v << s) | (v >> (32 - s)); }

__device__ __forceinline__ void tf2x32(uint32_t& x0, uint32_t& x1){
  const uint32_t k0 = 0u, k1 = 42u;
  const uint32_t k2 = 0x1BD11BDAu ^ k0 ^ k1;
  x0 += k0; x1 += k1;
#define TFR(r) { x0 += x1; x1 = rotl32(x1,(r)); x1 ^= x0; }
  TFR(13) TFR(15) TFR(26) TFR(6)
  x0 += k1; x1 += k2 + 1u;
  TFR(17) TFR(29) TFR(16) TFR(24)
  x0 += k2; x1 += k0 + 2u;
  TFR(13) TFR(15) TFR(26) TFR(6)
  x0 += k0; x1 += k1 + 3u;
  TFR(17) TFR(29) TFR(16) TFR(24)
  x0 += k1; x1 += k2 + 4u;
  TFR(13) TFR(15) TFR(26) TFR(6)
  x0 += k2; x1 += k0 + 5u;
#undef TFR
}

// XLA f32 ErfInv (Giles) — exact coefficient match with jax/XLA.
// NOTE: must stay BIT-EXACT (log1pf, not a log2 rewrite): noise feeds
// f_norm = r0/max(r3,1e-5), whose derivative -f_norm/r3 amplifies ~1e-6
// noise shifts to ~1e-2 output error in sparse regions (round-2 fail).
__device__ __forceinline__ float erfinv_xla(float x){
  float w = -log1pf(-x*x);
  float p;
  if (w < 5.0f){
    w -= 2.5f;
    p =  2.81022636e-08f;
    p = fmaf(p,w, 3.43273939e-07f);
    p = fmaf(p,w,-3.5233877e-06f);
    p = fmaf(p,w,-4.39150654e-06f);
    p = fmaf(p,w, 0.00021858087f);
    p = fmaf(p,w,-0.00125372503f);
    p = fmaf(p,w,-0.00417768164f);
    p = fmaf(p,w, 0.246640727f);
    p = fmaf(p,w, 1.50140941f);
  } else {
    w = sqrtf(w) - 3.0f;
    p = -0.000200214257f;
    p = fmaf(p,w, 0.000100950558f);
    p = fmaf(p,w, 0.00134934322f);
    p = fmaf(p,w,-0.00367342844f);
    p = fmaf(p,w, 0.00573950773f);
    p = fmaf(p,w,-0.0076224613f);
    p = fmaf(p,w, 0.00943887047f);
    p = fmaf(p,w, 1.00167406f);
    p = fmaf(p,w, 2.83297682f);
  }
  return p*x;
}

// noise[i] = 0.8 * sqrt(2)*erfinv(uniform(-1,1)) with jax bit semantics
__device__ __forceinline__ float noise_at(uint32_t idx, uint32_t half){
#if JAX_PARTITIONABLE
  (void)half;
  uint32_t x0 = 0u, x1 = idx;     // counter = (hi=0, lo=i)
  tf2x32(x0, x1);
  uint32_t bits = x0 ^ x1;        // partitionable 32-bit path: xor-fold of both words
#else
  uint32_t j  = (idx < half) ? idx : (idx - half);
  uint32_t x0 = j, x1 = j + half;
  tf2x32(x0, x1);
  uint32_t bits = (idx < half) ? x0 : x1;
#endif
  float f = __uint_as_float((bits >> 9) | 0x3f800000u) - 1.0f;      // [0,1)
  float u = fmaxf(-0.99999994f, fmaf(f, 2.0f, -0.99999994f));       // (-1,1)
  return (1.41421356f * erfinv_xla(u)) * 0.8f;
}

// jax.nn.gelu approximate=True — minimal-op form (round-6 verified; the round-8
// exp2f rewrite used the PRECISE ocml entry and regressed — keep __expf).
__device__ __forceinline__ float gelu_f(float x){
  float t = x*x;
  float inner = x * fmaf(0.035677408136f, t, 0.7978845608028654f);
  float e = __expf(2.0f * inner);
  float r = __builtin_amdgcn_rcpf(e + 1.0f);
  return x - x*r;
}

__device__ __forceinline__ uint32_t pack2h_scaled(float a, float b){
  union { f16 h[2]; uint32_t u; } c;
  c.h[0] = (f16)(a * GRID_SCALE);
  c.h[1] = (f16)(b * GRID_SCALE);
  return c.u;
}
__device__ __forceinline__ uint32_t pack2h_raw(float a, float b){
  union { f16 h[2]; uint32_t u; } c;
  c.h[0] = (f16)a;
  c.h[1] = (f16)b;
  return c.u;
}

// common per-particle geometry
__device__ __forceinline__ void particle_cell(const float* xsr, int i,
                                              float& sx, float& sy, float& sz,
                                              int& bx, int& by, int& bz,
                                              float& dx, float& dy, float& dz){
  sx = fminf(fmaxf(xsr[3*i+0], 0.0f), 1.0f);
  sy = fminf(fmaxf(xsr[3*i+1], 0.0f), 1.0f);
  sz = fminf(fmaxf(xsr[3*i+2], 0.0f), 1.0f);
  float cx = fminf(fmaxf(sx*127.0f, 0.0f), 126.999f);
  float cy = fminf(fmaxf(sy*127.0f, 0.0f), 126.999f);
  float cz = fminf(fmaxf(sz*127.0f, 0.0f), 126.999f);
  float bxf = floorf(cx), byf = floorf(cy), bzf = floorf(cz);
  bx = (int)bxf; by = (int)byf; bz = (int)bzf;
  dx = cx - bxf; dy = cy - byf; dz = cz - bzf;
}

__device__ __forceinline__ int qbin_of(float qx01, float qy01, float qz01){
  int bx = min((int)(qx01*127.0f), 127) >> 2;
  int by = min((int)(qy01*127.0f), 127) >> 2;
  int bz = min((int)(qz01*127.0f), 127) >> 2;
  return (((bx<<5)+by)<<5)+bz;
}

// ---------------- fused histogram + rank capture + payload compute ----------------
// u16 cell counters packed 2-per-int: atomicAdd(1<<16*(bin&1)) — low half max ~8
// (Poisson lam=0.24) so no carry into high half. rank = old>>16*(bin&1).
// Payload computed HERE once (stored unsorted); scatter2 becomes a pure permute.
__global__ void __launch_bounds__(256) hist2_kernel(
    const float* __restrict__ xsr, const float* __restrict__ xsc,
    const float* __restrict__ Wf,  const float* __restrict__ bf,
    const float* __restrict__ xq,
    int* __restrict__ cells32, int* __restrict__ qcnt,
    uint32_t* __restrict__ pcode, uint32_t* __restrict__ qcode,
    half8* __restrict__ pp_u, float* __restrict__ pz_u, int N, int M){
  int i = blockIdx.x*256 + threadIdx.x;
  if (i < N){
    float sx,sy,sz,dx,dy,dz; int bx,by,bz;
    particle_cell(xsr,i,sx,sy,sz,bx,by,bz,dx,dy,dz);
    float ux = xsc[3*i+0] - sx;
    float uy = xsc[3*i+1] - sy;
    float uz = xsc[3*i+2] - sz;
    float f0 = gelu_f(ux*Wf[0] + uy*Wf[3] + uz*Wf[6] + bf[0]);
    float f1 = gelu_f(ux*Wf[1] + uy*Wf[4] + uz*Wf[7] + bf[1]);
    float f2 = gelu_f(ux*Wf[2] + uy*Wf[5] + uz*Wf[8] + bf[2]);
    int bin = (((bx<<7)+by)<<7)+bz;
    int sh = (bin & 1) << 4;
    uint32_t old = (uint32_t)atomicAdd(&cells32[bin >> 1], 1 << sh);
    uint32_t rank = (old >> sh) & 2047u;
    pcode[i] = ((uint32_t)bin << 11) | rank;
    half8 ph;
    ph[0] = (f16)(f0*GRID_SCALE); ph[1] = (f16)(f1*GRID_SCALE); ph[2] = (f16)(f2*GRID_SCALE);
    ph[3] = (f16)(ux*GRID_SCALE); ph[4] = (f16)(uy*GRID_SCALE); ph[5] = (f16)(uz*GRID_SCALE);
    ph[6] = (f16)dx; ph[7] = (f16)dy;
    pp_u[i] = ph;
    pz_u[i] = dz;
  }
  if (i < M){
    float qx01 = fminf(fmaxf(xq[3*i+0], 0.0f), 1.0f);
    float qy01 = fminf(fmaxf(xq[3*i+1], 0.0f), 1.0f);
    float qz01 = fminf(fmaxf(xq[3*i+2], 0.0f), 1.0f);
    int qb = qbin_of(qx01,qy01,qz01);
    uint32_t rank = (uint32_t)atomicAdd(&qcnt[qb], 1);
    qcode[i] = ((uint32_t)qb << 17) | rank;
  }
}

// scan stage 1, IN-PLACE on u16-packed counters: each int4 = 8 cells.
// Block covers 2048 cells = 1024 ints; thread t handles 8 cells (4 ints).
// Local exclusive-scan values <= block total (~Poisson(492)) — fits u16 (90x margin).
__global__ void __launch_bounds__(256) scan1_kernel(int* __restrict__ cells32,
                                                    int* __restrict__ bsum){
  __shared__ int lds[256];
  int t = threadIdx.x;
  int base = blockIdx.x*1024 + t*4;
  int4 a = *reinterpret_cast<const int4*>(cells32 + base);
  int c0 =  a.x        & 0xFFFF, c1 = ((uint32_t)a.x) >> 16;
  int c2 =  a.y        & 0xFFFF, c3 = ((uint32_t)a.y) >> 16;
  int c4 =  a.z        & 0xFFFF, c5 = ((uint32_t)a.z) >> 16;
  int c6 =  a.w        & 0xFFFF, c7 = ((uint32_t)a.w) >> 16;
  int s = c0+c1+c2+c3+c4+c5+c6+c7;
  lds[t] = s; __syncthreads();
  for (int off = 1; off < 256; off <<= 1){
    int v = (t >= off) ? lds[t-off] : 0;
    __syncthreads();
    lds[t] += v;
    __syncthreads();
  }
  int e = lds[t] - s;
  if (t == 255) bsum[blockIdx.x] = lds[255];
  int4 o;
  o.x = e | ((e + c0) << 16); e += c0 + c1;
  o.y = e | ((e + c2) << 16); e += c2 + c3;
  o.z = e | ((e + c4) << 16); e += c4 + c5;
  o.w = e | ((e + c6) << 16);
  *reinterpret_cast<int4*>(cells32 + base) = o;
}

// fused: exclusive scan of bsum (particle block sums) + full exclusive scan of qcnt
// qstart[] = exclusive bin starts (read-only downstream — no bump).
__global__ void __launch_bounds__(1024) scan2q_kernel(int* __restrict__ bsum,
                                                      const int* __restrict__ qcnt,
                                                      int* __restrict__ qstart){
  __shared__ int lds[1024];
  int t = threadIdx.x;
  int v = bsum[t];
  lds[t] = v; __syncthreads();
  for (int off = 1; off < 1024; off <<= 1){
    int u = (t >= off) ? lds[t-off] : 0;
    __syncthreads();
    lds[t] += u;
    __syncthreads();
  }
  bsum[t] = lds[t] - v;
  __syncthreads();
  int base = t*32;
  int loc[32];
  int s = 0;
#pragma unroll
  for (int j = 0; j < 32; ++j){ loc[j] = qcnt[base+j]; s += loc[j]; }
  lds[t] = s; __syncthreads();
  for (int off = 1; off < 1024; off <<= 1){
    int u = (t >= off) ? lds[t-off] : 0;
    __syncthreads();
    lds[t] += u;
    __syncthreads();
  }
  int run = lds[t] - s;
#pragma unroll
  for (int j = 0; j < 32; ++j){ qstart[base+j] = run; run += loc[j]; }
}

// ATOMIC-FREE scatter, now a pure permute for particles (payload precomputed in
// hist2): pos = S(bin) + rank. Query side builds sorted qpk from xq + qcode.
__global__ void __launch_bounds__(256) scatter2_kernel(
    const float* __restrict__ xq,
    const int* __restrict__ cells32, const int* __restrict__ bsum,
    const int* __restrict__ qstart,
    const uint32_t* __restrict__ pcode, const uint32_t* __restrict__ qcode,
    const half8* __restrict__ pp_u, const float* __restrict__ pz_u,
    half8* __restrict__ pp, float* __restrict__ pz,
    float4* __restrict__ qpk, int N, int M){
  int i = blockIdx.x*256 + threadIdx.x;
  if (i < N){
    const uint16_t* cells16 = reinterpret_cast<const uint16_t*>(cells32);
    uint32_t pc = pcode[i];
    int bin  = (int)(pc >> 11);
    int rank = (int)(pc & 2047u);
    int pos = (int)cells16[bin] + bsum[bin >> 11] + rank;
    pp[pos] = pp_u[i];
    pz[pos] = pz_u[i];
  }
  if (i < M){
    float qx01 = fminf(fmaxf(xq[3*i+0], 0.0f), 1.0f);
    float qy01 = fminf(fmaxf(xq[3*i+1], 0.0f), 1.0f);
    float qz01 = fminf(fmaxf(xq[3*i+2], 0.0f), 1.0f);
    uint32_t qc = qcode[i];
    int qb   = (int)(qc >> 17);
    int rank = (int)(qc & 131071u);
    int pos = qstart[qb] + rank;
    qpk[pos] = make_float4(qx01, qy01, qz01, __int_as_float(i));
  }
}

// z-pair per-cell gather (packed f16 payload) -> packed f16 grid (16B/cell).
// S(b) = cells16[b] + bsum[b>>11] = global START of bin b (u16 local scan + block base).
__global__ void __launch_bounds__(256) p2g_gather_pair_kernel(
    const int* __restrict__ cells32, const int* __restrict__ bsum,
    const half8* __restrict__ pp, const float* __restrict__ pz,
    uint4* __restrict__ gridh, int N){
  int tid = blockIdx.x*256 + threadIdx.x;   // exactly NCELLS/2 threads
  int zg = tid & 63, y = (tid >> 6) & 127, x = tid >> 13;
  int z0 = zg << 1;
  const uint16_t* cells16 = reinterpret_cast<const uint16_t*>(cells32);
  auto S = [&](int b){ return (int)cells16[b] + bsum[b >> 11]; };
  float a0[2]={0,0},a1[2]={0,0},a2[2]={0,0},a3[2]={0,0},a4[2]={0,0},a5[2]={0,0},a6[2]={0,0};
#pragma unroll
  for (int ox = 0; ox < 2; ++ox){
    int bx = x - ox; if (bx < 0) continue;
#pragma unroll
    for (int oy = 0; oy < 2; ++oy){
      int by = y - oy; if (by < 0) continue;
      int b0 = ((((bx<<7)+by)<<7)) + z0;
      int em = S(b0);
      int sm = (z0 > 0) ? S(b0-1) : em;
      int e0 = S(b0+1);
      int e1 = (b0+2 < NCELLS) ? S(b0+2) : N;
      for (int p = sm; p < e1; ++p){
        half8 P = pp[p]; float dz = pz[p];
        float pdx = (float)P[6], pdy = (float)P[7];
        float wx = ox ? pdx : 1.0f - pdx;
        float wy = oy ? pdy : 1.0f - pdy;
        float wxy = wx*wy;
        float omdz = 1.0f - dz;
        float w0 = (p < em) ? dz : ((p < e0) ? omdz : 0.0f);
        float w1 = (p < em) ? 0.0f : ((p < e0) ? dz : omdz);
        w0 *= wxy; w1 *= wxy;
        float v0=(float)P[0], v1=(float)P[1], v2=(float)P[2];
        float v3=(float)P[3], v4=(float)P[4], v5=(float)P[5];
        a0[0]=fmaf(v0,w0,a0[0]); a1[0]=fmaf(v1,w0,a1[0]); a2[0]=fmaf(v2,w0,a2[0]);
        a3[0]+=w0; a4[0]=fmaf(v3,w0,a4[0]); a5[0]=fmaf(v4,w0,a5[0]); a6[0]=fmaf(v5,w0,a6[0]);
        a0[1]=fmaf(v0,w1,a0[1]); a1[1]=fmaf(v1,w1,a1[1]); a2[1]=fmaf(v2,w1,a2[1]);
        a3[1]+=w1; a4[1]=fmaf(v3,w1,a4[1]); a5[1]=fmaf(v4,w1,a5[1]); a6[1]=fmaf(v5,w1,a6[1]);
      }
    }
  }
  int cell0 = ((((x<<7)+y)<<7)) + z0;
  uint4 g0, g1;
  g0.x = pack2h_raw(a0[0], a1[0]); g0.y = pack2h_raw(a2[0], a4[0]);
  g0.z = pack2h_raw(a5[0], a6[0]); g0.w = __float_as_uint(a3[0]);
  g1.x = pack2h_raw(a0[1], a1[1]); g1.y = pack2h_raw(a2[1], a4[1]);
  g1.z = pack2h_raw(a5[1], a6[1]); g1.w = __float_as_uint(a3[1]);
  uint4* g = gridh + cell0;
  g[0] = g0; g[1] = g1;
}

// ---------------- fused gather + MFMA MLP (K=16 chained, f16 grid) ----------------
// FROZEN (round-10 verified): noise phase-split, ~126 us, VALUBusy 87-88%.
__global__ void __launch_bounds__(256, 4) gather_mlp_sorted_kernel(
    const float4* __restrict__ qpk,
    const uint4* __restrict__ gridh,
    const float* __restrict__ W1,  const float* __restrict__ b1,
    const float* __restrict__ W2,  const float* __restrict__ b2,
    const float* __restrict__ W3,  const float* __restrict__ b3,
    float* __restrict__ out, int M, int nblk)
{
  __shared__ __align__(16) f16  decs[4][64*DSTR]; // per-wave DEC^T [q][k<=32], 20 KB
  __shared__ __align__(16) f16  w1t[64*WSTR];     // W1^T [o][k], k padded 24->32, 5 KB
  __shared__ __align__(16) f16  w2t[64*W2STR];    // W2^T [o][k], 9 KB
  __shared__ __align__(16) float b1s[64], b2s[64];
  __shared__ __align__(16) float w3s[64*4];       // W3 rows padded to 4 floats, 1 KB

  // stage weights (block-cooperative)
  for (int i = threadIdx.x; i < 64*32; i += 256){
    int n = i >> 5, k = i & 31;
    w1t[n*WSTR + k] = (k < 24) ? (f16)W1[k*64 + n] : (f16)0.0f;
  }
  for (int i = threadIdx.x; i < 64*64; i += 256){
    int n = i >> 6, k = i & 63;
    w2t[n*W2STR + k] = (f16)W2[k*64 + n];
  }
  if (threadIdx.x < 64){ b1s[threadIdx.x] = b1[threadIdx.x]; b2s[threadIdx.x] = b2[threadIdx.x]; }
  for (int i = threadIdx.x; i < 192; i += 256){
    w3s[(i/3)*4 + (i - (i/3)*3)] = W3[i];
  }
  __syncthreads();

  int b = blockIdx.x;
  int nb8 = (nblk >> 3) << 3;
  int c = (b < nb8) ? ((b & 7)*(nblk >> 3) + (b >> 3)) : b;   // XCD-contiguous chunks
  int t = c*256 + (int)threadIdx.x;
  bool active = (t < M);
  int tc = active ? t : (M - 1);

  float4 qv = qpk[tc];
  float qx01 = qv.x, qy01 = qv.y, qz01 = qv.z;
  int m = __float_as_int(qv.w);
  float qx = qx01*127.0f, qy = qy01*127.0f, qz = qz01*127.0f;

  // ---- phase 1: all 24 noise values (pure VALU, unrolled/static) ----
  const uint32_t KSTRIDE = 3u*(uint32_t)M;
  const uint32_t HALF    = 4u*KSTRIDE;
  uint32_t m3 = 3u*(uint32_t)m;
  float nx[8], ny[8], nz[8];
#pragma unroll
  for (int k = 0; k < 8; ++k) {
    uint32_t base = (uint32_t)k*KSTRIDE + m3;
    nx[k] = noise_at(base+0u, HALF);
    ny[k] = noise_at(base+1u, HALF);
    nz[k] = noise_at(base+2u, HALF);
  }

  // ---- phase 2: 8 trilerps, fully unrolled (loads overlap across paths) ----
  float r0=0.f,r1=0.f,r2=0.f,r3=0.f,r4=0.f,r5=0.f,r6=0.f;
#pragma unroll
  for (int k = 0; k < 8; ++k) {
    float px = qx + nx[k];
    float py = qy + ny[k];
    float pz = qz + nz[k];
    float fxf = floorf(px), fyf = floorf(py), fzf = floorf(pz);
    float fx = px - fxf, fy = py - fyf, fz = pz - fzf;
    int lx = (int)fxf, ly = (int)fyf, lz = (int)fzf;
    int x0i = min(max(lx,0),127),   x1i = min(max(lx+1,0),127);
    int y0i = min(max(ly,0),127),   y1i = min(max(ly+1,0),127);
    int z0i = min(max(lz,0),127),   z1i = min(max(lz+1,0),127);
    float ex = 1.0f-fx, ey = 1.0f-fy, ez = 1.0f-fz;

    auto corner = [&](int xi,int yi,int zi,float w){
      uint4 q4 = gridh[(((xi<<7)+yi)<<7)+zi];
      union { uint32_t u; f16 h[2]; } c0, c1, c2;
      c0.u = q4.x; c1.u = q4.y; c2.u = q4.z;
      r0 = fmaf((float)c0.h[0], w, r0);
      r1 = fmaf((float)c0.h[1], w, r1);
      r2 = fmaf((float)c1.h[0], w, r2);
      r4 = fmaf((float)c1.h[1], w, r4);
      r5 = fmaf((float)c2.h[0], w, r5);
      r6 = fmaf((float)c2.h[1], w, r6);
      r3 = fmaf(__uint_as_float(q4.w), w, r3);
    };
    corner(x0i,y0i,z0i, ex*ey*ez);
    corner(x0i,y0i,z1i, ex*ey*fz);
    corner(x0i,y1i,z0i, ex*fy*ez);
    corner(x0i,y1i,z1i, ex*fy*fz);
    corner(x1i,y0i,z0i, fx*ey*ez);
    corner(x1i,y0i,z1i, fx*ey*fz);
    corner(x1i,y1i,z0i, fx*fy*ez);
    corner(x1i,y1i,z1i, fx*fy*fz);
  }

  // d-channel is f32 -> mask decision window identical to the all-f32 kernel
  float dmean = r3*0.125f;
  float denom = fmaxf(dmean, 1e-5f);
  float maskf = (dmean > 1e-5f) ? 1.0f : 0.0f;
  float s   = 0.125f/denom*maskf;
  float sfu = s * GRID_ISCALE;   // exact /1024 for the scaled f16 channels
  float un0 = r4*sfu, un1 = r5*sfu, un2 = r6*sfu;

  float dec[24];
  dec[0]=r0*sfu; dec[1]=r1*sfu; dec[2]=r2*sfu; dec[3]=un0; dec[4]=un1; dec[5]=un2;
  dec[6]  = __builtin_amdgcn_sinf(0.5f*qx01);   // v_sin input is revolutions
  dec[7]  = __builtin_amdgcn_sinf(0.5f*qy01);
  dec[8]  = __builtin_amdgcn_sinf(0.5f*qz01);
  dec[9]  = __builtin_amdgcn_cosf(0.5f*qx01);
  dec[10] = __builtin_amdgcn_cosf(0.5f*qy01);
  dec[11] = __builtin_amdgcn_cosf(0.5f*qz01);
  dec[12] = __builtin_amdgcn_sinf(qx01);
  dec[13] = __builtin_amdgcn_sinf(qy01);
  dec[14] = __builtin_amdgcn_sinf(qz01);
  dec[15] = __builtin_amdgcn_cosf(qx01);
  dec[16] = __builtin_amdgcn_cosf(qy01);
  dec[17] = __builtin_amdgcn_cosf(qz01);
  dec[18] = __builtin_amdgcn_sinf(2.0f*qx01);
  dec[19] = __builtin_amdgcn_sinf(2.0f*qy01);
  dec[20] = __builtin_amdgcn_sinf(2.0f*qz01);
  dec[21] = __builtin_amdgcn_cosf(2.0f*qx01);
  dec[22] = __builtin_amdgcn_cosf(2.0f*qy01);
  dec[23] = __builtin_amdgcn_cosf(2.0f*qz01);

  // ---- MLP via chained 16x16x16 MFMAs (verified rounds 5/6) ----
  int lane = threadIdx.x & 63;
  int wv   = threadIdx.x >> 6;
  f16* hb = &decs[wv][0];
  int lo = lane & 15;           // C col / frag m-n index
  int hi = lane >> 4;           // quad id: frag k base = 4*hi; C row base = 4*hi

  // stage dec (fp16, k padded to 32) into hb[row=lane][k]: 4x b128
  {
    half8 dh;
#pragma unroll
    for (int c4 = 0; c4 < 3; ++c4){
#pragma unroll
      for (int j = 0; j < 8; ++j) dh[j] = (f16)dec[c4*8 + j];
      *reinterpret_cast<half8*>(&hb[lane*DSTR + c4*8]) = dh;
    }
#pragma unroll
    for (int j = 0; j < 8; ++j) dh[j] = (f16)0.0f;
    *reinterpret_cast<half8*>(&hb[lane*DSTR + 24]) = dh;
  }

  half4 w1f[4][2];
#pragma unroll
  for (int a = 0; a < 4; ++a)
#pragma unroll
    for (int kb = 0; kb < 2; ++kb)
      w1f[a][kb] = *reinterpret_cast<const half4*>(&w1t[(16*a + lo)*WSTR + 16*kb + 4*hi]);

  half4 dff[4][2];
#pragma unroll
  for (int bq = 0; bq < 4; ++bq)
#pragma unroll
    for (int kb = 0; kb < 2; ++kb)
      dff[bq][kb] = *reinterpret_cast<const half4*>(&hb[(16*bq + lo)*DSTR + 16*kb + 4*hi]);

  // layer 1: H^T = W1^T @ DEC^T, C-init = bias; hv[a][bq] is layer-2 B-frag (kb=a)
  half4 hv[4][4];
#pragma unroll
  for (int a = 0; a < 4; ++a){
    f32x4 zb = *reinterpret_cast<const f32x4*>(&b1s[16*a + 4*hi]);
#pragma unroll
    for (int bq = 0; bq < 4; ++bq){
      f32x4 z = __builtin_amdgcn_mfma_f32_16x16x16f16(w1f[a][0], dff[bq][0], zb, 0, 0, 0);
      z       = __builtin_amdgcn_mfma_f32_16x16x16f16(w1f[a][1], dff[bq][1], z,  0, 0, 0);
      half4 hvv;
#pragma unroll
      for (int p = 0; p < 4; ++p) hvv[p] = (f16)gelu_f(z[p]);
      hv[a][bq] = hvv;
    }
  }

  // layer 2 + 3: G^T = W2^T @ H^T (4 chained K=16), gelu + partial W3 dots in regs
  float part[4][3];
#pragma unroll
  for (int bq = 0; bq < 4; ++bq){ part[bq][0]=0.f; part[bq][1]=0.f; part[bq][2]=0.f; }

#pragma unroll
  for (int a2 = 0; a2 < 4; ++a2){
    half4 w2f[4];
#pragma unroll
    for (int kb = 0; kb < 4; ++kb)
      w2f[kb] = *reinterpret_cast<const half4*>(&w2t[(16*a2 + lo)*W2STR + 16*kb + 4*hi]);
    f32x4 zb2 = *reinterpret_cast<const f32x4*>(&b2s[16*a2 + 4*hi]);
#pragma unroll
    for (int bq = 0; bq < 4; ++bq){
      f32x4 z = __builtin_amdgcn_mfma_f32_16x16x16f16(w2f[0], hv[0][bq], zb2, 0, 0, 0);
      z       = __builtin_amdgcn_mfma_f32_16x16x16f16(w2f[1], hv[1][bq], z,   0, 0, 0);
      z       = __builtin_amdgcn_mfma_f32_16x16x16f16(w2f[2], hv[2][bq], z,   0, 0, 0);
      z       = __builtin_amdgcn_mfma_f32_16x16x16f16(w2f[3], hv[3][bq], z,   0, 0, 0);
#pragma unroll
      for (int p = 0; p < 4; ++p){
        f32x4 w3v = *reinterpret_cast<const f32x4*>(&w3s[(16*a2 + 4*hi + p)*4]);
        float g = gelu_f(z[p]);
        part[bq][0] = fmaf(g, w3v[0], part[bq][0]);
        part[bq][1] = fmaf(g, w3v[1], part[bq][1]);
        part[bq][2] = fmaf(g, w3v[2], part[bq][2]);
      }
    }
  }

  // reduce partials across the 4 quad-groups (lanes lo+16*hi')
#pragma unroll
  for (int bq = 0; bq < 4; ++bq)
#pragma unroll
    for (int cc = 0; cc < 3; ++cc){
      float v = part[bq][cc];
      v += __shfl_xor(v, 16, 64);
      v += __shfl_xor(v, 32, 64);
      part[bq][cc] = v;
    }

  // lane L owns query q* = 16*hi + lo = L  -> select bq == hi (static select chain)
  float o0 = (hi==0) ? part[0][0] : (hi==1) ? part[1][0] : (hi==2) ? part[2][0] : part[3][0];
  float o1 = (hi==0) ? part[0][1] : (hi==1) ? part[1][1] : (hi==2) ? part[2][1] : part[3][1];
  float o2 = (hi==0) ? part[0][2] : (hi==1) ? part[1][2] : (hi==2) ? part[2][2] : part[3][2];
  o0 += b3[0]; o1 += b3[1]; o2 += b3[2];

  if (active){
    out[3*m+0] = fminf(fmaxf(un0 + o0, 0.001f), 0.999f);
    out[3*m+1] = fminf(fmaxf(un1 + o1, 0.001f), 0.999f);
    out[3*m+2] = fminf(fmaxf(un2 + o2, 0.001f), 0.999f);
  }
}

// ---------------- fallbacks (ws too small; not used in practice) ----------------
__global__ void __launch_bounds__(256) p2g_atomic_kernel(
    const float* __restrict__ xsr, const float* __restrict__ xsc,
    const float* __restrict__ Wf,  const float* __restrict__ bf,
    float* __restrict__ grid, int N)
{
  int i = blockIdx.x*256 + threadIdx.x;
  if (i >= N) return;
  float sx,sy,sz,dx,dy,dz; int bx,by,bz;
  particle_cell(xsr,i,sx,sy,sz,bx,by,bz,dx,dy,dz);
  float ux = xsc[3*i+0] - sx;
  float uy = xsc[3*i+1] - sy;
  float uz = xsc[3*i+2] - sz;
  float f0 = gelu_f(ux*Wf[0] + uy*Wf[3] + uz*Wf[6] + bf[0]);
  float f1 = gelu_f(ux*Wf[1] + uy*Wf[4] + uz*Wf[7] + bf[1]);
  float f2 = gelu_f(ux*Wf[2] + uy*Wf[5] + uz*Wf[8] + bf[2]);
  float ex = 1.0f - dx, ey = 1.0f - dy, ez = 1.0f - dz;
  auto splat = [&](int xi, int yi, int zi, float w){
    float* p = grid + ((size_t)((((xi<<7)+yi)<<7)+zi) << 3);
    unsafeAtomicAdd(p+0, f0*w);
    unsafeAtomicAdd(p+1, f1*w);
    unsafeAtomicAdd(p+2, f2*w);
    unsafeAtomicAdd(p+3, w);
    unsafeAtomicAdd(p+4, ux*w);
    unsafeAtomicAdd(p+5, uy*w);
    unsafeAtomicAdd(p+6, uz*w);
  };
  splat(bx,  by,  bz,   ex*ey*ez);
  splat(bx,  by,  bz+1, ex*ey*dz);
  splat(bx,  by+1,bz,   ex*dy*ez);
  splat(bx,  by+1,bz+1, ex*dy*dz);
  splat(bx+1,by,  bz,   dx*ey*ez);
  splat(bx+1,by,  bz+1, dx*ey*dz);
  splat(bx+1,by+1,bz,   dx*dy*ez);
  splat(bx+1,by+1,bz+1, dx*dy*dz);
}

// fallback: convert f32 grid (8 floats/cell, unscaled) -> packed f16 grid
__global__ void __launch_bounds__(256) grid2half_kernel(
    const float* __restrict__ grid, uint4* __restrict__ gridh){
  int i = blockIdx.x*256 + threadIdx.x;   // NCELLS threads
  const float4* p = reinterpret_cast<const float4*>(grid + ((size_t)i << 3));
  float4 A = p[0], B = p[1];
  uint4 g;
  g.x = pack2h_scaled(A.x, A.y);
  g.y = pack2h_scaled(A.z, B.x);
  g.z = pack2h_scaled(B.y, B.z);
  g.w = __float_as_uint(A.w);
  gridh[i] = g;
}

__global__ void __launch_bounds__(256) qident_kernel(
    const float* __restrict__ xq, float4* __restrict__ qpk, int M){
  int i = blockIdx.x*256 + threadIdx.x;
  if (i >= M) return;
  float qx01 = fminf(fmaxf(xq[3*i+0], 0.0f), 1.0f);
  float qy01 = fminf(fmaxf(xq[3*i+1], 0.0f), 1.0f);
  float qz01 = fminf(fmaxf(xq[3*i+2], 0.0f), 1.0f);
  qpk[i] = make_float4(qx01, qy01, qz01, __int_as_float(i));
}

extern "C" void kernel_launch(void* const* d_in, const int* in_sizes, int n_in,
                              void* d_out, int out_size, void* d_ws, size_t ws_size,
                              hipStream_t stream)
{
  const float* xq  = (const float*)d_in[0];
  const float* xsr = (const float*)d_in[1];
  const float* xsc = (const float*)d_in[2];
  const float* Wf  = (const float*)d_in[3];
  const float* bf  = (const float*)d_in[4];
  const float* W1  = (const float*)d_in[5];
  const float* b1  = (const float*)d_in[6];
  const float* W2  = (const float*)d_in[7];
  const float* b2  = (const float*)d_in[8];
  const float* W3  = (const float*)d_in[9];
  const float* b3  = (const float*)d_in[10];
  float* out  = (float*)d_out;
  int M = in_sizes[0]/3;
  int N = in_sizes[1]/3;

  // workspace layout: gridh (packed f16) + qpk always live; union region holds
  // EITHER the main path's sort buffers OR the fallback's 64 MB f32 grid.
  char* W = (char*)d_ws;
  size_t off = 0;
  auto alloc = [&](size_t bytes){ size_t o = off; off = (off + bytes + 255) & ~(size_t)255; return o; };
  size_t o_gridh = alloc((size_t)NCELLS * 16);            // 32 MiB packed f16 grid
  size_t o_qpk   = alloc((size_t)M * sizeof(float4));     // 8 MB
  size_t o_union = off;
  // main-path sub-offsets within the union region:
  size_t o_cells = alloc((size_t)(NCELLS/2) * sizeof(int)); // 4 MiB (u16-packed counters)
  size_t o_qcnt  = alloc((size_t)NQBINS * sizeof(int));   // 128 KB (directly after cells)
  size_t o_bsum  = alloc((size_t)SCAN_BLOCKS * sizeof(int));
  size_t o_qstart= alloc((size_t)NQBINS * sizeof(int));   // 128 KB
  size_t o_pcode = alloc((size_t)N * sizeof(uint32_t));   // 2 MB
  size_t o_qcode = alloc((size_t)M * sizeof(uint32_t));   // 2 MB
  size_t o_ppu   = alloc((size_t)N * sizeof(half8));      // 8 MB unsorted payload
  size_t o_pzu   = alloc((size_t)N * sizeof(float));      // 2 MB
  size_t o_pp    = alloc((size_t)N * sizeof(half8));      // 8 MB sorted payload
  size_t o_pz    = alloc((size_t)N * sizeof(float));      // 2 MB
  size_t main_end = off;
  size_t full_end = (o_union + (size_t)NCELLS * 8 * sizeof(float) > main_end)
                  ? (o_union + (size_t)NCELLS * 8 * sizeof(float)) : main_end;

  uint4*    gridh  = (uint4*)(W + o_gridh);
  float4*   qpk    = (float4*)(W + o_qpk);
  int*      cells  = (int*)(W + o_cells);
  int*      qcnt   = (int*)(W + o_qcnt);
  int*      bsum   = (int*)(W + o_bsum);
  int*      qstart = (int*)(W + o_qstart);
  uint32_t* pcode  = (uint32_t*)(W + o_pcode);
  uint32_t* qcode  = (uint32_t*)(W + o_qcode);
  half8*    pp_u   = (half8*)(W + o_ppu);
  float*    pz_u   = (float*)(W + o_pzu);
  half8*    pp     = (half8*)(W + o_pp);
  float*    pz     = (float*)(W + o_pz);
  float*    gridf  = (float*)(W + o_union);   // fallback f32 grid (aliases sort buffers)

  int nthr = (N > M) ? N : M;
  int nblkNM = (nthr + 255) / 256;

  if (main_end <= ws_size && full_end <= ws_size) {
    hipMemsetAsync(cells, 0, (size_t)(NCELLS/2) * sizeof(int) + (size_t)NQBINS * sizeof(int), stream);
    hist2_kernel<<<nblkNM, 256, 0, stream>>>(xsr, xsc, Wf, bf, xq, cells, qcnt,
                                             pcode, qcode, pp_u, pz_u, N, M);
    scan1_kernel<<<SCAN_BLOCKS, 256, 0, stream>>>(cells, bsum);
    scan2q_kernel<<<1, 1024, 0, stream>>>(bsum, qcnt, qstart);
    scatter2_kernel<<<nblkNM, 256, 0, stream>>>(xq, cells, bsum, qstart,
                                                pcode, qcode, pp_u, pz_u,
                                                pp, pz, qpk, N, M);
    p2g_gather_pair_kernel<<<(NCELLS/2)/256, 256, 0, stream>>>(cells, bsum, pp, pz, gridh, N);
  } else if (full_end <= ws_size) {
    hipMemsetAsync(gridf, 0, (size_t)NCELLS * 8 * sizeof(float), stream);
    p2g_atomic_kernel<<<(N+255)/256, 256, 0, stream>>>(xsr, xsc, Wf, bf, gridf, N);
    grid2half_kernel<<<NCELLS/256, 256, 0, stream>>>(gridf, gridh);
    qident_kernel<<<(M+255)/256, 256, 0, stream>>>(xq, qpk, M);
  } else {
    // minimal-footprint fallback: f32 atomic grid in the union region start
    hipMemsetAsync(gridf, 0, (size_t)NCELLS * 8 * sizeof(float), stream);
    p2g_atomic_kernel<<<(N+255)/256, 256, 0, stream>>>(xsr, xsc, Wf, bf, gridf, N);
    grid2half_kernel<<<NCELLS/256, 256, 0, stream>>>(gridf, gridh);
    qident_kernel<<<(M+255)/256, 256, 0, stream>>>(xq, qpk, M);
  }

  int nblk = (M + 255) / 256;
  gather_mlp_sorted_kernel<<<nblk, 256, 0, stream>>>(qpk, gridh, W1,b1,W2,b2,W3,b3, out, M, nblk);
}